// Round 1
// baseline (2424.394 us; speedup 1.0000x reference)
//
#include <hip/hip_runtime.h>

#define N_DIM 4096
#define C_DIM 512
#define CN_ ((long)C_DIM * (long)N_DIM)   // 2,097,152

enum { EPI_NONE = 0, EPI_PHI = 1, EPI_RELU_BIAS = 2, EPI_RES_BIAS = 3, EPI_PRE = 4 };

// ---------------------------------------------------------------------------
// Generic tiled fp32 GEMM: OUT[o,n] = epi( sum_c W[o,c] * X[c,n] )
// W row-major (O,K); X row-major (K-ish, N) with rows stride N_DIM.
// GROUPED: 4 groups of 128; W is (4,128,128); X channel base = g*128, K=128.
// blockIdx: x = o-tile (64), y = n-tile (64), z = batch.
// ---------------------------------------------------------------------------
template<int EPI, bool GROUPED>
__global__ __launch_bounds__(256) void gemm_wx(
    const float* __restrict__ W, const float* __restrict__ X,
    float* __restrict__ OUT, const float* __restrict__ bias,
    const float* __restrict__ aux0, const float* __restrict__ aux1,
    int K, long xzstride, long ozstride, long a0zstride)
{
    __shared__ float Ws[16][64];
    __shared__ float Xs[16][64];
    int tid = threadIdx.x;
    int o0 = blockIdx.x * 64, n0 = blockIdx.y * 64;
    int z = blockIdx.z;
    const float* Xz = X + (long)z * xzstride;
    float* Oz = OUT + (long)z * ozstride;
    const float* A0 = nullptr;
    if (EPI == EPI_PRE || EPI == EPI_RES_BIAS) A0 = aux0 + (long)z * a0zstride;

    const float* Wp = W;
    int ob = o0, cbase = 0;
    if (GROUPED) { int g = o0 >> 7; Wp = W + (long)g * 128 * 128; ob = o0 & 127; cbase = g << 7; }

    int lw_o = tid >> 2;          // 0..63
    int lw_k = (tid & 3) * 4;     // 0,4,8,12
    int lx_k = tid >> 4;          // 0..15
    int lx_n = (tid & 15) * 4;    // 0..60
    int to = (tid >> 4) * 4, tn = (tid & 15) * 4;

    float acc[4][4];
#pragma unroll
    for (int i = 0; i < 4; i++)
#pragma unroll
        for (int j = 0; j < 4; j++) acc[i][j] = 0.f;

    for (int k0 = 0; k0 < K; k0 += 16) {
        float4 wv = *(const float4*)&Wp[(long)(ob + lw_o) * K + k0 + lw_k];
        Ws[lw_k + 0][lw_o] = wv.x; Ws[lw_k + 1][lw_o] = wv.y;
        Ws[lw_k + 2][lw_o] = wv.z; Ws[lw_k + 3][lw_o] = wv.w;
        *(float4*)&Xs[lx_k][lx_n] =
            *(const float4*)&Xz[(long)(cbase + k0 + lx_k) * N_DIM + n0 + lx_n];
        __syncthreads();
#pragma unroll
        for (int kk = 0; kk < 16; kk++) {
            float4 a = *(const float4*)&Ws[kk][to];
            float4 b = *(const float4*)&Xs[kk][tn];
            float av[4] = {a.x, a.y, a.z, a.w};
            float bv[4] = {b.x, b.y, b.z, b.w};
#pragma unroll
            for (int i = 0; i < 4; i++)
#pragma unroll
                for (int j = 0; j < 4; j++) acc[i][j] = fmaf(av[i], bv[j], acc[i][j]);
        }
        __syncthreads();
    }

#pragma unroll
    for (int i = 0; i < 4; i++) {
        int o = o0 + to + i;
        long row = (long)o * N_DIM + n0 + tn;
        float tv[4];
#pragma unroll
        for (int j = 0; j < 4; j++) {
            float v = acc[i][j];
            if (EPI == EPI_PHI)            v = fmaxf(v, 0.f) + 1.f;
            else if (EPI == EPI_RELU_BIAS) v = fmaxf(v + bias[o], 0.f);
            else if (EPI == EPI_RES_BIAS)  v = v + bias[o] + A0[row + j];
            else if (EPI == EPI_PRE)       v = A0[row + j] + aux1[row + j] * v;
            tv[j] = v;
        }
        *(float4*)&Oz[row] = make_float4(tv[0], tv[1], tv[2], tv[3]);
    }
}

// out[b,c] = scale * sum_n in[b,c,n] * (w ? w[b,n] : 1)
__global__ __launch_bounds__(256) void rowreduce(
    const float* __restrict__ in, const float* __restrict__ w,
    float* __restrict__ out, float scale)
{
    int c = blockIdx.x, b = blockIdx.y, tid = threadIdx.x;
    const float* I = in + ((long)b * C_DIM + c) * N_DIM;
    float s = 0.f;
    for (int n = tid * 4; n < N_DIM; n += 1024) {
        float4 v = *(const float4*)&I[n];
        if (w) {
            float4 a = *(const float4*)&w[(long)b * N_DIM + n];
            s += v.x * a.x + v.y * a.y + v.z * a.z + v.w * a.w;
        } else {
            s += v.x + v.y + v.z + v.w;
        }
    }
    __shared__ float red[4];
#pragma unroll
    for (int off = 32; off; off >>= 1) s += __shfl_down(s, off, 64);
    int wid = tid >> 6, lane = tid & 63;
    if (lane == 0) red[wid] = s;
    __syncthreads();
    if (tid == 0) out[(long)b * C_DIM + c] = (red[0] + red[1] + red[2] + red[3]) * scale;
}

// logits[b,n] = sum_c Qg[b,c] * k0[b,c,n]
__global__ __launch_bounds__(256) void logits_k(
    const float* __restrict__ k0, const float* __restrict__ Qg,
    float* __restrict__ logits)
{
    int tid = threadIdx.x, nn = tid & 63, cc = tid >> 6;
    int b = blockIdx.y;
    int n = blockIdx.x * 64 + nn;
    const float* Kp = k0 + (long)b * CN_;
    const float* Q = Qg + (long)b * C_DIM;
    float s = 0.f;
    for (int c = cc * 128; c < cc * 128 + 128; c++)
        s += Q[c] * Kp[(long)c * N_DIM + n];
    __shared__ float red[4][64];
    red[cc][nn] = s;
    __syncthreads();
    if (cc == 0)
        logits[(long)b * N_DIM + n] = red[0][nn] + red[1][nn] + red[2][nn] + red[3][nn];
}

// alpha[b,n] = softmax_n(logits[b,:]) * N
__global__ __launch_bounds__(256) void softmax_alpha(
    const float* __restrict__ logits, float* __restrict__ alpha)
{
    int b = blockIdx.x, tid = threadIdx.x;
    const float* L = logits + (long)b * N_DIM;
    float* A = alpha + (long)b * N_DIM;
    float lv[16];
    float mx = -3.4e38f;
#pragma unroll
    for (int i = 0; i < 4; i++) {
        float4 v = *(const float4*)&L[tid * 4 + i * 1024];
        lv[4 * i + 0] = v.x; lv[4 * i + 1] = v.y; lv[4 * i + 2] = v.z; lv[4 * i + 3] = v.w;
        mx = fmaxf(mx, fmaxf(fmaxf(v.x, v.y), fmaxf(v.z, v.w)));
    }
    __shared__ float red[8];
    float m = mx;
#pragma unroll
    for (int off = 32; off; off >>= 1) m = fmaxf(m, __shfl_down(m, off, 64));
    int wid = tid >> 6, lane = tid & 63;
    if (lane == 0) red[wid] = m;
    __syncthreads();
    m = fmaxf(fmaxf(red[0], red[1]), fmaxf(red[2], red[3]));
    float e[16], s = 0.f;
#pragma unroll
    for (int i = 0; i < 16; i++) { e[i] = expf(lv[i] - m); s += e[i]; }
#pragma unroll
    for (int off = 32; off; off >>= 1) s += __shfl_down(s, off, 64);
    if (lane == 0) red[4 + wid] = s;
    __syncthreads();
    float S = red[4] + red[5] + red[6] + red[7];
    float sc = 4096.f / S;
#pragma unroll
    for (int i = 0; i < 4; i++)
        *(float4*)&A[tid * 4 + i * 1024] =
            make_float4(e[4 * i] * sc, e[4 * i + 1] * sc, e[4 * i + 2] * sc, e[4 * i + 3] * sc);
}

// kv[b,c,d] += (1/sqrt(C)) * sum_{n in chunk} (k0[b,c,n]*alpha[b,n]) * v0[b,d,n]
// grid: (c/64, d/64, 4*4): z = b*4 + nchunk. kv must be pre-zeroed.
__global__ __launch_bounds__(256) void kv_nt(
    const float* __restrict__ k0, const float* __restrict__ v0,
    const float* __restrict__ alpha, float* __restrict__ kv)
{
    __shared__ float As[32][68];
    __shared__ float Bs[32][68];
    int tid = threadIdx.x;
    int c0 = blockIdx.x * 64, d0 = blockIdx.y * 64;
    int b = blockIdx.z >> 2, nch = blockIdx.z & 3;
    const float* Kp = k0 + (long)b * CN_;
    const float* Vp = v0 + (long)b * CN_;
    const float* Al = alpha + (long)b * N_DIM;
    int li = tid >> 2, ln = (tid & 3) * 8;
    int tc = (tid >> 4) * 4, td = (tid & 15) * 4;
    float acc[4][4];
#pragma unroll
    for (int i = 0; i < 4; i++)
#pragma unroll
        for (int j = 0; j < 4; j++) acc[i][j] = 0.f;

    for (int n0 = nch * 1024; n0 < nch * 1024 + 1024; n0 += 32) {
        float4 a1 = *(const float4*)&Kp[(long)(c0 + li) * N_DIM + n0 + ln];
        float4 a2 = *(const float4*)&Kp[(long)(c0 + li) * N_DIM + n0 + ln + 4];
        float4 w1 = *(const float4*)&Al[n0 + ln];
        float4 w2 = *(const float4*)&Al[n0 + ln + 4];
        As[ln + 0][li] = a1.x * w1.x; As[ln + 1][li] = a1.y * w1.y;
        As[ln + 2][li] = a1.z * w1.z; As[ln + 3][li] = a1.w * w1.w;
        As[ln + 4][li] = a2.x * w2.x; As[ln + 5][li] = a2.y * w2.y;
        As[ln + 6][li] = a2.z * w2.z; As[ln + 7][li] = a2.w * w2.w;
        float4 b1 = *(const float4*)&Vp[(long)(d0 + li) * N_DIM + n0 + ln];
        float4 b2 = *(const float4*)&Vp[(long)(d0 + li) * N_DIM + n0 + ln + 4];
        Bs[ln + 0][li] = b1.x; Bs[ln + 1][li] = b1.y; Bs[ln + 2][li] = b1.z; Bs[ln + 3][li] = b1.w;
        Bs[ln + 4][li] = b2.x; Bs[ln + 5][li] = b2.y; Bs[ln + 6][li] = b2.z; Bs[ln + 7][li] = b2.w;
        __syncthreads();
#pragma unroll
        for (int nn = 0; nn < 32; nn++) {
            float4 av = *(const float4*)&As[nn][tc];
            float4 bv = *(const float4*)&Bs[nn][td];
            float avv[4] = {av.x, av.y, av.z, av.w};
            float bvv[4] = {bv.x, bv.y, bv.z, bv.w};
#pragma unroll
            for (int i = 0; i < 4; i++)
#pragma unroll
                for (int j = 0; j < 4; j++) acc[i][j] = fmaf(avv[i], bvv[j], acc[i][j]);
        }
        __syncthreads();
    }
    const float s = 0.044194173824159216f; // 1/sqrt(512)
    float* KV = kv + (long)b * C_DIM * C_DIM;
#pragma unroll
    for (int i = 0; i < 4; i++)
#pragma unroll
        for (int j = 0; j < 4; j++)
            atomicAdd(&KV[(long)(c0 + tc + i) * C_DIM + d0 + td + j], acc[i][j] * s);
}

// den6[mm,n] = sum_c q6[mm,c,n] * k_sum[(m0+mm)%4, c]
__global__ __launch_bounds__(256) void den_k(
    const float* __restrict__ q6, const float* __restrict__ k_sum,
    float* __restrict__ den6, int m0)
{
    int tid = threadIdx.x, nn = tid & 63, cc = tid >> 6;
    int mm = blockIdx.y;
    int b = (m0 + mm) & 3;
    int n = blockIdx.x * 64 + nn;
    const float* Q = q6 + (long)mm * CN_;
    const float* ks = k_sum + (long)b * C_DIM;
    float s = 0.f;
    for (int c = cc * 128; c < cc * 128 + 128; c++)
        s += ks[c] * Q[(long)c * N_DIM + n];
    __shared__ float red[4][64];
    red[cc][nn] = s;
    __syncthreads();
    if (cc == 0)
        den6[(long)mm * N_DIM + n] = red[0][nn] + red[1][nn] + red[2][nn] + red[3][nn];
}

// ybar[d,n] += (1/12) * sum_mm ( sum_c kv[b][c,d]*q6[mm,c,n] ) * phi6[mm,d,n] / (den6[mm,n]+eps)
__global__ __launch_bounds__(256) void ybar_accum(
    const float* __restrict__ kv, const float* __restrict__ q6,
    const float* __restrict__ phi6, const float* __restrict__ den6,
    float* __restrict__ ybar, int m0, int mcnt)
{
    __shared__ float Ws[16][64];
    __shared__ float Xs[16][64];
    int tid = threadIdx.x;
    int d0 = blockIdx.x * 64, n0 = blockIdx.y * 64;
    int lx_k = tid >> 4, lx_n = (tid & 15) * 4;
    int to = (tid >> 4) * 4, tn = (tid & 15) * 4;
    float ytile[4][4];
#pragma unroll
    for (int i = 0; i < 4; i++)
#pragma unroll
        for (int j = 0; j < 4; j++) ytile[i][j] = 0.f;

    for (int mm = 0; mm < mcnt; ++mm) {
        int b = (m0 + mm) & 3;
        const float* kvb = kv + (long)b * C_DIM * C_DIM;
        const float* Q = q6 + (long)mm * CN_;
        float acc[4][4];
#pragma unroll
        for (int i = 0; i < 4; i++)
#pragma unroll
            for (int j = 0; j < 4; j++) acc[i][j] = 0.f;

        for (int k0 = 0; k0 < C_DIM; k0 += 16) {
            *(float4*)&Ws[lx_k][lx_n] =
                *(const float4*)&kvb[(long)(k0 + lx_k) * C_DIM + d0 + lx_n];
            *(float4*)&Xs[lx_k][lx_n] =
                *(const float4*)&Q[(long)(k0 + lx_k) * N_DIM + n0 + lx_n];
            __syncthreads();
#pragma unroll
            for (int kk = 0; kk < 16; kk++) {
                float4 a = *(const float4*)&Ws[kk][to];
                float4 x = *(const float4*)&Xs[kk][tn];
                float av[4] = {a.x, a.y, a.z, a.w};
                float bv[4] = {x.x, x.y, x.z, x.w};
#pragma unroll
                for (int i = 0; i < 4; i++)
#pragma unroll
                    for (int j = 0; j < 4; j++) acc[i][j] = fmaf(av[i], bv[j], acc[i][j]);
            }
            __syncthreads();
        }
        const float* P = phi6 + (long)mm * CN_;
        const float* D = den6 + (long)mm * N_DIM;
        float zrow[4];
#pragma unroll
        for (int j = 0; j < 4; j++) zrow[j] = 1.f / (D[n0 + tn + j] + 1e-6f);
#pragma unroll
        for (int i = 0; i < 4; i++) {
            long row = (long)(d0 + to + i) * N_DIM + n0 + tn;
#pragma unroll
            for (int j = 0; j < 4; j++)
                ytile[i][j] += acc[i][j] * zrow[j] * P[row + j];
        }
    }
#pragma unroll
    for (int i = 0; i < 4; i++) {
        long row = (long)(d0 + to + i) * N_DIM + n0 + tn;
        float4 old = *(float4*)&ybar[row];
        old.x += ytile[i][0] * (1.f / 12.f);
        old.y += ytile[i][1] * (1.f / 12.f);
        old.z += ytile[i][2] * (1.f / 12.f);
        old.w += ytile[i][3] * (1.f / 12.f);
        *(float4*)&ybar[row] = old;
    }
}

// Column LayerNorm over the 512 channels at each (b,n); optional relu.
// in/out layout (C_DIM, N_DIM), z-strided per batch.
__global__ __launch_bounds__(256) void col_ln(
    const float* __restrict__ in, float* __restrict__ out,
    const float* __restrict__ gamma, const float* __restrict__ beta,
    int do_relu, long zin, long zout)
{
    __shared__ float g[512], bb[512];
    __shared__ float red[2][4][64];
    int tid = threadIdx.x;
    for (int i = tid; i < 512; i += 256) { g[i] = gamma[i]; bb[i] = beta[i]; }
    int nn = tid & 63, cc = tid >> 6;
    int n = blockIdx.x * 64 + nn;
    const float* I = in + (long)blockIdx.y * zin;
    float* O = out + (long)blockIdx.y * zout;
    float s = 0.f, s2 = 0.f;
    for (int c = cc * 128; c < cc * 128 + 128; c++) {
        float v = I[(long)c * N_DIM + n];
        s += v; s2 += v * v;
    }
    red[0][cc][nn] = s; red[1][cc][nn] = s2;
    __syncthreads();
    float S = red[0][0][nn] + red[0][1][nn] + red[0][2][nn] + red[0][3][nn];
    float S2 = red[1][0][nn] + red[1][1][nn] + red[1][2][nn] + red[1][3][nn];
    float mean = S * (1.f / 512.f);
    float var = S2 * (1.f / 512.f) - mean * mean;
    float r = rsqrtf(var + 1e-6f);
    for (int c = cc * 128; c < cc * 128 + 128; c++) {
        float v = (I[(long)c * N_DIM + n] - mean) * r * g[c] + bb[c];
        if (do_relu) v = fmaxf(v, 0.f);
        O[(long)c * N_DIM + n] = v;
    }
}

extern "C" void kernel_launch(void* const* d_in, const int* in_sizes, int n_in,
                              void* d_out, int out_size, void* d_ws, size_t ws_size,
                              hipStream_t stream)
{
    const float* x     = (const float*)d_in[0];
    const float* Wq    = (const float*)d_in[1];
    const float* Wk    = (const float*)d_in[2];
    const float* Wv    = (const float*)d_in[3];
    const float* Wphi  = (const float*)d_in[4];
    const float* ln1_w = (const float*)d_in[5];
    const float* ln1_b = (const float*)d_in[6];
    const float* fc1_w = (const float*)d_in[7];
    const float* fc1_b = (const float*)d_in[8];
    const float* fc2_w = (const float*)d_in[9];
    const float* fc2_b = (const float*)d_in[10];
    const float* ln2_w = (const float*)d_in[11];
    const float* ln2_b = (const float*)d_in[12];
    float* out = (float*)d_out;

    float* ws = (float*)d_ws;
    // small region [0, 16 MiB)
    float* kvbuf  = ws;                 // 4*512*512   = 1,048,576 f
    float* ybar   = ws + 1048576;       // 512*4096    = 2,097,152 f
    float* Qg     = ws + 3145728;       // 2048 f
    float* logits = ws + 3147776;       // 16384 f
    float* alpha  = ws + 3164160;       // 16384 f
    float* ksum   = ws + 3180544;       // 2048 f
    float* den6   = ws + 3182592;       // 24576 f
    // big region @ 16 MiB, stage-overlapped (stream-sequential lifetimes)
    float* big  = ws + 4194304;
    float* k0   = big;                  // stage1: 4*CN
    float* v0   = big + 4 * CN_;        // stage1: 4*CN
    float* q6   = big;                  // stage2: 6*CN
    float* phi6 = big + 6 * CN_;        // stage2: 6*CN
    float* pre  = big;                  // stage3: 4*CN
    float* tln  = big + 4 * CN_;        // stage3: 4*CN
    float* ubuf = big + 8 * CN_;        // stage3: 4*CN
    float* hbuf = big + 12 * CN_;       // stage3: 2048*4096 = 4*CN (per-b reuse)

    dim3 blk(256);

    hipMemsetAsync(ybar, 0, 2097152 * sizeof(float), stream);
    hipMemsetAsync(kvbuf, 0, 1048576 * sizeof(float), stream);

    // ---- stage 1: k0, v0, Qg, alpha, k_sum, kv (first batches, b=0..3) ----
    gemm_wx<EPI_PHI, true><<<dim3(8, 64, 4), blk, 0, stream>>>(
        Wk, x, k0, nullptr, nullptr, nullptr, 128, CN_, CN_, 0);
    gemm_wx<EPI_NONE, false><<<dim3(8, 64, 4), blk, 0, stream>>>(
        Wv, x, v0, nullptr, nullptr, nullptr, 512, CN_, CN_, 0);
    rowreduce<<<dim3(512, 4), blk, 0, stream>>>(k0, nullptr, Qg, 1.f / 4096.f);
    logits_k<<<dim3(64, 4), blk, 0, stream>>>(k0, Qg, logits);
    softmax_alpha<<<dim3(4), blk, 0, stream>>>(logits, alpha);
    rowreduce<<<dim3(512, 4), blk, 0, stream>>>(k0, alpha, ksum, 1.f);
    kv_nt<<<dim3(8, 8, 16), blk, 0, stream>>>(k0, v0, alpha, kvbuf);

    // ---- stage 2: q, phi_rest, den, ybar accumulation (m in 2 chunks of 6) ----
    for (int ch = 0; ch < 2; ++ch) {
        int m0 = ch * 6;
        const float* xr = x + (long)(4 + m0) * CN_;
        gemm_wx<EPI_PHI, true><<<dim3(8, 64, 6), blk, 0, stream>>>(
            Wq, xr, q6, nullptr, nullptr, nullptr, 128, CN_, CN_, 0);
        gemm_wx<EPI_NONE, false><<<dim3(8, 64, 6), blk, 0, stream>>>(
            Wphi, xr, phi6, nullptr, nullptr, nullptr, 512, CN_, CN_, 0);
        den_k<<<dim3(64, 6), blk, 0, stream>>>(q6, ksum, den6, m0);
        ybar_accum<<<dim3(8, 64), blk, 0, stream>>>(kvbuf, q6, phi6, den6, ybar, m0, 6);
    }

    // ---- stage 3: pre = first + ybar*phi_first; LN1; MLP; LN2+relu ----
    gemm_wx<EPI_PRE, false><<<dim3(8, 64, 4), blk, 0, stream>>>(
        Wphi, x, pre, nullptr, x, ybar, 512, CN_, CN_, CN_);
    col_ln<<<dim3(64, 4), blk, 0, stream>>>(pre, tln, ln1_w, ln1_b, 0, CN_, CN_);
    for (int b = 0; b < 4; ++b) {
        gemm_wx<EPI_RELU_BIAS, false><<<dim3(32, 64, 1), blk, 0, stream>>>(
            fc1_w, tln + (long)b * CN_, hbuf, fc1_b, nullptr, nullptr, 512, 0, 0, 0);
        gemm_wx<EPI_RES_BIAS, false><<<dim3(8, 64, 1), blk, 0, stream>>>(
            fc2_w, hbuf, ubuf + (long)b * CN_, fc2_b, tln + (long)b * CN_, nullptr, 2048, 0, 0, 0);
    }
    col_ln<<<dim3(64, 4), blk, 0, stream>>>(ubuf, out, ln2_w, ln2_b, 1, CN_, CN_);

    // ---- passthrough: out[4:] = rest ----
    hipMemcpyAsync(out + 4 * CN_, x + 4 * CN_, 12 * CN_ * sizeof(float),
                   hipMemcpyDeviceToDevice, stream);
}

// Round 3
// 1121.990 us; speedup vs baseline: 2.1608x; 2.1608x over previous
//
#include <hip/hip_runtime.h>

#define N_DIM 4096
#define C_DIM 512
#define CN_ ((long)C_DIM * (long)N_DIM)   // 2,097,152

typedef unsigned short ushort_t;
typedef __attribute__((ext_vector_type(8))) short bf16x8;
typedef __attribute__((ext_vector_type(4))) float f32x4;

__device__ __forceinline__ ushort_t f2b(float f) {
    unsigned u = __builtin_bit_cast(unsigned, f);
    u += 0x7fffu + ((u >> 16) & 1u);
    return (ushort_t)(u >> 16);
}
__device__ __forceinline__ float b2f(ushort_t s) {
    return __builtin_bit_cast(float, (unsigned)s << 16);
}

enum { EPI_NONE = 0, EPI_PHI = 1, EPI_RELU_BIAS = 2, EPI_RES_BIAS = 3, EPI_PRE = 4 };

// ---------------------------------------------------------------------------
// bf16 MFMA GEMM: OUT[z][n][o] = epi( sum_k A[z][n][k] * W[o][k] )
// A bf16 [z][N_DIM][a_rstride], W bf16 (O,K) row-major (grouped: (4,128,128)).
// Tile: 64 n x 128 o, BK=32, 4 waves (2x2), wave = 32n x 64o = 2x4 frags.
// ---------------------------------------------------------------------------
template<int EPI, bool GROUPED, bool OBF>
__global__ __launch_bounds__(256) void mfma_gemm(
    const ushort_t* __restrict__ Wb, const ushort_t* __restrict__ A,
    void* __restrict__ OUTV, const float* __restrict__ bias,
    const ushort_t* __restrict__ auxb, const float* __restrict__ auxf,
    int K, int O, int a_rstride, long a_zstride, long o_zstride, long auxb_zstride)
{
    __shared__ ushort_t Als[64][40];
    __shared__ ushort_t Bls[128][40];
    const int tid = threadIdx.x;
    const int o0 = blockIdx.x * 128;
    const int n0 = blockIdx.y * 64;
    const int z = blockIdx.z;
    const ushort_t* Az = A + (long)z * a_zstride;
    const ushort_t* Wp = Wb;
    int kbase = 0, obase = o0;
    if (GROUPED) { int g = o0 >> 7; Wp = Wb + (long)g * (128 * 128); kbase = g << 7; obase = 0; }

    const int ar = tid >> 2, as = (tid & 3) * 8;     // A stage: row n0+ar, k as..as+7
    const int br = tid >> 1, bs = (tid & 1) * 16;    // B stage: row br, k bs..bs+15
    const int w = tid >> 6, l = tid & 63;
    const int wr = (w >> 1) * 32, wc = (w & 1) * 64;
    const int fr = l & 15, ks = l >> 4;

    f32x4 acc[2][4];
#pragma unroll
    for (int m = 0; m < 2; ++m)
#pragma unroll
        for (int nf = 0; nf < 4; ++nf) acc[m][nf] = f32x4{0.f, 0.f, 0.f, 0.f};

    const ushort_t* aptr = Az + (long)(n0 + ar) * a_rstride + kbase + as;
    const ushort_t* bptr = Wp + (long)(obase + br) * K + bs;

    for (int kk = 0; kk < K; kk += 32) {
        uint4 av = *(const uint4*)(aptr + kk);
        uint4 bv0 = *(const uint4*)(bptr + kk);
        uint4 bv1 = *(const uint4*)(bptr + kk + 8);
        __syncthreads();
        *(uint4*)&Als[ar][as] = av;
        *(uint4*)&Bls[br][bs] = bv0;
        *(uint4*)&Bls[br][bs + 8] = bv1;
        __syncthreads();
        bf16x8 af[2], bfv[4];
#pragma unroll
        for (int m = 0; m < 2; ++m)
            af[m] = *(const bf16x8*)&Als[wr + m * 16 + fr][ks * 8];
#pragma unroll
        for (int nf = 0; nf < 4; ++nf)
            bfv[nf] = *(const bf16x8*)&Bls[wc + nf * 16 + fr][ks * 8];
#pragma unroll
        for (int m = 0; m < 2; ++m)
#pragma unroll
            for (int nf = 0; nf < 4; ++nf)
                acc[m][nf] = __builtin_amdgcn_mfma_f32_16x16x32_bf16(
                    af[m], bfv[nf], acc[m][nf], 0, 0, 0);
    }

#pragma unroll
    for (int m = 0; m < 2; ++m) {
#pragma unroll
        for (int nf = 0; nf < 4; ++nf) {
            const int oo = o0 + wc + nf * 16 + fr;
            float bval = 0.f;
            if (EPI == EPI_RELU_BIAS || EPI == EPI_RES_BIAS) bval = bias[oo];
#pragma unroll
            for (int j = 0; j < 4; ++j) {
                const int nn = n0 + wr + m * 16 + ks * 4 + j;
                const long ridx = (long)nn * O + oo;
                float v = acc[m][nf][j];
                if (EPI == EPI_PHI)            v = fmaxf(v, 0.f) + 1.f;
                else if (EPI == EPI_RELU_BIAS) v = fmaxf(v + bval, 0.f);
                else if (EPI == EPI_RES_BIAS)  v = v + bval + b2f(auxb[(long)z * auxb_zstride + ridx]);
                else if (EPI == EPI_PRE)       v = b2f(auxb[(long)z * auxb_zstride + ridx]) + auxf[ridx] * v;
                if (OBF) ((ushort_t*)OUTV)[(long)z * o_zstride + ridx] = f2b(v);
                else     ((float*)OUTV)[(long)z * o_zstride + ridx] = v;
            }
        }
    }
}

// ---------------------------------------------------------------------------
// ybar[n][d] (+)= (1/12) sum_mm (sum_c q4[mm][n][c]*kvT[mm][d][c]) * z * phi4
// ---------------------------------------------------------------------------
__global__ __launch_bounds__(256) void ybar_mfma(
    const ushort_t* __restrict__ q4, const ushort_t* __restrict__ kvT,
    const ushort_t* __restrict__ phi4, const float* __restrict__ den4,
    float* __restrict__ ybar, int accflag)
{
    __shared__ ushort_t Als[64][40];
    __shared__ ushort_t Bls[128][40];
    const int tid = threadIdx.x;
    const int o0 = blockIdx.x * 128;
    const int n0 = blockIdx.y * 64;
    const int ar = tid >> 2, as = (tid & 3) * 8;
    const int br = tid >> 1, bs = (tid & 1) * 16;
    const int w = tid >> 6, l = tid & 63;
    const int wr = (w >> 1) * 32, wc = (w & 1) * 64;
    const int fr = l & 15, ks = l >> 4;

    f32x4 yt[2][4];
#pragma unroll
    for (int m = 0; m < 2; ++m)
#pragma unroll
        for (int nf = 0; nf < 4; ++nf) yt[m][nf] = f32x4{0.f, 0.f, 0.f, 0.f};

    for (int mm = 0; mm < 4; ++mm) {
        const ushort_t* aptr = q4 + (long)mm * CN_ + (long)(n0 + ar) * 512 + as;
        const ushort_t* bptr = kvT + (long)mm * (512 * 512) + (long)(o0 + br) * 512 + bs;
        f32x4 acc[2][4];
#pragma unroll
        for (int m = 0; m < 2; ++m)
#pragma unroll
            for (int nf = 0; nf < 4; ++nf) acc[m][nf] = f32x4{0.f, 0.f, 0.f, 0.f};

        for (int kk = 0; kk < 512; kk += 32) {
            uint4 av = *(const uint4*)(aptr + kk);
            uint4 bv0 = *(const uint4*)(bptr + kk);
            uint4 bv1 = *(const uint4*)(bptr + kk + 8);
            __syncthreads();
            *(uint4*)&Als[ar][as] = av;
            *(uint4*)&Bls[br][bs] = bv0;
            *(uint4*)&Bls[br][bs + 8] = bv1;
            __syncthreads();
            bf16x8 af[2], bfv[4];
#pragma unroll
            for (int m = 0; m < 2; ++m)
                af[m] = *(const bf16x8*)&Als[wr + m * 16 + fr][ks * 8];
#pragma unroll
            for (int nf = 0; nf < 4; ++nf)
                bfv[nf] = *(const bf16x8*)&Bls[wc + nf * 16 + fr][ks * 8];
#pragma unroll
            for (int m = 0; m < 2; ++m)
#pragma unroll
                for (int nf = 0; nf < 4; ++nf)
                    acc[m][nf] = __builtin_amdgcn_mfma_f32_16x16x32_bf16(
                        af[m], bfv[nf], acc[m][nf], 0, 0, 0);
        }
        const ushort_t* P = phi4 + (long)mm * CN_;
        const float* D = den4 + (long)mm * N_DIM;
        float zr[2][4];
#pragma unroll
        for (int m = 0; m < 2; ++m)
#pragma unroll
            for (int j = 0; j < 4; ++j)
                zr[m][j] = 1.f / (D[n0 + wr + m * 16 + ks * 4 + j] + 1e-6f);
#pragma unroll
        for (int m = 0; m < 2; ++m)
#pragma unroll
            for (int nf = 0; nf < 4; ++nf) {
                const int oo = o0 + wc + nf * 16 + fr;
#pragma unroll
                for (int j = 0; j < 4; ++j) {
                    const int nn = n0 + wr + m * 16 + ks * 4 + j;
                    yt[m][nf][j] += acc[m][nf][j] * zr[m][j] * b2f(P[(long)nn * 512 + oo]);
                }
            }
        __syncthreads();
    }
#pragma unroll
    for (int m = 0; m < 2; ++m)
#pragma unroll
        for (int nf = 0; nf < 4; ++nf) {
            const int oo = o0 + wc + nf * 16 + fr;
#pragma unroll
            for (int j = 0; j < 4; ++j) {
                const int nn = n0 + wr + m * 16 + ks * 4 + j;
                const long idx = (long)nn * 512 + oo;
                float r = yt[m][nf][j] * (1.f / 12.f);
                if (accflag) r += ybar[idx];
                ybar[idx] = r;
            }
        }
}

// fp32 -> bf16 elementwise
__global__ __launch_bounds__(256) void cvt_f2b(
    const float* __restrict__ in, ushort_t* __restrict__ out, int n)
{
    int i = (blockIdx.x * 256 + threadIdx.x) * 4;
    if (i >= n) return;
    float4 v = *(const float4*)&in[i];
    union { ushort_t s[4]; uint2 u; } p;
    p.s[0] = f2b(v.x); p.s[1] = f2b(v.y); p.s[2] = f2b(v.z); p.s[3] = f2b(v.w);
    *(uint2*)&out[i] = p.u;
}

// transpose fp32 [z][rows][cols] -> bf16 [z][cols][rows]
__global__ __launch_bounds__(256) void transpose_f2b(
    const float* __restrict__ in, ushort_t* __restrict__ out,
    int rows, int cols, long in_z, long out_z)
{
    __shared__ float t[64][65];
    const int tid = threadIdx.x;
    const int n0 = blockIdx.x * 64, c0 = blockIdx.y * 64;
    const float* I = in + (long)blockIdx.z * in_z;
    ushort_t* Ot = out + (long)blockIdx.z * out_z;
    const int r = tid >> 2, s4 = (tid & 3) * 16;
#pragma unroll
    for (int i = 0; i < 16; i += 4) {
        float4 v = *(const float4*)&I[(long)(c0 + r) * cols + n0 + s4 + i];
        t[r][s4 + i] = v.x; t[r][s4 + i + 1] = v.y;
        t[r][s4 + i + 2] = v.z; t[r][s4 + i + 3] = v.w;
    }
    __syncthreads();
    union { ushort_t s[16]; uint4 u[2]; } pk;
#pragma unroll
    for (int i = 0; i < 16; ++i) pk.s[i] = f2b(t[s4 + i][r]);
    uint4* dst = (uint4*)&Ot[(long)(n0 + r) * rows + c0 + s4];
    dst[0] = pk.u[0]; dst[1] = pk.u[1];
}

// transpose fp32 [z][rows][cols] -> fp32 [z][cols][rows]
__global__ __launch_bounds__(256) void transpose_ff(
    const float* __restrict__ in, float* __restrict__ out,
    int rows, int cols, long in_z, long out_z)
{
    __shared__ float t[64][65];
    const int tid = threadIdx.x;
    const int n0 = blockIdx.x * 64, c0 = blockIdx.y * 64;
    const float* I = in + (long)blockIdx.z * in_z;
    float* Ot = out + (long)blockIdx.z * out_z;
    const int r = tid >> 2, s4 = (tid & 3) * 16;
#pragma unroll
    for (int i = 0; i < 16; i += 4) {
        float4 v = *(const float4*)&I[(long)(c0 + r) * cols + n0 + s4 + i];
        t[r][s4 + i] = v.x; t[r][s4 + i + 1] = v.y;
        t[r][s4 + i + 2] = v.z; t[r][s4 + i + 3] = v.w;
    }
    __syncthreads();
#pragma unroll
    for (int i = 0; i < 16; i += 4) {
        float4 o = make_float4(t[s4 + i][r], t[s4 + i + 1][r], t[s4 + i + 2][r], t[s4 + i + 3][r]);
        *(float4*)&Ot[(long)(n0 + r) * rows + c0 + s4 + i] = o;
    }
}

// partial column reduce: part[ns][b][c] = sum_{n in slice} X[b][n][c] * (wgt?[b][n])
__global__ __launch_bounds__(256) void colreduce_part(
    const ushort_t* __restrict__ X, const float* __restrict__ wgt,
    float* __restrict__ part)
{
    const int c = blockIdx.x * 256 + threadIdx.x;
    const int b = blockIdx.y, ns = blockIdx.z;
    const ushort_t* Xb = X + (long)b * CN_;
    float s = 0.f;
    for (int n = ns * 512; n < ns * 512 + 512; ++n) {
        float v = b2f(Xb[(long)n * C_DIM + c]);
        s += wgt ? v * wgt[(long)b * N_DIM + n] : v;
    }
    part[((long)ns * 4 + b) * C_DIM + c] = s;
}

__global__ __launch_bounds__(256) void colreduce_fin(
    const float* __restrict__ part, float* __restrict__ out, float scale)
{
    int b = blockIdx.x;
    for (int c = threadIdx.x; c < 512; c += 256) {
        float s = 0.f;
        for (int ns = 0; ns < 8; ++ns) s += part[((long)ns * 4 + b) * C_DIM + c];
        out[b * C_DIM + c] = s * scale;
    }
}

// out[z][n] = sum_c X[z][n][c] * w[z][c]
__global__ __launch_bounds__(256) void dot_rows(
    const ushort_t* __restrict__ X, const float* __restrict__ w,
    float* __restrict__ out)
{
    const int tid = threadIdx.x;
    const int rn = tid >> 2, cs = (tid & 3) * 128;
    const int z = blockIdx.y;
    const int n = blockIdx.x * 64 + rn;
    const ushort_t* row = X + (long)z * CN_ + (long)n * C_DIM;
    const float* wz = w + (long)z * C_DIM;
    float s = 0.f;
    for (int i = 0; i < 128; i += 8) {
        uint4 u = *(const uint4*)&row[cs + i];
        const ushort_t* us = (const ushort_t*)&u;
#pragma unroll
        for (int k2 = 0; k2 < 8; ++k2) s += b2f(us[k2]) * wz[cs + i + k2];
    }
    s += __shfl_xor(s, 1); s += __shfl_xor(s, 2);
    if ((tid & 3) == 0) out[(long)z * N_DIM + n] = s;
}

// alpha[b,n] = softmax_n(logits[b,:]) * N
__global__ __launch_bounds__(256) void softmax_alpha(
    const float* __restrict__ logits, float* __restrict__ alpha)
{
    int b = blockIdx.x, tid = threadIdx.x;
    const float* L = logits + (long)b * N_DIM;
    float* A = alpha + (long)b * N_DIM;
    float lv[16];
    float mx = -3.4e38f;
#pragma unroll
    for (int i = 0; i < 4; i++) {
        float4 v = *(const float4*)&L[tid * 4 + i * 1024];
        lv[4 * i + 0] = v.x; lv[4 * i + 1] = v.y; lv[4 * i + 2] = v.z; lv[4 * i + 3] = v.w;
        mx = fmaxf(mx, fmaxf(fmaxf(v.x, v.y), fmaxf(v.z, v.w)));
    }
    __shared__ float red[8];
    float m = mx;
#pragma unroll
    for (int off = 32; off; off >>= 1) m = fmaxf(m, __shfl_down(m, off, 64));
    int wid = tid >> 6, lane = tid & 63;
    if (lane == 0) red[wid] = m;
    __syncthreads();
    m = fmaxf(fmaxf(red[0], red[1]), fmaxf(red[2], red[3]));
    float e[16], s = 0.f;
#pragma unroll
    for (int i = 0; i < 16; i++) { e[i] = expf(lv[i] - m); s += e[i]; }
#pragma unroll
    for (int off = 32; off; off >>= 1) s += __shfl_down(s, off, 64);
    if (lane == 0) red[4 + wid] = s;
    __syncthreads();
    float S = red[4] + red[5] + red[6] + red[7];
    float sc = 4096.f / S;
#pragma unroll
    for (int i = 0; i < 4; i++)
        *(float4*)&A[tid * 4 + i * 1024] =
            make_float4(e[4 * i] * sc, e[4 * i + 1] * sc, e[4 * i + 2] * sc, e[4 * i + 3] * sc);
}

// kv[b][c][d] = (1/sqrt(C)) sum_n k0[b][n][c]*alpha[b][n] * v0[b][n][d]
__global__ __launch_bounds__(256) void kv_fp32(
    const ushort_t* __restrict__ k0, const ushort_t* __restrict__ v0,
    const float* __restrict__ alpha, float* __restrict__ kv)
{
    __shared__ float Ks[32][68];
    __shared__ float Vs[32][68];
    const int tid = threadIdx.x;
    const int c0 = blockIdx.x * 64, d0 = blockIdx.y * 64, b = blockIdx.z;
    const ushort_t* Kp = k0 + (long)b * CN_;
    const ushort_t* Vp = v0 + (long)b * CN_;
    const float* Al = alpha + (long)b * N_DIM;
    const int nn = tid >> 3, c8 = (tid & 7) * 8;
    const int tc = (tid >> 4) * 4, td = (tid & 15) * 4;
    float acc[4][4];
#pragma unroll
    for (int i = 0; i < 4; i++)
#pragma unroll
        for (int j = 0; j < 4; j++) acc[i][j] = 0.f;

    for (int n0 = 0; n0 < N_DIM; n0 += 32) {
        uint4 ku = *(const uint4*)&Kp[(long)(n0 + nn) * C_DIM + c0 + c8];
        uint4 vu = *(const uint4*)&Vp[(long)(n0 + nn) * C_DIM + d0 + c8];
        float a = Al[n0 + nn];
        __syncthreads();
        const ushort_t* kp = (const ushort_t*)&ku;
        const ushort_t* vp = (const ushort_t*)&vu;
#pragma unroll
        for (int i = 0; i < 8; ++i) Ks[nn][c8 + i] = b2f(kp[i]) * a;
#pragma unroll
        for (int i = 0; i < 8; ++i) Vs[nn][c8 + i] = b2f(vp[i]);
        __syncthreads();
#pragma unroll
        for (int q = 0; q < 32; ++q) {
            float4 ka = *(const float4*)&Ks[q][tc];
            float4 vb = *(const float4*)&Vs[q][td];
            float av[4] = {ka.x, ka.y, ka.z, ka.w};
            float bv[4] = {vb.x, vb.y, vb.z, vb.w};
#pragma unroll
            for (int i = 0; i < 4; i++)
#pragma unroll
                for (int j = 0; j < 4; j++) acc[i][j] = fmaf(av[i], bv[j], acc[i][j]);
        }
    }
    const float s = 0.044194173824159216f; // 1/sqrt(512)
    float* KV = kv + (long)b * 262144;
#pragma unroll
    for (int i = 0; i < 4; i++)
#pragma unroll
        for (int j = 0; j < 4; j++)
            KV[(long)(c0 + tc + i) * 512 + d0 + td + j] = acc[i][j] * s;
}

// row LayerNorm over c (512) per (z,n); optional relu; out bf16 or f32
template<int RELU, int OBF>
__global__ __launch_bounds__(256) void ln_row(
    const float* __restrict__ in, const float* __restrict__ g,
    const float* __restrict__ bt, void* __restrict__ outv)
{
    const int tid = threadIdx.x;
    const int r = tid >> 3, cs = (tid & 7) * 64;
    const long base = (((long)blockIdx.y * N_DIM) + blockIdx.x * 32 + r) * C_DIM + cs;
    const float* I = in + base;
    float4 v[16];
    float s = 0.f, s2 = 0.f;
#pragma unroll
    for (int i = 0; i < 16; ++i) {
        v[i] = *(const float4*)&I[i * 4];
        s += v[i].x + v[i].y + v[i].z + v[i].w;
        s2 += v[i].x * v[i].x + v[i].y * v[i].y + v[i].z * v[i].z + v[i].w * v[i].w;
    }
#pragma unroll
    for (int off = 1; off < 8; off <<= 1) { s += __shfl_xor(s, off); s2 += __shfl_xor(s2, off); }
    const float mean = s * (1.f / 512.f);
    const float var = s2 * (1.f / 512.f) - mean * mean;
    const float rs = rsqrtf(var + 1e-6f);
#pragma unroll
    for (int i = 0; i < 16; ++i) {
        float4 gv = *(const float4*)&g[cs + i * 4];
        float4 bv = *(const float4*)&bt[cs + i * 4];
        float o[4];
        o[0] = (v[i].x - mean) * rs * gv.x + bv.x;
        o[1] = (v[i].y - mean) * rs * gv.y + bv.y;
        o[2] = (v[i].z - mean) * rs * gv.z + bv.z;
        o[3] = (v[i].w - mean) * rs * gv.w + bv.w;
        if (RELU) {
            o[0] = fmaxf(o[0], 0.f); o[1] = fmaxf(o[1], 0.f);
            o[2] = fmaxf(o[2], 0.f); o[3] = fmaxf(o[3], 0.f);
        }
        if (OBF) {
            union { ushort_t s4[4]; uint2 u; } p;
            p.s4[0] = f2b(o[0]); p.s4[1] = f2b(o[1]); p.s4[2] = f2b(o[2]); p.s4[3] = f2b(o[3]);
            *(uint2*)&((ushort_t*)outv)[base + i * 4] = p.u;
        } else {
            *(float4*)&((float*)outv)[base + i * 4] = make_float4(o[0], o[1], o[2], o[3]);
        }
    }
}

extern "C" void kernel_launch(void* const* d_in, const int* in_sizes, int n_in,
                              void* d_out, int out_size, void* d_ws, size_t ws_size,
                              hipStream_t stream)
{
    const float* x     = (const float*)d_in[0];
    const float* Wq    = (const float*)d_in[1];
    const float* Wk    = (const float*)d_in[2];
    const float* Wv    = (const float*)d_in[3];
    const float* Wphi  = (const float*)d_in[4];
    const float* ln1_w = (const float*)d_in[5];
    const float* ln1_b = (const float*)d_in[6];
    const float* fc1_w = (const float*)d_in[7];
    const float* fc1_bias = (const float*)d_in[8];
    const float* fc2_w = (const float*)d_in[9];
    const float* fc2_bias = (const float*)d_in[10];
    const float* ln2_w = (const float*)d_in[11];
    const float* ln2_b = (const float*)d_in[12];
    float* out = (float*)d_out;

    float* ws = (float*)d_ws;
    const long CN = CN_;
    // region map (float units); lifetimes are stream-sequential:
    ushort_t* xTfirst = (ushort_t*)ws;                 // [0,2CN): xT b0..3 bf16 -> tln later
    ushort_t* tln     = (ushort_t*)ws;
    ushort_t* xTc  = (ushort_t*)(ws + 2 * CN);         // [2CN,4CN): xT chunk -> hbuf later
    ushort_t* hbuf = (ushort_t*)(ws + 2 * CN);
    ushort_t* k0b = (ushort_t*)(ws + 4 * CN);          // [4CN,6CN)
    ushort_t* v0b = (ushort_t*)(ws + 6 * CN);          // [6CN,8CN)
    float* pre = ws + 4 * CN;                          // reuses k0+v0 region
    float* tmp = ws + 4 * CN;                          // reuses pre region
    ushort_t* q4   = (ushort_t*)(ws + 8 * CN);         // [8CN,10CN)
    ushort_t* phi4 = (ushort_t*)(ws + 10 * CN);        // [10CN,12CN)
    float* ubuf = ws + 8 * CN;                         // reuses q4+phi4 region
    float* ybar = ws + 12 * CN;                        // [12CN,13CN)
    float* kvb  = ws + 13 * CN;                        // 1M floats
    ushort_t* kvT = (ushort_t*)(ws + 13 * CN + 1048576);   // 1M bf16
    float* wb = ws + 13 * CN + 1048576 + 524288;
    ushort_t* Wk_b   = (ushort_t*)(wb);
    ushort_t* Wq_b   = (ushort_t*)(wb + 32768);
    ushort_t* Wv_b   = (ushort_t*)(wb + 65536);
    ushort_t* Wphi_b = (ushort_t*)(wb + 196608);
    ushort_t* fc1_b16 = (ushort_t*)(wb + 327680);
    ushort_t* fc2_b16 = (ushort_t*)(wb + 851968);
    float* part   = wb + 1376256;
    float* Qg     = wb + 1392640;
    float* ksum   = wb + 1394688;
    float* logits = wb + 1396736;
    float* alpha  = wb + 1413120;
    float* den4   = wb + 1429504;

    dim3 blk(256);

    // weights -> bf16
    cvt_f2b<<<64, blk, 0, stream>>>(Wk, Wk_b, 65536);
    cvt_f2b<<<64, blk, 0, stream>>>(Wq, Wq_b, 65536);
    cvt_f2b<<<256, blk, 0, stream>>>(Wv, Wv_b, 262144);
    cvt_f2b<<<256, blk, 0, stream>>>(Wphi, Wphi_b, 262144);
    cvt_f2b<<<1024, blk, 0, stream>>>(fc1_w, fc1_b16, 1048576);
    cvt_f2b<<<1024, blk, 0, stream>>>(fc2_w, fc2_b16, 1048576);

    // xT for first 4 batches (also serves as firstT residual source)
    transpose_f2b<<<dim3(64, 8, 4), blk, 0, stream>>>(x, xTfirst, 512, 4096, CN, CN);

    // stage 1: k0, v0, reductions, alpha, ksum, kv
    mfma_gemm<EPI_PHI, true, true><<<dim3(4, 64, 4), blk, 0, stream>>>(
        Wk_b, xTfirst, k0b, nullptr, nullptr, nullptr, 128, 512, 512, CN, CN, 0);
    mfma_gemm<EPI_NONE, false, true><<<dim3(4, 64, 4), blk, 0, stream>>>(
        Wv_b, xTfirst, v0b, nullptr, nullptr, nullptr, 512, 512, 512, CN, CN, 0);
    colreduce_part<<<dim3(2, 4, 8), blk, 0, stream>>>(k0b, nullptr, part);
    colreduce_fin<<<4, blk, 0, stream>>>(part, Qg, 1.f / 4096.f);
    dot_rows<<<dim3(64, 4), blk, 0, stream>>>(k0b, Qg, logits);
    softmax_alpha<<<4, blk, 0, stream>>>(logits, alpha);
    colreduce_part<<<dim3(2, 4, 8), blk, 0, stream>>>(k0b, alpha, part);
    colreduce_fin<<<4, blk, 0, stream>>>(part, ksum, 1.f);
    kv_fp32<<<dim3(8, 8, 4), blk, 0, stream>>>(k0b, v0b, alpha, kvb);
    transpose_f2b<<<dim3(8, 8, 4), blk, 0, stream>>>(kvb, kvT, 512, 512, 262144, 262144);

    // stage 2: rest in 3 chunks of 4 (b = mm since chunks are 4-aligned)
    for (int ch = 0; ch < 3; ++ch) {
        const float* xr = x + (long)(4 + 4 * ch) * CN;
        transpose_f2b<<<dim3(64, 8, 4), blk, 0, stream>>>(xr, xTc, 512, 4096, CN, CN);
        mfma_gemm<EPI_PHI, true, true><<<dim3(4, 64, 4), blk, 0, stream>>>(
            Wq_b, xTc, q4, nullptr, nullptr, nullptr, 128, 512, 512, CN, CN, 0);
        mfma_gemm<EPI_NONE, false, true><<<dim3(4, 64, 4), blk, 0, stream>>>(
            Wphi_b, xTc, phi4, nullptr, nullptr, nullptr, 512, 512, 512, CN, CN, 0);
        dot_rows<<<dim3(64, 4), blk, 0, stream>>>(q4, ksum, den4);
        ybar_mfma<<<dim3(4, 64), blk, 0, stream>>>(q4, kvT, phi4, den4, ybar, ch > 0);
    }

    // stage 3: pre = firstT + ybar*phiF; LN1; MLP; LN2+relu; transpose out
    mfma_gemm<EPI_PRE, false, false><<<dim3(4, 64, 4), blk, 0, stream>>>(
        Wphi_b, xTfirst, pre, nullptr, xTfirst, ybar, 512, 512, 512, CN, CN, CN);
    ln_row<0, 1><<<dim3(128, 4), blk, 0, stream>>>(pre, ln1_w, ln1_b, tln);
    for (int b = 0; b < 4; ++b) {
        mfma_gemm<EPI_RELU_BIAS, false, true><<<dim3(16, 64, 1), blk, 0, stream>>>(
            fc1_b16, tln + (long)b * CN, hbuf, fc1_bias, nullptr, nullptr,
            512, 2048, 512, 0, 0, 0);
        mfma_gemm<EPI_RES_BIAS, false, false><<<dim3(4, 64, 1), blk, 0, stream>>>(
            fc2_b16, hbuf, ubuf + (long)b * CN, fc2_bias, tln + (long)b * CN, nullptr,
            2048, 512, 2048, 0, 0, 0);
    }
    ln_row<1, 0><<<dim3(128, 4), blk, 0, stream>>>(ubuf, ln2_w, ln2_b, tmp);
    transpose_ff<<<dim3(8, 64, 4), blk, 0, stream>>>(tmp, out, 4096, 512, CN, CN);

    // passthrough: out[4:] = rest
    hipMemcpyAsync(out + 4 * CN, x + 4 * CN, 12 * CN * sizeof(float),
                   hipMemcpyDeviceToDevice, stream);
}

// Round 4
// 1003.658 us; speedup vs baseline: 2.4156x; 1.1179x over previous
//
#include <hip/hip_runtime.h>

#define N_DIM 4096
#define C_DIM 512
#define CN_ ((long)C_DIM * (long)N_DIM)   // 2,097,152

typedef unsigned short ushort_t;
typedef __attribute__((ext_vector_type(8))) short bf16x8;
typedef __attribute__((ext_vector_type(4))) float f32x4;

__device__ __forceinline__ ushort_t f2b(float f) {
    unsigned u = __builtin_bit_cast(unsigned, f);
    u += 0x7fffu + ((u >> 16) & 1u);
    return (ushort_t)(u >> 16);
}
__device__ __forceinline__ float b2f(ushort_t s) {
    return __builtin_bit_cast(float, (unsigned)s << 16);
}

enum { EPI_NONE = 0, EPI_PHI = 1, EPI_RELU_BIAS = 2, EPI_RES_BIAS = 3, EPI_PRE = 4 };

// ---------------------------------------------------------------------------
// bf16 MFMA GEMM: OUT[z][n][o] = epi( sum_k A[z][n][k] * W[o][k] )
// ---------------------------------------------------------------------------
template<int EPI, bool GROUPED, bool OBF>
__global__ __launch_bounds__(256) void mfma_gemm(
    const ushort_t* __restrict__ Wb, const ushort_t* __restrict__ A,
    void* __restrict__ OUTV, const float* __restrict__ bias,
    const ushort_t* __restrict__ auxb, const float* __restrict__ auxf,
    int K, int O, int a_rstride, long a_zstride, long o_zstride, long auxb_zstride)
{
    __shared__ ushort_t Als[64][40];
    __shared__ ushort_t Bls[128][40];
    const int tid = threadIdx.x;
    const int o0 = blockIdx.x * 128;
    const int n0 = blockIdx.y * 64;
    const int z = blockIdx.z;
    const ushort_t* Az = A + (long)z * a_zstride;
    const ushort_t* Wp = Wb;
    int kbase = 0, obase = o0;
    if (GROUPED) { int g = o0 >> 7; Wp = Wb + (long)g * (128 * 128); kbase = g << 7; obase = 0; }

    const int ar = tid >> 2, as = (tid & 3) * 8;
    const int br = tid >> 1, bs = (tid & 1) * 16;
    const int w = tid >> 6, l = tid & 63;
    const int wr = (w >> 1) * 32, wc = (w & 1) * 64;
    const int fr = l & 15, ks = l >> 4;

    f32x4 acc[2][4];
#pragma unroll
    for (int m = 0; m < 2; ++m)
#pragma unroll
        for (int nf = 0; nf < 4; ++nf) acc[m][nf] = f32x4{0.f, 0.f, 0.f, 0.f};

    const ushort_t* aptr = Az + (long)(n0 + ar) * a_rstride + kbase + as;
    const ushort_t* bptr = Wp + (long)(obase + br) * K + bs;

    for (int kk = 0; kk < K; kk += 32) {
        uint4 av = *(const uint4*)(aptr + kk);
        uint4 bv0 = *(const uint4*)(bptr + kk);
        uint4 bv1 = *(const uint4*)(bptr + kk + 8);
        __syncthreads();
        *(uint4*)&Als[ar][as] = av;
        *(uint4*)&Bls[br][bs] = bv0;
        *(uint4*)&Bls[br][bs + 8] = bv1;
        __syncthreads();
        bf16x8 af[2], bfv[4];
#pragma unroll
        for (int m = 0; m < 2; ++m)
            af[m] = *(const bf16x8*)&Als[wr + m * 16 + fr][ks * 8];
#pragma unroll
        for (int nf = 0; nf < 4; ++nf)
            bfv[nf] = *(const bf16x8*)&Bls[wc + nf * 16 + fr][ks * 8];
#pragma unroll
        for (int m = 0; m < 2; ++m)
#pragma unroll
            for (int nf = 0; nf < 4; ++nf)
                acc[m][nf] = __builtin_amdgcn_mfma_f32_16x16x32_bf16(
                    af[m], bfv[nf], acc[m][nf], 0, 0, 0);
    }

#pragma unroll
    for (int m = 0; m < 2; ++m) {
#pragma unroll
        for (int nf = 0; nf < 4; ++nf) {
            const int oo = o0 + wc + nf * 16 + fr;
            float bval = 0.f;
            if (EPI == EPI_RELU_BIAS || EPI == EPI_RES_BIAS) bval = bias[oo];
#pragma unroll
            for (int j = 0; j < 4; ++j) {
                const int nn = n0 + wr + m * 16 + ks * 4 + j;
                const long ridx = (long)nn * O + oo;
                float v = acc[m][nf][j];
                if (EPI == EPI_PHI)            v = fmaxf(v, 0.f) + 1.f;
                else if (EPI == EPI_RELU_BIAS) v = fmaxf(v + bval, 0.f);
                else if (EPI == EPI_RES_BIAS)  v = v + bval + b2f(auxb[(long)z * auxb_zstride + ridx]);
                else if (EPI == EPI_PRE)       v = b2f(auxb[(long)z * auxb_zstride + ridx]) + auxf[ridx] * v;
                if (OBF) ((ushort_t*)OUTV)[(long)z * o_zstride + ridx] = f2b(v);
                else     ((float*)OUTV)[(long)z * o_zstride + ridx] = v;
            }
        }
    }
}

// ---------------------------------------------------------------------------
// kv NT-MFMA: kvb[b][d][c] += sum_{n in chunk} v0c[b][d][n] * khat[b][c][n]
// grid (c/128, d/64, b*4+chunk); kvb pre-zeroed fp32.
// ---------------------------------------------------------------------------
__global__ __launch_bounds__(256) void kv_mfma(
    const ushort_t* __restrict__ v0c, const ushort_t* __restrict__ khat,
    float* __restrict__ kvb)
{
    __shared__ ushort_t Als[64][40];
    __shared__ ushort_t Bls[128][40];
    const int tid = threadIdx.x;
    const int c0 = blockIdx.x * 128;
    const int d0 = blockIdx.y * 64;
    const int b = blockIdx.z >> 2, nch = blockIdx.z & 3;
    const ushort_t* Ab = v0c + (long)b * CN_;
    const ushort_t* Bb = khat + (long)b * CN_;
    const int ar = tid >> 2, as = (tid & 3) * 8;
    const int br = tid >> 1, bs = (tid & 1) * 16;
    const int w = tid >> 6, l = tid & 63;
    const int wr = (w >> 1) * 32, wc = (w & 1) * 64;
    const int fr = l & 15, ks = l >> 4;

    f32x4 acc[2][4];
#pragma unroll
    for (int m = 0; m < 2; ++m)
#pragma unroll
        for (int nf = 0; nf < 4; ++nf) acc[m][nf] = f32x4{0.f, 0.f, 0.f, 0.f};

    const ushort_t* aptr = Ab + (long)(d0 + ar) * N_DIM + nch * 1024 + as;
    const ushort_t* bptr = Bb + (long)(c0 + br) * N_DIM + nch * 1024 + bs;

    for (int kk = 0; kk < 1024; kk += 32) {
        uint4 av = *(const uint4*)(aptr + kk);
        uint4 bv0 = *(const uint4*)(bptr + kk);
        uint4 bv1 = *(const uint4*)(bptr + kk + 8);
        __syncthreads();
        *(uint4*)&Als[ar][as] = av;
        *(uint4*)&Bls[br][bs] = bv0;
        *(uint4*)&Bls[br][bs + 8] = bv1;
        __syncthreads();
        bf16x8 af[2], bfv[4];
#pragma unroll
        for (int m = 0; m < 2; ++m)
            af[m] = *(const bf16x8*)&Als[wr + m * 16 + fr][ks * 8];
#pragma unroll
        for (int nf = 0; nf < 4; ++nf)
            bfv[nf] = *(const bf16x8*)&Bls[wc + nf * 16 + fr][ks * 8];
#pragma unroll
        for (int m = 0; m < 2; ++m)
#pragma unroll
            for (int nf = 0; nf < 4; ++nf)
                acc[m][nf] = __builtin_amdgcn_mfma_f32_16x16x32_bf16(
                    af[m], bfv[nf], acc[m][nf], 0, 0, 0);
    }

    float* KV = kvb + (long)b * 262144;
#pragma unroll
    for (int m = 0; m < 2; ++m)
#pragma unroll
        for (int nf = 0; nf < 4; ++nf) {
            const int cc = c0 + wc + nf * 16 + fr;
#pragma unroll
            for (int j = 0; j < 4; ++j) {
                const int dd = d0 + wr + m * 16 + ks * 4 + j;
                atomicAdd(&KV[(long)dd * 512 + cc], acc[m][nf][j]);
            }
        }
}

// kvT[i] = f2b(kvb[i] * 1/sqrt(512))
__global__ __launch_bounds__(256) void cvt_scale(
    const float* __restrict__ in, ushort_t* __restrict__ out)
{
    const float s = 0.044194173824159216f;
    int i = (blockIdx.x * 256 + threadIdx.x) * 4;
    float4 v = *(const float4*)&in[i];
    union { ushort_t sh[4]; uint2 u; } p;
    p.sh[0] = f2b(v.x * s); p.sh[1] = f2b(v.y * s);
    p.sh[2] = f2b(v.z * s); p.sh[3] = f2b(v.w * s);
    *(uint2*)&out[i] = p.u;
}

// bf16 [z][4096][512] -> bf16 [z][512][4096]; ALPHA: out *= alpha[z][n]
template<int ALPHA>
__global__ __launch_bounds__(256) void transpose_b2b(
    const ushort_t* __restrict__ in, ushort_t* __restrict__ out,
    const float* __restrict__ alpha)
{
    __shared__ ushort_t t[64][72];
    const int tid = threadIdx.x;
    const int n0 = blockIdx.x * 64, c0 = blockIdx.y * 64, z = blockIdx.z;
    const ushort_t* I = in + (long)z * CN_;
    ushort_t* O = out + (long)z * CN_;
    const int r = tid >> 2, s8 = (tid & 3) * 16;
    uint4 u0 = *(const uint4*)&I[(long)(n0 + r) * 512 + c0 + s8];
    uint4 u1 = *(const uint4*)&I[(long)(n0 + r) * 512 + c0 + s8 + 8];
    *(uint4*)&t[r][s8] = u0;
    *(uint4*)&t[r][s8 + 8] = u1;
    __syncthreads();
    union { ushort_t sh[16]; uint4 u[2]; } p;
#pragma unroll
    for (int i = 0; i < 16; ++i) {
        ushort_t v = t[s8 + i][r];
        if (ALPHA) v = f2b(b2f(v) * alpha[(long)z * N_DIM + n0 + s8 + i]);
        p.sh[i] = v;
    }
    uint4* dst = (uint4*)&O[(long)(c0 + r) * N_DIM + n0 + s8];
    dst[0] = p.u[0]; dst[1] = p.u[1];
}

// ---------------------------------------------------------------------------
// ybar[n][d] (+)= (1/12) sum_mm (sum_c q4[mm][n][c]*kvT[mm][d][c]) * z * phi4
// ---------------------------------------------------------------------------
__global__ __launch_bounds__(256) void ybar_mfma(
    const ushort_t* __restrict__ q4, const ushort_t* __restrict__ kvT,
    const ushort_t* __restrict__ phi4, const float* __restrict__ den4,
    float* __restrict__ ybar, int accflag)
{
    __shared__ ushort_t Als[64][40];
    __shared__ ushort_t Bls[128][40];
    const int tid = threadIdx.x;
    const int o0 = blockIdx.x * 128;
    const int n0 = blockIdx.y * 64;
    const int ar = tid >> 2, as = (tid & 3) * 8;
    const int br = tid >> 1, bs = (tid & 1) * 16;
    const int w = tid >> 6, l = tid & 63;
    const int wr = (w >> 1) * 32, wc = (w & 1) * 64;
    const int fr = l & 15, ks = l >> 4;

    f32x4 yt[2][4];
#pragma unroll
    for (int m = 0; m < 2; ++m)
#pragma unroll
        for (int nf = 0; nf < 4; ++nf) yt[m][nf] = f32x4{0.f, 0.f, 0.f, 0.f};

    for (int mm = 0; mm < 4; ++mm) {
        const ushort_t* aptr = q4 + (long)mm * CN_ + (long)(n0 + ar) * 512 + as;
        const ushort_t* bptr = kvT + (long)mm * (512 * 512) + (long)(o0 + br) * 512 + bs;
        f32x4 acc[2][4];
#pragma unroll
        for (int m = 0; m < 2; ++m)
#pragma unroll
            for (int nf = 0; nf < 4; ++nf) acc[m][nf] = f32x4{0.f, 0.f, 0.f, 0.f};

        for (int kk = 0; kk < 512; kk += 32) {
            uint4 av = *(const uint4*)(aptr + kk);
            uint4 bv0 = *(const uint4*)(bptr + kk);
            uint4 bv1 = *(const uint4*)(bptr + kk + 8);
            __syncthreads();
            *(uint4*)&Als[ar][as] = av;
            *(uint4*)&Bls[br][bs] = bv0;
            *(uint4*)&Bls[br][bs + 8] = bv1;
            __syncthreads();
            bf16x8 af[2], bfv[4];
#pragma unroll
            for (int m = 0; m < 2; ++m)
                af[m] = *(const bf16x8*)&Als[wr + m * 16 + fr][ks * 8];
#pragma unroll
            for (int nf = 0; nf < 4; ++nf)
                bfv[nf] = *(const bf16x8*)&Bls[wc + nf * 16 + fr][ks * 8];
#pragma unroll
            for (int m = 0; m < 2; ++m)
#pragma unroll
                for (int nf = 0; nf < 4; ++nf)
                    acc[m][nf] = __builtin_amdgcn_mfma_f32_16x16x32_bf16(
                        af[m], bfv[nf], acc[m][nf], 0, 0, 0);
        }
        const ushort_t* P = phi4 + (long)mm * CN_;
        const float* D = den4 + (long)mm * N_DIM;
        float zr[2][4];
#pragma unroll
        for (int m = 0; m < 2; ++m)
#pragma unroll
            for (int j = 0; j < 4; ++j)
                zr[m][j] = 1.f / (D[n0 + wr + m * 16 + ks * 4 + j] + 1e-6f);
#pragma unroll
        for (int m = 0; m < 2; ++m)
#pragma unroll
            for (int nf = 0; nf < 4; ++nf) {
                const int oo = o0 + wc + nf * 16 + fr;
#pragma unroll
                for (int j = 0; j < 4; ++j) {
                    const int nn = n0 + wr + m * 16 + ks * 4 + j;
                    yt[m][nf][j] += acc[m][nf][j] * zr[m][j] * b2f(P[(long)nn * 512 + oo]);
                }
            }
        __syncthreads();
    }
#pragma unroll
    for (int m = 0; m < 2; ++m)
#pragma unroll
        for (int nf = 0; nf < 4; ++nf) {
            const int oo = o0 + wc + nf * 16 + fr;
#pragma unroll
            for (int j = 0; j < 4; ++j) {
                const int nn = n0 + wr + m * 16 + ks * 4 + j;
                const long idx = (long)nn * 512 + oo;
                float r = yt[m][nf][j] * (1.f / 12.f);
                if (accflag) r += ybar[idx];
                ybar[idx] = r;
            }
        }
}

// fp32 -> bf16 elementwise
__global__ __launch_bounds__(256) void cvt_f2b(
    const float* __restrict__ in, ushort_t* __restrict__ out, int n)
{
    int i = (blockIdx.x * 256 + threadIdx.x) * 4;
    if (i >= n) return;
    float4 v = *(const float4*)&in[i];
    union { ushort_t s[4]; uint2 u; } p;
    p.s[0] = f2b(v.x); p.s[1] = f2b(v.y); p.s[2] = f2b(v.z); p.s[3] = f2b(v.w);
    *(uint2*)&out[i] = p.u;
}

// transpose fp32 [z][rows][cols] -> bf16 [z][cols][rows]
__global__ __launch_bounds__(256) void transpose_f2b(
    const float* __restrict__ in, ushort_t* __restrict__ out,
    int rows, int cols, long in_z, long out_z)
{
    __shared__ float t[64][65];
    const int tid = threadIdx.x;
    const int n0 = blockIdx.x * 64, c0 = blockIdx.y * 64;
    const float* I = in + (long)blockIdx.z * in_z;
    ushort_t* Ot = out + (long)blockIdx.z * out_z;
    const int r = tid >> 2, s4 = (tid & 3) * 16;
#pragma unroll
    for (int i = 0; i < 16; i += 4) {
        float4 v = *(const float4*)&I[(long)(c0 + r) * cols + n0 + s4 + i];
        t[r][s4 + i] = v.x; t[r][s4 + i + 1] = v.y;
        t[r][s4 + i + 2] = v.z; t[r][s4 + i + 3] = v.w;
    }
    __syncthreads();
    union { ushort_t s[16]; uint4 u[2]; } pk;
#pragma unroll
    for (int i = 0; i < 16; ++i) pk.s[i] = f2b(t[s4 + i][r]);
    uint4* dst = (uint4*)&Ot[(long)(n0 + r) * rows + c0 + s4];
    dst[0] = pk.u[0]; dst[1] = pk.u[1];
}

// transpose fp32 [z][rows][cols] -> fp32 [z][cols][rows]
__global__ __launch_bounds__(256) void transpose_ff(
    const float* __restrict__ in, float* __restrict__ out,
    int rows, int cols, long in_z, long out_z)
{
    __shared__ float t[64][65];
    const int tid = threadIdx.x;
    const int n0 = blockIdx.x * 64, c0 = blockIdx.y * 64;
    const float* I = in + (long)blockIdx.z * in_z;
    float* Ot = out + (long)blockIdx.z * out_z;
    const int r = tid >> 2, s4 = (tid & 3) * 16;
#pragma unroll
    for (int i = 0; i < 16; i += 4) {
        float4 v = *(const float4*)&I[(long)(c0 + r) * cols + n0 + s4 + i];
        t[r][s4 + i] = v.x; t[r][s4 + i + 1] = v.y;
        t[r][s4 + i + 2] = v.z; t[r][s4 + i + 3] = v.w;
    }
    __syncthreads();
#pragma unroll
    for (int i = 0; i < 16; i += 4) {
        float4 o = make_float4(t[s4 + i][r], t[s4 + i + 1][r], t[s4 + i + 2][r], t[s4 + i + 3][r]);
        *(float4*)&Ot[(long)(n0 + r) * rows + c0 + s4 + i] = o;
    }
}

// partial column reduce: part[ns][b][c] = sum_{n in slice} X[b][n][c] * (wgt?[b][n])
__global__ __launch_bounds__(256) void colreduce_part(
    const ushort_t* __restrict__ X, const float* __restrict__ wgt,
    float* __restrict__ part)
{
    const int c = blockIdx.x * 256 + threadIdx.x;
    const int b = blockIdx.y, ns = blockIdx.z;
    const ushort_t* Xb = X + (long)b * CN_;
    float s = 0.f;
    for (int n = ns * 512; n < ns * 512 + 512; ++n) {
        float v = b2f(Xb[(long)n * C_DIM + c]);
        s += wgt ? v * wgt[(long)b * N_DIM + n] : v;
    }
    part[((long)ns * 4 + b) * C_DIM + c] = s;
}

__global__ __launch_bounds__(256) void colreduce_fin(
    const float* __restrict__ part, float* __restrict__ out, float scale)
{
    int b = blockIdx.x;
    for (int c = threadIdx.x; c < 512; c += 256) {
        float s = 0.f;
        for (int ns = 0; ns < 8; ++ns) s += part[((long)ns * 4 + b) * C_DIM + c];
        out[b * C_DIM + c] = s * scale;
    }
}

// out[z][n] = sum_c X[z][n][c] * w[z][c]
__global__ __launch_bounds__(256) void dot_rows(
    const ushort_t* __restrict__ X, const float* __restrict__ w,
    float* __restrict__ out)
{
    const int tid = threadIdx.x;
    const int rn = tid >> 2, cs = (tid & 3) * 128;
    const int z = blockIdx.y;
    const int n = blockIdx.x * 64 + rn;
    const ushort_t* row = X + (long)z * CN_ + (long)n * C_DIM;
    const float* wz = w + (long)z * C_DIM;
    float s = 0.f;
    for (int i = 0; i < 128; i += 8) {
        uint4 u = *(const uint4*)&row[cs + i];
        const ushort_t* us = (const ushort_t*)&u;
#pragma unroll
        for (int k2 = 0; k2 < 8; ++k2) s += b2f(us[k2]) * wz[cs + i + k2];
    }
    s += __shfl_xor(s, 1); s += __shfl_xor(s, 2);
    if ((tid & 3) == 0) out[(long)z * N_DIM + n] = s;
}

// alpha[b,n] = softmax_n(logits[b,:]) * N
__global__ __launch_bounds__(256) void softmax_alpha(
    const float* __restrict__ logits, float* __restrict__ alpha)
{
    int b = blockIdx.x, tid = threadIdx.x;
    const float* L = logits + (long)b * N_DIM;
    float* A = alpha + (long)b * N_DIM;
    float lv[16];
    float mx = -3.4e38f;
#pragma unroll
    for (int i = 0; i < 4; i++) {
        float4 v = *(const float4*)&L[tid * 4 + i * 1024];
        lv[4 * i + 0] = v.x; lv[4 * i + 1] = v.y; lv[4 * i + 2] = v.z; lv[4 * i + 3] = v.w;
        mx = fmaxf(mx, fmaxf(fmaxf(v.x, v.y), fmaxf(v.z, v.w)));
    }
    __shared__ float red[8];
    float m = mx;
#pragma unroll
    for (int off = 32; off; off >>= 1) m = fmaxf(m, __shfl_down(m, off, 64));
    int wid = tid >> 6, lane = tid & 63;
    if (lane == 0) red[wid] = m;
    __syncthreads();
    m = fmaxf(fmaxf(red[0], red[1]), fmaxf(red[2], red[3]));
    float e[16], s = 0.f;
#pragma unroll
    for (int i = 0; i < 16; i++) { e[i] = expf(lv[i] - m); s += e[i]; }
#pragma unroll
    for (int off = 32; off; off >>= 1) s += __shfl_down(s, off, 64);
    if (lane == 0) red[4 + wid] = s;
    __syncthreads();
    float S = red[4] + red[5] + red[6] + red[7];
    float sc = 4096.f / S;
#pragma unroll
    for (int i = 0; i < 4; i++)
        *(float4*)&A[tid * 4 + i * 1024] =
            make_float4(e[4 * i] * sc, e[4 * i + 1] * sc, e[4 * i + 2] * sc, e[4 * i + 3] * sc);
}

// row LayerNorm over c (512) per (z,n); optional relu; out bf16 or f32
template<int RELU, int OBF>
__global__ __launch_bounds__(256) void ln_row(
    const float* __restrict__ in, const float* __restrict__ g,
    const float* __restrict__ bt, void* __restrict__ outv)
{
    const int tid = threadIdx.x;
    const int r = tid >> 3, cs = (tid & 7) * 64;
    const long base = (((long)blockIdx.y * N_DIM) + blockIdx.x * 32 + r) * C_DIM + cs;
    const float* I = in + base;
    float4 v[16];
    float s = 0.f, s2 = 0.f;
#pragma unroll
    for (int i = 0; i < 16; ++i) {
        v[i] = *(const float4*)&I[i * 4];
        s += v[i].x + v[i].y + v[i].z + v[i].w;
        s2 += v[i].x * v[i].x + v[i].y * v[i].y + v[i].z * v[i].z + v[i].w * v[i].w;
    }
#pragma unroll
    for (int off = 1; off < 8; off <<= 1) { s += __shfl_xor(s, off); s2 += __shfl_xor(s2, off); }
    const float mean = s * (1.f / 512.f);
    const float var = s2 * (1.f / 512.f) - mean * mean;
    const float rs = rsqrtf(var + 1e-6f);
#pragma unroll
    for (int i = 0; i < 16; ++i) {
        float4 gv = *(const float4*)&g[cs + i * 4];
        float4 bv = *(const float4*)&bt[cs + i * 4];
        float o[4];
        o[0] = (v[i].x - mean) * rs * gv.x + bv.x;
        o[1] = (v[i].y - mean) * rs * gv.y + bv.y;
        o[2] = (v[i].z - mean) * rs * gv.z + bv.z;
        o[3] = (v[i].w - mean) * rs * gv.w + bv.w;
        if (RELU) {
            o[0] = fmaxf(o[0], 0.f); o[1] = fmaxf(o[1], 0.f);
            o[2] = fmaxf(o[2], 0.f); o[3] = fmaxf(o[3], 0.f);
        }
        if (OBF) {
            union { ushort_t s4[4]; uint2 u; } p;
            p.s4[0] = f2b(o[0]); p.s4[1] = f2b(o[1]); p.s4[2] = f2b(o[2]); p.s4[3] = f2b(o[3]);
            *(uint2*)&((ushort_t*)outv)[base + i * 4] = p.u;
        } else {
            *(float4*)&((float*)outv)[base + i * 4] = make_float4(o[0], o[1], o[2], o[3]);
        }
    }
}

extern "C" void kernel_launch(void* const* d_in, const int* in_sizes, int n_in,
                              void* d_out, int out_size, void* d_ws, size_t ws_size,
                              hipStream_t stream)
{
    const float* x     = (const float*)d_in[0];
    const float* Wq    = (const float*)d_in[1];
    const float* Wk    = (const float*)d_in[2];
    const float* Wv    = (const float*)d_in[3];
    const float* Wphi  = (const float*)d_in[4];
    const float* ln1_w = (const float*)d_in[5];
    const float* ln1_b = (const float*)d_in[6];
    const float* fc1_w = (const float*)d_in[7];
    const float* fc1_bias = (const float*)d_in[8];
    const float* fc2_w = (const float*)d_in[9];
    const float* fc2_bias = (const float*)d_in[10];
    const float* ln2_w = (const float*)d_in[11];
    const float* ln2_b = (const float*)d_in[12];
    float* out = (float*)d_out;

    float* ws = (float*)d_ws;
    const long CN = CN_;
    // region map (float units); lifetimes are stream-sequential:
    ushort_t* xTfirst = (ushort_t*)ws;                 // [0,2CN)
    ushort_t* tln     = (ushort_t*)ws;
    ushort_t* xTc  = (ushort_t*)(ws + 2 * CN);         // [2CN,4CN)
    ushort_t* hbuf = (ushort_t*)(ws + 2 * CN);
    ushort_t* k0b = (ushort_t*)(ws + 4 * CN);          // [4CN,6CN)
    ushort_t* v0b = (ushort_t*)(ws + 6 * CN);          // [6CN,8CN)
    float* pre = ws + 4 * CN;                          // stage3 reuse
    float* tmp = ws + 4 * CN;
    ushort_t* khat = (ushort_t*)(ws + 8 * CN);         // [8CN,10CN) stage1
    ushort_t* q4   = (ushort_t*)(ws + 8 * CN);         // stage2 reuse
    ushort_t* v0c  = (ushort_t*)(ws + 10 * CN);        // [10CN,12CN) stage1
    ushort_t* phi4 = (ushort_t*)(ws + 10 * CN);        // stage2 reuse
    float* ubuf = ws + 8 * CN;                         // stage3 reuse
    float* ybar = ws + 12 * CN;                        // [12CN,13CN)
    float* kvb  = ws + 13 * CN;                        // 1M floats
    ushort_t* kvT = (ushort_t*)(ws + 13 * CN + 1048576);   // 1M bf16
    float* wb = ws + 13 * CN + 1048576 + 524288;
    ushort_t* Wk_b   = (ushort_t*)(wb);
    ushort_t* Wq_b   = (ushort_t*)(wb + 32768);
    ushort_t* Wv_b   = (ushort_t*)(wb + 65536);
    ushort_t* Wphi_b = (ushort_t*)(wb + 196608);
    ushort_t* fc1_b16 = (ushort_t*)(wb + 327680);
    ushort_t* fc2_b16 = (ushort_t*)(wb + 851968);
    float* part   = wb + 1376256;
    float* Qg     = wb + 1392640;
    float* ksum   = wb + 1394688;
    float* logits = wb + 1396736;
    float* alpha  = wb + 1413120;
    float* den4   = wb + 1429504;

    dim3 blk(256);

    // weights -> bf16
    cvt_f2b<<<64, blk, 0, stream>>>(Wk, Wk_b, 65536);
    cvt_f2b<<<64, blk, 0, stream>>>(Wq, Wq_b, 65536);
    cvt_f2b<<<256, blk, 0, stream>>>(Wv, Wv_b, 262144);
    cvt_f2b<<<256, blk, 0, stream>>>(Wphi, Wphi_b, 262144);
    cvt_f2b<<<1024, blk, 0, stream>>>(fc1_w, fc1_b16, 1048576);
    cvt_f2b<<<1024, blk, 0, stream>>>(fc2_w, fc2_b16, 1048576);
    hipMemsetAsync(kvb, 0, 1048576 * sizeof(float), stream);

    // xT for first 4 batches (residual + phi_first source)
    transpose_f2b<<<dim3(64, 8, 4), blk, 0, stream>>>(x, xTfirst, 512, 4096, CN, CN);

    // stage 1: k0, v0, reductions, alpha, ksum, kv (MFMA path)
    mfma_gemm<EPI_PHI, true, true><<<dim3(4, 64, 4), blk, 0, stream>>>(
        Wk_b, xTfirst, k0b, nullptr, nullptr, nullptr, 128, 512, 512, CN, CN, 0);
    mfma_gemm<EPI_NONE, false, true><<<dim3(4, 64, 4), blk, 0, stream>>>(
        Wv_b, xTfirst, v0b, nullptr, nullptr, nullptr, 512, 512, 512, CN, CN, 0);
    colreduce_part<<<dim3(2, 4, 8), blk, 0, stream>>>(k0b, nullptr, part);
    colreduce_fin<<<4, blk, 0, stream>>>(part, Qg, 1.f / 4096.f);
    dot_rows<<<dim3(64, 4), blk, 0, stream>>>(k0b, Qg, logits);
    softmax_alpha<<<4, blk, 0, stream>>>(logits, alpha);
    colreduce_part<<<dim3(2, 4, 8), blk, 0, stream>>>(k0b, alpha, part);
    colreduce_fin<<<4, blk, 0, stream>>>(part, ksum, 1.f);
    transpose_b2b<1><<<dim3(64, 8, 4), blk, 0, stream>>>(k0b, khat, alpha);
    transpose_b2b<0><<<dim3(64, 8, 4), blk, 0, stream>>>(v0b, v0c, nullptr);
    kv_mfma<<<dim3(4, 8, 16), blk, 0, stream>>>(v0c, khat, kvb);
    cvt_scale<<<1024, blk, 0, stream>>>(kvb, kvT);

    // stage 2: rest in 3 chunks of 4 (b = mm since chunks are 4-aligned)
    for (int ch = 0; ch < 3; ++ch) {
        const float* xr = x + (long)(4 + 4 * ch) * CN;
        transpose_f2b<<<dim3(64, 8, 4), blk, 0, stream>>>(xr, xTc, 512, 4096, CN, CN);
        mfma_gemm<EPI_PHI, true, true><<<dim3(4, 64, 4), blk, 0, stream>>>(
            Wq_b, xTc, q4, nullptr, nullptr, nullptr, 128, 512, 512, CN, CN, 0);
        mfma_gemm<EPI_NONE, false, true><<<dim3(4, 64, 4), blk, 0, stream>>>(
            Wphi_b, xTc, phi4, nullptr, nullptr, nullptr, 512, 512, 512, CN, CN, 0);
        dot_rows<<<dim3(64, 4), blk, 0, stream>>>(q4, ksum, den4);
        ybar_mfma<<<dim3(4, 64), blk, 0, stream>>>(q4, kvT, phi4, den4, ybar, ch > 0);
    }

    // stage 3: pre = firstT + ybar*phiF; LN1; MLP; LN2+relu; transpose out
    mfma_gemm<EPI_PRE, false, false><<<dim3(4, 64, 4), blk, 0, stream>>>(
        Wphi_b, xTfirst, pre, nullptr, xTfirst, ybar, 512, 512, 512, CN, CN, CN);
    ln_row<0, 1><<<dim3(128, 4), blk, 0, stream>>>(pre, ln1_w, ln1_b, tln);
    for (int b = 0; b < 4; ++b) {
        mfma_gemm<EPI_RELU_BIAS, false, true><<<dim3(16, 64, 1), blk, 0, stream>>>(
            fc1_b16, tln + (long)b * CN, hbuf, fc1_bias, nullptr, nullptr,
            512, 2048, 512, 0, 0, 0);
        mfma_gemm<EPI_RES_BIAS, false, false><<<dim3(4, 64, 1), blk, 0, stream>>>(
            fc2_b16, hbuf, ubuf + (long)b * CN, fc2_bias, tln + (long)b * CN, nullptr,
            2048, 512, 2048, 0, 0, 0);
    }
    ln_row<1, 0><<<dim3(128, 4), blk, 0, stream>>>(ubuf, ln2_w, ln2_b, tmp);
    transpose_ff<<<dim3(8, 64, 4), blk, 0, stream>>>(tmp, out, 4096, 512, CN, CN);

    // passthrough: out[4:] = rest
    hipMemcpyAsync(out + 4 * CN, x + 4 * CN, 12 * CN * sizeof(float),
                   hipMemcpyDeviceToDevice, stream);
}

// Round 5
// 801.161 us; speedup vs baseline: 3.0261x; 1.2528x over previous
//
#include <hip/hip_runtime.h>

#define N_DIM 4096
#define C_DIM 512
#define CN_ ((long)C_DIM * (long)N_DIM)   // 2,097,152

typedef unsigned short ushort_t;
typedef __attribute__((ext_vector_type(8))) short bf16x8;
typedef __attribute__((ext_vector_type(4))) float f32x4;

__device__ __forceinline__ ushort_t f2b(float f) {
    unsigned u = __builtin_bit_cast(unsigned, f);
    u += 0x7fffu + ((u >> 16) & 1u);
    return (ushort_t)(u >> 16);
}
__device__ __forceinline__ float b2f(ushort_t s) {
    return __builtin_bit_cast(float, (unsigned)s << 16);
}

enum { EPI_NONE = 0, EPI_PHI = 1, EPI_RELU_BIAS = 2, EPI_RES_BIAS = 3, EPI_PRE = 4 };

// ---------------------------------------------------------------------------
// bf16 MFMA GEMM: OUT[z][n][o] = epi( sum_k A[z][n][k] * W[o][k] )
// ---------------------------------------------------------------------------
template<int EPI, bool GROUPED, bool OBF>
__global__ __launch_bounds__(256) void mfma_gemm(
    const ushort_t* __restrict__ Wb, const ushort_t* __restrict__ A,
    void* __restrict__ OUTV, const float* __restrict__ bias,
    const ushort_t* __restrict__ auxb, const float* __restrict__ auxf,
    int K, int O, int a_rstride, long a_zstride, long o_zstride, long auxb_zstride)
{
    __shared__ ushort_t Als[64][40];
    __shared__ ushort_t Bls[128][40];
    const int tid = threadIdx.x;
    const int o0 = blockIdx.x * 128;
    const int n0 = blockIdx.y * 64;
    const int z = blockIdx.z;
    const ushort_t* Az = A + (long)z * a_zstride;
    const ushort_t* Wp = Wb;
    int kbase = 0, obase = o0;
    if (GROUPED) { int g = o0 >> 7; Wp = Wb + (long)g * (128 * 128); kbase = g << 7; obase = 0; }

    const int ar = tid >> 2, as = (tid & 3) * 8;
    const int br = tid >> 1, bs = (tid & 1) * 16;
    const int w = tid >> 6, l = tid & 63;
    const int wr = (w >> 1) * 32, wc = (w & 1) * 64;
    const int fr = l & 15, ks = l >> 4;

    f32x4 acc[2][4];
#pragma unroll
    for (int m = 0; m < 2; ++m)
#pragma unroll
        for (int nf = 0; nf < 4; ++nf) acc[m][nf] = f32x4{0.f, 0.f, 0.f, 0.f};

    const ushort_t* aptr = Az + (long)(n0 + ar) * a_rstride + kbase + as;
    const ushort_t* bptr = Wp + (long)(obase + br) * K + bs;

    for (int kk = 0; kk < K; kk += 32) {
        uint4 av = *(const uint4*)(aptr + kk);
        uint4 bv0 = *(const uint4*)(bptr + kk);
        uint4 bv1 = *(const uint4*)(bptr + kk + 8);
        __syncthreads();
        *(uint4*)&Als[ar][as] = av;
        *(uint4*)&Bls[br][bs] = bv0;
        *(uint4*)&Bls[br][bs + 8] = bv1;
        __syncthreads();
        bf16x8 af[2], bfv[4];
#pragma unroll
        for (int m = 0; m < 2; ++m)
            af[m] = *(const bf16x8*)&Als[wr + m * 16 + fr][ks * 8];
#pragma unroll
        for (int nf = 0; nf < 4; ++nf)
            bfv[nf] = *(const bf16x8*)&Bls[wc + nf * 16 + fr][ks * 8];
#pragma unroll
        for (int m = 0; m < 2; ++m)
#pragma unroll
            for (int nf = 0; nf < 4; ++nf)
                acc[m][nf] = __builtin_amdgcn_mfma_f32_16x16x32_bf16(
                    af[m], bfv[nf], acc[m][nf], 0, 0, 0);
    }

#pragma unroll
    for (int m = 0; m < 2; ++m) {
#pragma unroll
        for (int nf = 0; nf < 4; ++nf) {
            const int oo = o0 + wc + nf * 16 + fr;
            float bval = 0.f;
            if (EPI == EPI_RELU_BIAS || EPI == EPI_RES_BIAS) bval = bias[oo];
#pragma unroll
            for (int j = 0; j < 4; ++j) {
                const int nn = n0 + wr + m * 16 + ks * 4 + j;
                const long ridx = (long)nn * O + oo;
                float v = acc[m][nf][j];
                if (EPI == EPI_PHI)            v = fmaxf(v, 0.f) + 1.f;
                else if (EPI == EPI_RELU_BIAS) v = fmaxf(v + bval, 0.f);
                else if (EPI == EPI_RES_BIAS)  v = v + bval + b2f(auxb[(long)z * auxb_zstride + ridx]);
                else if (EPI == EPI_PRE)       v = b2f(auxb[(long)z * auxb_zstride + ridx]) + auxf[ridx] * v;
                if (OBF) ((ushort_t*)OUTV)[(long)z * o_zstride + ridx] = f2b(v);
                else     ((float*)OUTV)[(long)z * o_zstride + ridx] = v;
            }
        }
    }
}

// ---------------------------------------------------------------------------
// kv NT-MFMA: kvb[b][d][c] += sum_{n in chunk} v0c[b][d][n] * khat[b][c][n]
// ---------------------------------------------------------------------------
__global__ __launch_bounds__(256) void kv_mfma(
    const ushort_t* __restrict__ v0c, const ushort_t* __restrict__ khat,
    float* __restrict__ kvb)
{
    __shared__ ushort_t Als[64][40];
    __shared__ ushort_t Bls[128][40];
    const int tid = threadIdx.x;
    const int c0 = blockIdx.x * 128;
    const int d0 = blockIdx.y * 64;
    const int b = blockIdx.z >> 2, nch = blockIdx.z & 3;
    const ushort_t* Ab = v0c + (long)b * CN_;
    const ushort_t* Bb = khat + (long)b * CN_;
    const int ar = tid >> 2, as = (tid & 3) * 8;
    const int br = tid >> 1, bs = (tid & 1) * 16;
    const int w = tid >> 6, l = tid & 63;
    const int wr = (w >> 1) * 32, wc = (w & 1) * 64;
    const int fr = l & 15, ks = l >> 4;

    f32x4 acc[2][4];
#pragma unroll
    for (int m = 0; m < 2; ++m)
#pragma unroll
        for (int nf = 0; nf < 4; ++nf) acc[m][nf] = f32x4{0.f, 0.f, 0.f, 0.f};

    const ushort_t* aptr = Ab + (long)(d0 + ar) * N_DIM + nch * 1024 + as;
    const ushort_t* bptr = Bb + (long)(c0 + br) * N_DIM + nch * 1024 + bs;

    for (int kk = 0; kk < 1024; kk += 32) {
        uint4 av = *(const uint4*)(aptr + kk);
        uint4 bv0 = *(const uint4*)(bptr + kk);
        uint4 bv1 = *(const uint4*)(bptr + kk + 8);
        __syncthreads();
        *(uint4*)&Als[ar][as] = av;
        *(uint4*)&Bls[br][bs] = bv0;
        *(uint4*)&Bls[br][bs + 8] = bv1;
        __syncthreads();
        bf16x8 af[2], bfv[4];
#pragma unroll
        for (int m = 0; m < 2; ++m)
            af[m] = *(const bf16x8*)&Als[wr + m * 16 + fr][ks * 8];
#pragma unroll
        for (int nf = 0; nf < 4; ++nf)
            bfv[nf] = *(const bf16x8*)&Bls[wc + nf * 16 + fr][ks * 8];
#pragma unroll
        for (int m = 0; m < 2; ++m)
#pragma unroll
            for (int nf = 0; nf < 4; ++nf)
                acc[m][nf] = __builtin_amdgcn_mfma_f32_16x16x32_bf16(
                    af[m], bfv[nf], acc[m][nf], 0, 0, 0);
    }

    float* KV = kvb + (long)b * 262144;
#pragma unroll
    for (int m = 0; m < 2; ++m)
#pragma unroll
        for (int nf = 0; nf < 4; ++nf) {
            const int cc = c0 + wc + nf * 16 + fr;
#pragma unroll
            for (int j = 0; j < 4; ++j) {
                const int dd = d0 + wr + m * 16 + ks * 4 + j;
                atomicAdd(&KV[(long)dd * 512 + cc], acc[m][nf][j]);
            }
        }
}

// kvT[i] = f2b(kvb[i] * 1/sqrt(512))
__global__ __launch_bounds__(256) void cvt_scale(
    const float* __restrict__ in, ushort_t* __restrict__ out)
{
    const float s = 0.044194173824159216f;
    int i = (blockIdx.x * 256 + threadIdx.x) * 4;
    float4 v = *(const float4*)&in[i];
    union { ushort_t sh[4]; uint2 u; } p;
    p.sh[0] = f2b(v.x * s); p.sh[1] = f2b(v.y * s);
    p.sh[2] = f2b(v.z * s); p.sh[3] = f2b(v.w * s);
    *(uint2*)&out[i] = p.u;
}

// bf16 [z][4096][512] -> bf16 [z][512][4096]; ALPHA: out *= alpha[z][n]
template<int ALPHA>
__global__ __launch_bounds__(256) void transpose_b2b(
    const ushort_t* __restrict__ in, ushort_t* __restrict__ out,
    const float* __restrict__ alpha)
{
    __shared__ ushort_t t[64][72];
    const int tid = threadIdx.x;
    const int n0 = blockIdx.x * 64, c0 = blockIdx.y * 64, z = blockIdx.z;
    const ushort_t* I = in + (long)z * CN_;
    ushort_t* O = out + (long)z * CN_;
    const int r = tid >> 2, s8 = (tid & 3) * 16;
    uint4 u0 = *(const uint4*)&I[(long)(n0 + r) * 512 + c0 + s8];
    uint4 u1 = *(const uint4*)&I[(long)(n0 + r) * 512 + c0 + s8 + 8];
    *(uint4*)&t[r][s8] = u0;
    *(uint4*)&t[r][s8 + 8] = u1;
    __syncthreads();
    union { ushort_t sh[16]; uint4 u[2]; } p;
#pragma unroll
    for (int i = 0; i < 16; ++i) {
        ushort_t v = t[s8 + i][r];
        if (ALPHA) v = f2b(b2f(v) * alpha[(long)z * N_DIM + n0 + s8 + i]);
        p.sh[i] = v;
    }
    uint4* dst = (uint4*)&O[(long)(c0 + r) * N_DIM + n0 + s8];
    dst[0] = p.u[0]; dst[1] = p.u[1];
}

// ---------------------------------------------------------------------------
// ybar[n][d] (+)= (1/12) sum_mm (sum_c q4[mm][n][c]*kvT[mm][d][c]) * z * phi4
// ---------------------------------------------------------------------------
__global__ __launch_bounds__(256) void ybar_mfma(
    const ushort_t* __restrict__ q4, const ushort_t* __restrict__ kvT,
    const ushort_t* __restrict__ phi4, const float* __restrict__ den4,
    float* __restrict__ ybar, int accflag)
{
    __shared__ ushort_t Als[64][40];
    __shared__ ushort_t Bls[128][40];
    const int tid = threadIdx.x;
    const int o0 = blockIdx.x * 128;
    const int n0 = blockIdx.y * 64;
    const int ar = tid >> 2, as = (tid & 3) * 8;
    const int br = tid >> 1, bs = (tid & 1) * 16;
    const int w = tid >> 6, l = tid & 63;
    const int wr = (w >> 1) * 32, wc = (w & 1) * 64;
    const int fr = l & 15, ks = l >> 4;

    f32x4 yt[2][4];
#pragma unroll
    for (int m = 0; m < 2; ++m)
#pragma unroll
        for (int nf = 0; nf < 4; ++nf) yt[m][nf] = f32x4{0.f, 0.f, 0.f, 0.f};

    for (int mm = 0; mm < 4; ++mm) {
        const ushort_t* aptr = q4 + (long)mm * CN_ + (long)(n0 + ar) * 512 + as;
        const ushort_t* bptr = kvT + (long)mm * (512 * 512) + (long)(o0 + br) * 512 + bs;
        f32x4 acc[2][4];
#pragma unroll
        for (int m = 0; m < 2; ++m)
#pragma unroll
            for (int nf = 0; nf < 4; ++nf) acc[m][nf] = f32x4{0.f, 0.f, 0.f, 0.f};

        for (int kk = 0; kk < 512; kk += 32) {
            uint4 av = *(const uint4*)(aptr + kk);
            uint4 bv0 = *(const uint4*)(bptr + kk);
            uint4 bv1 = *(const uint4*)(bptr + kk + 8);
            __syncthreads();
            *(uint4*)&Als[ar][as] = av;
            *(uint4*)&Bls[br][bs] = bv0;
            *(uint4*)&Bls[br][bs + 8] = bv1;
            __syncthreads();
            bf16x8 af[2], bfv[4];
#pragma unroll
            for (int m = 0; m < 2; ++m)
                af[m] = *(const bf16x8*)&Als[wr + m * 16 + fr][ks * 8];
#pragma unroll
            for (int nf = 0; nf < 4; ++nf)
                bfv[nf] = *(const bf16x8*)&Bls[wc + nf * 16 + fr][ks * 8];
#pragma unroll
            for (int m = 0; m < 2; ++m)
#pragma unroll
                for (int nf = 0; nf < 4; ++nf)
                    acc[m][nf] = __builtin_amdgcn_mfma_f32_16x16x32_bf16(
                        af[m], bfv[nf], acc[m][nf], 0, 0, 0);
        }
        const ushort_t* P = phi4 + (long)mm * CN_;
        const float* D = den4 + (long)mm * N_DIM;
        float zr[2][4];
#pragma unroll
        for (int m = 0; m < 2; ++m)
#pragma unroll
            for (int j = 0; j < 4; ++j)
                zr[m][j] = 1.f / (D[n0 + wr + m * 16 + ks * 4 + j] + 1e-6f);
#pragma unroll
        for (int m = 0; m < 2; ++m)
#pragma unroll
            for (int nf = 0; nf < 4; ++nf) {
                const int oo = o0 + wc + nf * 16 + fr;
#pragma unroll
                for (int j = 0; j < 4; ++j) {
                    const int nn = n0 + wr + m * 16 + ks * 4 + j;
                    yt[m][nf][j] += acc[m][nf][j] * zr[m][j] * b2f(P[(long)nn * 512 + oo]);
                }
            }
        __syncthreads();
    }
#pragma unroll
    for (int m = 0; m < 2; ++m)
#pragma unroll
        for (int nf = 0; nf < 4; ++nf) {
            const int oo = o0 + wc + nf * 16 + fr;
#pragma unroll
            for (int j = 0; j < 4; ++j) {
                const int nn = n0 + wr + m * 16 + ks * 4 + j;
                const long idx = (long)nn * 512 + oo;
                float r = yt[m][nf][j] * (1.f / 12.f);
                if (accflag) r += ybar[idx];
                ybar[idx] = r;
            }
        }
}

// fp32 -> bf16 elementwise
__global__ __launch_bounds__(256) void cvt_f2b(
    const float* __restrict__ in, ushort_t* __restrict__ out, int n)
{
    int i = (blockIdx.x * 256 + threadIdx.x) * 4;
    if (i >= n) return;
    float4 v = *(const float4*)&in[i];
    union { ushort_t s[4]; uint2 u; } p;
    p.s[0] = f2b(v.x); p.s[1] = f2b(v.y); p.s[2] = f2b(v.z); p.s[3] = f2b(v.w);
    *(uint2*)&out[i] = p.u;
}

// transpose fp32 [z][rows][cols] -> bf16 [z][cols][rows]
__global__ __launch_bounds__(256) void transpose_f2b(
    const float* __restrict__ in, ushort_t* __restrict__ out,
    int rows, int cols, long in_z, long out_z)
{
    __shared__ float t[64][65];
    const int tid = threadIdx.x;
    const int n0 = blockIdx.x * 64, c0 = blockIdx.y * 64;
    const float* I = in + (long)blockIdx.z * in_z;
    ushort_t* Ot = out + (long)blockIdx.z * out_z;
    const int r = tid >> 2, s4 = (tid & 3) * 16;
#pragma unroll
    for (int i = 0; i < 16; i += 4) {
        float4 v = *(const float4*)&I[(long)(c0 + r) * cols + n0 + s4 + i];
        t[r][s4 + i] = v.x; t[r][s4 + i + 1] = v.y;
        t[r][s4 + i + 2] = v.z; t[r][s4 + i + 3] = v.w;
    }
    __syncthreads();
    union { ushort_t s[16]; uint4 u[2]; } pk;
#pragma unroll
    for (int i = 0; i < 16; ++i) pk.s[i] = f2b(t[s4 + i][r]);
    uint4* dst = (uint4*)&Ot[(long)(n0 + r) * rows + c0 + s4];
    dst[0] = pk.u[0]; dst[1] = pk.u[1];
}

// transpose fp32 [z][rows][cols] -> fp32 [z][cols][rows]
__global__ __launch_bounds__(256) void transpose_ff(
    const float* __restrict__ in, float* __restrict__ out,
    int rows, int cols, long in_z, long out_z)
{
    __shared__ float t[64][65];
    const int tid = threadIdx.x;
    const int n0 = blockIdx.x * 64, c0 = blockIdx.y * 64;
    const float* I = in + (long)blockIdx.z * in_z;
    float* Ot = out + (long)blockIdx.z * out_z;
    const int r = tid >> 2, s4 = (tid & 3) * 16;
#pragma unroll
    for (int i = 0; i < 16; i += 4) {
        float4 v = *(const float4*)&I[(long)(c0 + r) * cols + n0 + s4 + i];
        t[r][s4 + i] = v.x; t[r][s4 + i + 1] = v.y;
        t[r][s4 + i + 2] = v.z; t[r][s4 + i + 3] = v.w;
    }
    __syncthreads();
#pragma unroll
    for (int i = 0; i < 16; i += 4) {
        float4 o = make_float4(t[s4 + i][r], t[s4 + i + 1][r], t[s4 + i + 2][r], t[s4 + i + 3][r]);
        *(float4*)&Ot[(long)(n0 + r) * rows + c0 + s4 + i] = o;
    }
}

// part[ns][b][c] = sum_{n in 128-row chunk ns} X[b][n][c] * (wgt?[b][n])
// grid (32, 4); wave reads a whole 512-c row coalesced (lane l -> c=8l..8l+7)
__global__ __launch_bounds__(256) void colreduce_part(
    const ushort_t* __restrict__ X, const float* __restrict__ wgt,
    float* __restrict__ part)
{
    const int ns = blockIdx.x, b = blockIdx.y;
    const int tid = threadIdx.x;
    const int w = tid >> 6, l = tid & 63;
    const int c8 = l * 8;
    const ushort_t* Xb = X + (long)b * CN_;
    float acc[8] = {0.f, 0.f, 0.f, 0.f, 0.f, 0.f, 0.f, 0.f};
    for (int r = w; r < 128; r += 4) {
        const int n = ns * 128 + r;
        uint4 u = *(const uint4*)&Xb[(long)n * C_DIM + c8];
        const ushort_t* us = (const ushort_t*)&u;
        const float wv = wgt ? wgt[(long)b * N_DIM + n] : 1.f;
#pragma unroll
        for (int i = 0; i < 8; ++i) acc[i] += b2f(us[i]) * wv;
    }
    __shared__ float red[4][512];
#pragma unroll
    for (int i = 0; i < 8; ++i) red[w][c8 + i] = acc[i];
    __syncthreads();
    for (int c = tid; c < 512; c += 256) {
        part[((long)ns * 4 + b) * C_DIM + c] =
            red[0][c] + red[1][c] + red[2][c] + red[3][c];
    }
}

__global__ __launch_bounds__(256) void colreduce_fin(
    const float* __restrict__ part, float* __restrict__ out, float scale)
{
    int b = blockIdx.x;
    for (int c = threadIdx.x; c < 512; c += 256) {
        float s = 0.f;
        for (int ns = 0; ns < 32; ++ns) s += part[((long)ns * 4 + b) * C_DIM + c];
        out[b * C_DIM + c] = s * scale;
    }
}

// out[z][n] = sum_c X[z][n][c] * w[z][c]
__global__ __launch_bounds__(256) void dot_rows(
    const ushort_t* __restrict__ X, const float* __restrict__ w,
    float* __restrict__ out)
{
    const int tid = threadIdx.x;
    const int rn = tid >> 2, cs = (tid & 3) * 128;
    const int z = blockIdx.y;
    const int n = blockIdx.x * 64 + rn;
    const ushort_t* row = X + (long)z * CN_ + (long)n * C_DIM;
    const float* wz = w + (long)z * C_DIM;
    float s = 0.f;
    for (int i = 0; i < 128; i += 8) {
        uint4 u = *(const uint4*)&row[cs + i];
        const ushort_t* us = (const ushort_t*)&u;
#pragma unroll
        for (int k2 = 0; k2 < 8; ++k2) s += b2f(us[k2]) * wz[cs + i + k2];
    }
    s += __shfl_xor(s, 1); s += __shfl_xor(s, 2);
    if ((tid & 3) == 0) out[(long)z * N_DIM + n] = s;
}

// alpha[b,n] = softmax_n(logits[b,:]) * N
__global__ __launch_bounds__(256) void softmax_alpha(
    const float* __restrict__ logits, float* __restrict__ alpha)
{
    int b = blockIdx.x, tid = threadIdx.x;
    const float* L = logits + (long)b * N_DIM;
    float* A = alpha + (long)b * N_DIM;
    float lv[16];
    float mx = -3.4e38f;
#pragma unroll
    for (int i = 0; i < 4; i++) {
        float4 v = *(const float4*)&L[tid * 4 + i * 1024];
        lv[4 * i + 0] = v.x; lv[4 * i + 1] = v.y; lv[4 * i + 2] = v.z; lv[4 * i + 3] = v.w;
        mx = fmaxf(mx, fmaxf(fmaxf(v.x, v.y), fmaxf(v.z, v.w)));
    }
    __shared__ float red[8];
    float m = mx;
#pragma unroll
    for (int off = 32; off; off >>= 1) m = fmaxf(m, __shfl_down(m, off, 64));
    int wid = tid >> 6, lane = tid & 63;
    if (lane == 0) red[wid] = m;
    __syncthreads();
    m = fmaxf(fmaxf(red[0], red[1]), fmaxf(red[2], red[3]));
    float e[16], s = 0.f;
#pragma unroll
    for (int i = 0; i < 16; i++) { e[i] = expf(lv[i] - m); s += e[i]; }
#pragma unroll
    for (int off = 32; off; off >>= 1) s += __shfl_down(s, off, 64);
    if (lane == 0) red[4 + wid] = s;
    __syncthreads();
    float S = red[4] + red[5] + red[6] + red[7];
    float sc = 4096.f / S;
#pragma unroll
    for (int i = 0; i < 4; i++)
        *(float4*)&A[tid * 4 + i * 1024] =
            make_float4(e[4 * i] * sc, e[4 * i + 1] * sc, e[4 * i + 2] * sc, e[4 * i + 3] * sc);
}

// row LayerNorm over c (512) per (z,n); optional relu; out bf16 or f32
template<int RELU, int OBF>
__global__ __launch_bounds__(256) void ln_row(
    const float* __restrict__ in, const float* __restrict__ g,
    const float* __restrict__ bt, void* __restrict__ outv)
{
    const int tid = threadIdx.x;
    const int r = tid >> 3, cs = (tid & 7) * 64;
    const long base = (((long)blockIdx.y * N_DIM) + blockIdx.x * 32 + r) * C_DIM + cs;
    const float* I = in + base;
    float4 v[16];
    float s = 0.f, s2 = 0.f;
#pragma unroll
    for (int i = 0; i < 16; ++i) {
        v[i] = *(const float4*)&I[i * 4];
        s += v[i].x + v[i].y + v[i].z + v[i].w;
        s2 += v[i].x * v[i].x + v[i].y * v[i].y + v[i].z * v[i].z + v[i].w * v[i].w;
    }
#pragma unroll
    for (int off = 1; off < 8; off <<= 1) { s += __shfl_xor(s, off); s2 += __shfl_xor(s2, off); }
    const float mean = s * (1.f / 512.f);
    const float var = s2 * (1.f / 512.f) - mean * mean;
    const float rs = rsqrtf(var + 1e-6f);
#pragma unroll
    for (int i = 0; i < 16; ++i) {
        float4 gv = *(const float4*)&g[cs + i * 4];
        float4 bv = *(const float4*)&bt[cs + i * 4];
        float o[4];
        o[0] = (v[i].x - mean) * rs * gv.x + bv.x;
        o[1] = (v[i].y - mean) * rs * gv.y + bv.y;
        o[2] = (v[i].z - mean) * rs * gv.z + bv.z;
        o[3] = (v[i].w - mean) * rs * gv.w + bv.w;
        if (RELU) {
            o[0] = fmaxf(o[0], 0.f); o[1] = fmaxf(o[1], 0.f);
            o[2] = fmaxf(o[2], 0.f); o[3] = fmaxf(o[3], 0.f);
        }
        if (OBF) {
            union { ushort_t s4[4]; uint2 u; } p;
            p.s4[0] = f2b(o[0]); p.s4[1] = f2b(o[1]); p.s4[2] = f2b(o[2]); p.s4[3] = f2b(o[3]);
            *(uint2*)&((ushort_t*)outv)[base + i * 4] = p.u;
        } else {
            *(float4*)&((float*)outv)[base + i * 4] = make_float4(o[0], o[1], o[2], o[3]);
        }
    }
}

extern "C" void kernel_launch(void* const* d_in, const int* in_sizes, int n_in,
                              void* d_out, int out_size, void* d_ws, size_t ws_size,
                              hipStream_t stream)
{
    const float* x     = (const float*)d_in[0];
    const float* Wq    = (const float*)d_in[1];
    const float* Wk    = (const float*)d_in[2];
    const float* Wv    = (const float*)d_in[3];
    const float* Wphi  = (const float*)d_in[4];
    const float* ln1_w = (const float*)d_in[5];
    const float* ln1_b = (const float*)d_in[6];
    const float* fc1_w = (const float*)d_in[7];
    const float* fc1_bias = (const float*)d_in[8];
    const float* fc2_w = (const float*)d_in[9];
    const float* fc2_bias = (const float*)d_in[10];
    const float* ln2_w = (const float*)d_in[11];
    const float* ln2_b = (const float*)d_in[12];
    float* out = (float*)d_out;

    float* ws = (float*)d_ws;
    const long CN = CN_;
    // region map (float units); lifetimes are stream-sequential:
    ushort_t* xTfirst = (ushort_t*)ws;                 // [0,2CN)
    ushort_t* tln     = (ushort_t*)ws;
    ushort_t* xTc  = (ushort_t*)(ws + 2 * CN);         // [2CN,4CN)
    ushort_t* hbuf = (ushort_t*)(ws + 2 * CN);
    ushort_t* k0b = (ushort_t*)(ws + 4 * CN);          // [4CN,6CN)
    ushort_t* v0b = (ushort_t*)(ws + 6 * CN);          // [6CN,8CN)
    float* pre = ws + 4 * CN;                          // stage3 reuse
    float* tmp = ws + 4 * CN;
    ushort_t* khat = (ushort_t*)(ws + 8 * CN);         // [8CN,10CN) stage1
    ushort_t* q4   = (ushort_t*)(ws + 8 * CN);         // stage2 reuse
    ushort_t* v0c  = (ushort_t*)(ws + 10 * CN);        // [10CN,12CN) stage1
    ushort_t* phi4 = (ushort_t*)(ws + 10 * CN);        // stage2 reuse
    float* ubuf = ws + 8 * CN;                         // stage3 reuse
    float* ybar = ws + 12 * CN;                        // [12CN,13CN)
    float* kvb  = ws + 13 * CN;                        // 1M floats
    ushort_t* kvT = (ushort_t*)(ws + 13 * CN + 1048576);   // 1M bf16
    float* wb = ws + 13 * CN + 1048576 + 524288;
    ushort_t* Wk_b   = (ushort_t*)(wb);
    ushort_t* Wq_b   = (ushort_t*)(wb + 32768);
    ushort_t* Wv_b   = (ushort_t*)(wb + 65536);
    ushort_t* Wphi_b = (ushort_t*)(wb + 196608);
    ushort_t* fc1_b16 = (ushort_t*)(wb + 327680);
    ushort_t* fc2_b16 = (ushort_t*)(wb + 851968);
    float* part   = wb + 1376256;                      // 65536 floats (32 slices)
    float* Qg     = wb + 1441792;
    float* ksum   = wb + 1443840;
    float* logits = wb + 1445888;
    float* alpha  = wb + 1462272;
    float* den4   = wb + 1478656;

    dim3 blk(256);

    // weights -> bf16
    cvt_f2b<<<64, blk, 0, stream>>>(Wk, Wk_b, 65536);
    cvt_f2b<<<64, blk, 0, stream>>>(Wq, Wq_b, 65536);
    cvt_f2b<<<256, blk, 0, stream>>>(Wv, Wv_b, 262144);
    cvt_f2b<<<256, blk, 0, stream>>>(Wphi, Wphi_b, 262144);
    cvt_f2b<<<1024, blk, 0, stream>>>(fc1_w, fc1_b16, 1048576);
    cvt_f2b<<<1024, blk, 0, stream>>>(fc2_w, fc2_b16, 1048576);
    hipMemsetAsync(kvb, 0, 1048576 * sizeof(float), stream);

    // xT for first 4 batches (residual + phi_first source)
    transpose_f2b<<<dim3(64, 8, 4), blk, 0, stream>>>(x, xTfirst, 512, 4096, CN, CN);

    // stage 1: k0, v0, reductions, alpha, ksum, kv (MFMA path)
    mfma_gemm<EPI_PHI, true, true><<<dim3(4, 64, 4), blk, 0, stream>>>(
        Wk_b, xTfirst, k0b, nullptr, nullptr, nullptr, 128, 512, 512, CN, CN, 0);
    mfma_gemm<EPI_NONE, false, true><<<dim3(4, 64, 4), blk, 0, stream>>>(
        Wv_b, xTfirst, v0b, nullptr, nullptr, nullptr, 512, 512, 512, CN, CN, 0);
    colreduce_part<<<dim3(32, 4), blk, 0, stream>>>(k0b, nullptr, part);
    colreduce_fin<<<4, blk, 0, stream>>>(part, Qg, 1.f / 4096.f);
    dot_rows<<<dim3(64, 4), blk, 0, stream>>>(k0b, Qg, logits);
    softmax_alpha<<<4, blk, 0, stream>>>(logits, alpha);
    colreduce_part<<<dim3(32, 4), blk, 0, stream>>>(k0b, alpha, part);
    colreduce_fin<<<4, blk, 0, stream>>>(part, ksum, 1.f);
    transpose_b2b<1><<<dim3(64, 8, 4), blk, 0, stream>>>(k0b, khat, alpha);
    transpose_b2b<0><<<dim3(64, 8, 4), blk, 0, stream>>>(v0b, v0c, nullptr);
    kv_mfma<<<dim3(4, 8, 16), blk, 0, stream>>>(v0c, khat, kvb);
    cvt_scale<<<1024, blk, 0, stream>>>(kvb, kvT);

    // stage 2: rest in 3 chunks of 4 (b = mm since chunks are 4-aligned)
    for (int ch = 0; ch < 3; ++ch) {
        const float* xr = x + (long)(4 + 4 * ch) * CN;
        transpose_f2b<<<dim3(64, 8, 4), blk, 0, stream>>>(xr, xTc, 512, 4096, CN, CN);
        mfma_gemm<EPI_PHI, true, true><<<dim3(4, 64, 4), blk, 0, stream>>>(
            Wq_b, xTc, q4, nullptr, nullptr, nullptr, 128, 512, 512, CN, CN, 0);
        mfma_gemm<EPI_NONE, false, true><<<dim3(4, 64, 4), blk, 0, stream>>>(
            Wphi_b, xTc, phi4, nullptr, nullptr, nullptr, 512, 512, 512, CN, CN, 0);
        dot_rows<<<dim3(64, 4), blk, 0, stream>>>(q4, ksum, den4);
        ybar_mfma<<<dim3(4, 64), blk, 0, stream>>>(q4, kvT, phi4, den4, ybar, ch > 0);
    }

    // stage 3: pre = firstT + ybar*phiF; LN1; MLP; LN2+relu; transpose out
    mfma_gemm<EPI_PRE, false, false><<<dim3(4, 64, 4), blk, 0, stream>>>(
        Wphi_b, xTfirst, pre, nullptr, xTfirst, ybar, 512, 512, 512, CN, CN, CN);
    ln_row<0, 1><<<dim3(128, 4), blk, 0, stream>>>(pre, ln1_w, ln1_b, tln);
    for (int b = 0; b < 4; ++b) {
        mfma_gemm<EPI_RELU_BIAS, false, true><<<dim3(16, 64, 1), blk, 0, stream>>>(
            fc1_b16, tln + (long)b * CN, hbuf, fc1_bias, nullptr, nullptr,
            512, 2048, 512, 0, 0, 0);
        mfma_gemm<EPI_RES_BIAS, false, false><<<dim3(4, 64, 1), blk, 0, stream>>>(
            fc2_b16, hbuf, ubuf + (long)b * CN, fc2_bias, tln + (long)b * CN, nullptr,
            2048, 512, 2048, 0, 0, 0);
    }
    ln_row<1, 0><<<dim3(128, 4), blk, 0, stream>>>(ubuf, ln2_w, ln2_b, tmp);
    transpose_ff<<<dim3(8, 64, 4), blk, 0, stream>>>(tmp, out, 4096, 512, CN, CN);

    // passthrough: out[4:] = rest
    hipMemcpyAsync(out + 4 * CN, x + 4 * CN, 12 * CN * sizeof(float),
                   hipMemcpyDeviceToDevice, stream);
}

// Round 6
// 698.222 us; speedup vs baseline: 3.4722x; 1.1474x over previous
//
#include <hip/hip_runtime.h>

#define N_DIM 4096
#define C_DIM 512
#define CN_ ((long)C_DIM * (long)N_DIM)   // 2,097,152

typedef unsigned short ushort_t;
typedef __attribute__((ext_vector_type(8))) short bf16x8;
typedef __attribute__((ext_vector_type(4))) float f32x4;

__device__ __forceinline__ ushort_t f2b(float f) {
    unsigned u = __builtin_bit_cast(unsigned, f);
    u += 0x7fffu + ((u >> 16) & 1u);
    return (ushort_t)(u >> 16);
}
__device__ __forceinline__ float b2f(ushort_t s) {
    return __builtin_bit_cast(float, (unsigned)s << 16);
}

enum { EPI_NONE = 0, EPI_PHI = 1, EPI_RELU_BIAS = 2, EPI_RES_BIAS = 3, EPI_PRE = 4 };

// ---------------------------------------------------------------------------
// bf16 MFMA GEMM: OUT[z][n][o] = epi( sum_k A[z][n][k] * W[o][k] )
// Tile: 128 n x 128 o, BK=32, 4 waves (2x2), wave = 64n x 64o = 4x4 frags.
// ---------------------------------------------------------------------------
template<int EPI, bool GROUPED, bool OBF>
__global__ __launch_bounds__(256) void mfma_gemm(
    const ushort_t* __restrict__ Wb, const ushort_t* __restrict__ A,
    void* __restrict__ OUTV, const float* __restrict__ bias,
    const ushort_t* __restrict__ auxb, const float* __restrict__ auxf,
    int K, int O, int a_rstride, long a_zstride, long o_zstride, long auxb_zstride)
{
    __shared__ ushort_t Als[128][40];
    __shared__ ushort_t Bls[128][40];
    const int tid = threadIdx.x;
    const int o0 = blockIdx.x * 128;
    const int n0 = blockIdx.y * 128;
    const int z = blockIdx.z;
    const ushort_t* Az = A + (long)z * a_zstride;
    const ushort_t* Wp = Wb;
    int kbase = 0, obase = o0;
    if (GROUPED) { int g = o0 >> 7; Wp = Wb + (long)g * (128 * 128); kbase = g << 7; obase = 0; }

    const int sr = tid >> 1, ss = (tid & 1) * 16;   // stage: row, k-offset (2 uint4 each)
    const int w = tid >> 6, l = tid & 63;
    const int wr = (w >> 1) * 64, wc = (w & 1) * 64;
    const int fr = l & 15, ks = l >> 4;

    f32x4 acc[4][4];
#pragma unroll
    for (int m = 0; m < 4; ++m)
#pragma unroll
        for (int nf = 0; nf < 4; ++nf) acc[m][nf] = f32x4{0.f, 0.f, 0.f, 0.f};

    const ushort_t* aptr = Az + (long)(n0 + sr) * a_rstride + kbase + ss;
    const ushort_t* bptr = Wp + (long)(obase + sr) * K + ss;

    for (int kk = 0; kk < K; kk += 32) {
        uint4 av0 = *(const uint4*)(aptr + kk);
        uint4 av1 = *(const uint4*)(aptr + kk + 8);
        uint4 bv0 = *(const uint4*)(bptr + kk);
        uint4 bv1 = *(const uint4*)(bptr + kk + 8);
        __syncthreads();
        *(uint4*)&Als[sr][ss] = av0;
        *(uint4*)&Als[sr][ss + 8] = av1;
        *(uint4*)&Bls[sr][ss] = bv0;
        *(uint4*)&Bls[sr][ss + 8] = bv1;
        __syncthreads();
        bf16x8 af[4], bfv[4];
#pragma unroll
        for (int m = 0; m < 4; ++m)
            af[m] = *(const bf16x8*)&Als[wr + m * 16 + fr][ks * 8];
#pragma unroll
        for (int nf = 0; nf < 4; ++nf)
            bfv[nf] = *(const bf16x8*)&Bls[wc + nf * 16 + fr][ks * 8];
#pragma unroll
        for (int m = 0; m < 4; ++m)
#pragma unroll
            for (int nf = 0; nf < 4; ++nf)
                acc[m][nf] = __builtin_amdgcn_mfma_f32_16x16x32_bf16(
                    af[m], bfv[nf], acc[m][nf], 0, 0, 0);
    }

#pragma unroll
    for (int m = 0; m < 4; ++m) {
#pragma unroll
        for (int nf = 0; nf < 4; ++nf) {
            const int oo = o0 + wc + nf * 16 + fr;
            float bval = 0.f;
            if (EPI == EPI_RELU_BIAS || EPI == EPI_RES_BIAS) bval = bias[oo];
#pragma unroll
            for (int j = 0; j < 4; ++j) {
                const int nn = n0 + wr + m * 16 + ks * 4 + j;
                const long ridx = (long)nn * O + oo;
                float v = acc[m][nf][j];
                if (EPI == EPI_PHI)            v = fmaxf(v, 0.f) + 1.f;
                else if (EPI == EPI_RELU_BIAS) v = fmaxf(v + bval, 0.f);
                else if (EPI == EPI_RES_BIAS)  v = v + bval + b2f(auxb[(long)z * auxb_zstride + ridx]);
                else if (EPI == EPI_PRE)       v = b2f(auxb[(long)z * auxb_zstride + ridx]) + auxf[ridx] * v;
                if (OBF) ((ushort_t*)OUTV)[(long)z * o_zstride + ridx] = f2b(v);
                else     ((float*)OUTV)[(long)z * o_zstride + ridx] = v;
            }
        }
    }
}

// ---------------------------------------------------------------------------
// kv NT-MFMA: kvb[b][d][c] += sum_{n in chunk} v0c[b][d][n] * khat[b][c][n]
// ---------------------------------------------------------------------------
__global__ __launch_bounds__(256) void kv_mfma(
    const ushort_t* __restrict__ v0c, const ushort_t* __restrict__ khat,
    float* __restrict__ kvb)
{
    __shared__ ushort_t Als[64][40];
    __shared__ ushort_t Bls[128][40];
    const int tid = threadIdx.x;
    const int c0 = blockIdx.x * 128;
    const int d0 = blockIdx.y * 64;
    const int b = blockIdx.z >> 2, nch = blockIdx.z & 3;
    const ushort_t* Ab = v0c + (long)b * CN_;
    const ushort_t* Bb = khat + (long)b * CN_;
    const int ar = tid >> 2, as = (tid & 3) * 8;
    const int br = tid >> 1, bs = (tid & 1) * 16;
    const int w = tid >> 6, l = tid & 63;
    const int wr = (w >> 1) * 32, wc = (w & 1) * 64;
    const int fr = l & 15, ks = l >> 4;

    f32x4 acc[2][4];
#pragma unroll
    for (int m = 0; m < 2; ++m)
#pragma unroll
        for (int nf = 0; nf < 4; ++nf) acc[m][nf] = f32x4{0.f, 0.f, 0.f, 0.f};

    const ushort_t* aptr = Ab + (long)(d0 + ar) * N_DIM + nch * 1024 + as;
    const ushort_t* bptr = Bb + (long)(c0 + br) * N_DIM + nch * 1024 + bs;

    for (int kk = 0; kk < 1024; kk += 32) {
        uint4 av = *(const uint4*)(aptr + kk);
        uint4 bv0 = *(const uint4*)(bptr + kk);
        uint4 bv1 = *(const uint4*)(bptr + kk + 8);
        __syncthreads();
        *(uint4*)&Als[ar][as] = av;
        *(uint4*)&Bls[br][bs] = bv0;
        *(uint4*)&Bls[br][bs + 8] = bv1;
        __syncthreads();
        bf16x8 af[2], bfv[4];
#pragma unroll
        for (int m = 0; m < 2; ++m)
            af[m] = *(const bf16x8*)&Als[wr + m * 16 + fr][ks * 8];
#pragma unroll
        for (int nf = 0; nf < 4; ++nf)
            bfv[nf] = *(const bf16x8*)&Bls[wc + nf * 16 + fr][ks * 8];
#pragma unroll
        for (int m = 0; m < 2; ++m)
#pragma unroll
            for (int nf = 0; nf < 4; ++nf)
                acc[m][nf] = __builtin_amdgcn_mfma_f32_16x16x32_bf16(
                    af[m], bfv[nf], acc[m][nf], 0, 0, 0);
    }

    float* KV = kvb + (long)b * 262144;
#pragma unroll
    for (int m = 0; m < 2; ++m)
#pragma unroll
        for (int nf = 0; nf < 4; ++nf) {
            const int cc = c0 + wc + nf * 16 + fr;
#pragma unroll
            for (int j = 0; j < 4; ++j) {
                const int dd = d0 + wr + m * 16 + ks * 4 + j;
                atomicAdd(&KV[(long)dd * 512 + cc], acc[m][nf][j]);
            }
        }
}

// kvT[i] = f2b(kvb[i] * 1/sqrt(512))
__global__ __launch_bounds__(256) void cvt_scale(
    const float* __restrict__ in, ushort_t* __restrict__ out)
{
    const float s = 0.044194173824159216f;
    int i = (blockIdx.x * 256 + threadIdx.x) * 4;
    float4 v = *(const float4*)&in[i];
    union { ushort_t sh[4]; uint2 u; } p;
    p.sh[0] = f2b(v.x * s); p.sh[1] = f2b(v.y * s);
    p.sh[2] = f2b(v.z * s); p.sh[3] = f2b(v.w * s);
    *(uint2*)&out[i] = p.u;
}

// bf16 [z][4096][512] -> bf16 [z][512][4096]; ALPHA: out *= alpha[z][n]
template<int ALPHA>
__global__ __launch_bounds__(256) void transpose_b2b(
    const ushort_t* __restrict__ in, ushort_t* __restrict__ out,
    const float* __restrict__ alpha)
{
    __shared__ ushort_t t[64][72];
    const int tid = threadIdx.x;
    const int n0 = blockIdx.x * 64, c0 = blockIdx.y * 64, z = blockIdx.z;
    const ushort_t* I = in + (long)z * CN_;
    ushort_t* O = out + (long)z * CN_;
    const int r = tid >> 2, s8 = (tid & 3) * 16;
    uint4 u0 = *(const uint4*)&I[(long)(n0 + r) * 512 + c0 + s8];
    uint4 u1 = *(const uint4*)&I[(long)(n0 + r) * 512 + c0 + s8 + 8];
    *(uint4*)&t[r][s8] = u0;
    *(uint4*)&t[r][s8 + 8] = u1;
    __syncthreads();
    union { ushort_t sh[16]; uint4 u[2]; } p;
#pragma unroll
    for (int i = 0; i < 16; ++i) {
        ushort_t v = t[s8 + i][r];
        if (ALPHA) v = f2b(b2f(v) * alpha[(long)z * N_DIM + n0 + s8 + i]);
        p.sh[i] = v;
    }
    uint4* dst = (uint4*)&O[(long)(c0 + r) * N_DIM + n0 + s8];
    dst[0] = p.u[0]; dst[1] = p.u[1];
}

// ---------------------------------------------------------------------------
// ybar[n][d] (+)= (1/12) sum_mm (sum_c q4[mm][n][c]*kvT[mm][d][c]) * z * phi4
// ---------------------------------------------------------------------------
__global__ __launch_bounds__(256) void ybar_mfma(
    const ushort_t* __restrict__ q4, const ushort_t* __restrict__ kvT,
    const ushort_t* __restrict__ phi4, const float* __restrict__ den4,
    float* __restrict__ ybar, int accflag)
{
    __shared__ ushort_t Als[64][40];
    __shared__ ushort_t Bls[128][40];
    const int tid = threadIdx.x;
    const int o0 = blockIdx.x * 128;
    const int n0 = blockIdx.y * 64;
    const int ar = tid >> 2, as = (tid & 3) * 8;
    const int br = tid >> 1, bs = (tid & 1) * 16;
    const int w = tid >> 6, l = tid & 63;
    const int wr = (w >> 1) * 32, wc = (w & 1) * 64;
    const int fr = l & 15, ks = l >> 4;

    f32x4 yt[2][4];
#pragma unroll
    for (int m = 0; m < 2; ++m)
#pragma unroll
        for (int nf = 0; nf < 4; ++nf) yt[m][nf] = f32x4{0.f, 0.f, 0.f, 0.f};

    for (int mm = 0; mm < 4; ++mm) {
        const ushort_t* aptr = q4 + (long)mm * CN_ + (long)(n0 + ar) * 512 + as;
        const ushort_t* bptr = kvT + (long)mm * (512 * 512) + (long)(o0 + br) * 512 + bs;
        f32x4 acc[2][4];
#pragma unroll
        for (int m = 0; m < 2; ++m)
#pragma unroll
            for (int nf = 0; nf < 4; ++nf) acc[m][nf] = f32x4{0.f, 0.f, 0.f, 0.f};

        for (int kk = 0; kk < 512; kk += 32) {
            uint4 av = *(const uint4*)(aptr + kk);
            uint4 bv0 = *(const uint4*)(bptr + kk);
            uint4 bv1 = *(const uint4*)(bptr + kk + 8);
            __syncthreads();
            *(uint4*)&Als[ar][as] = av;
            *(uint4*)&Bls[br][bs] = bv0;
            *(uint4*)&Bls[br][bs + 8] = bv1;
            __syncthreads();
            bf16x8 af[2], bfv[4];
#pragma unroll
            for (int m = 0; m < 2; ++m)
                af[m] = *(const bf16x8*)&Als[wr + m * 16 + fr][ks * 8];
#pragma unroll
            for (int nf = 0; nf < 4; ++nf)
                bfv[nf] = *(const bf16x8*)&Bls[wc + nf * 16 + fr][ks * 8];
#pragma unroll
            for (int m = 0; m < 2; ++m)
#pragma unroll
                for (int nf = 0; nf < 4; ++nf)
                    acc[m][nf] = __builtin_amdgcn_mfma_f32_16x16x32_bf16(
                        af[m], bfv[nf], acc[m][nf], 0, 0, 0);
        }
        const ushort_t* P = phi4 + (long)mm * CN_;
        const float* D = den4 + (long)mm * N_DIM;
        float zr[2][4];
#pragma unroll
        for (int m = 0; m < 2; ++m)
#pragma unroll
            for (int j = 0; j < 4; ++j)
                zr[m][j] = 1.f / (D[n0 + wr + m * 16 + ks * 4 + j] + 1e-6f);
#pragma unroll
        for (int m = 0; m < 2; ++m)
#pragma unroll
            for (int nf = 0; nf < 4; ++nf) {
                const int oo = o0 + wc + nf * 16 + fr;
#pragma unroll
                for (int j = 0; j < 4; ++j) {
                    const int nn = n0 + wr + m * 16 + ks * 4 + j;
                    yt[m][nf][j] += acc[m][nf][j] * zr[m][j] * b2f(P[(long)nn * 512 + oo]);
                }
            }
        __syncthreads();
    }
#pragma unroll
    for (int m = 0; m < 2; ++m)
#pragma unroll
        for (int nf = 0; nf < 4; ++nf) {
            const int oo = o0 + wc + nf * 16 + fr;
#pragma unroll
            for (int j = 0; j < 4; ++j) {
                const int nn = n0 + wr + m * 16 + ks * 4 + j;
                const long idx = (long)nn * 512 + oo;
                float r = yt[m][nf][j] * (1.f / 12.f);
                if (accflag) r += ybar[idx];
                ybar[idx] = r;
            }
        }
}

// fp32 -> bf16 elementwise
__global__ __launch_bounds__(256) void cvt_f2b(
    const float* __restrict__ in, ushort_t* __restrict__ out, int n)
{
    int i = (blockIdx.x * 256 + threadIdx.x) * 4;
    if (i >= n) return;
    float4 v = *(const float4*)&in[i];
    union { ushort_t s[4]; uint2 u; } p;
    p.s[0] = f2b(v.x); p.s[1] = f2b(v.y); p.s[2] = f2b(v.z); p.s[3] = f2b(v.w);
    *(uint2*)&out[i] = p.u;
}

// transpose fp32 [z][rows][cols] -> bf16 [z][cols][rows]
__global__ __launch_bounds__(256) void transpose_f2b(
    const float* __restrict__ in, ushort_t* __restrict__ out,
    int rows, int cols, long in_z, long out_z)
{
    __shared__ float t[64][65];
    const int tid = threadIdx.x;
    const int n0 = blockIdx.x * 64, c0 = blockIdx.y * 64;
    const float* I = in + (long)blockIdx.z * in_z;
    ushort_t* Ot = out + (long)blockIdx.z * out_z;
    const int r = tid >> 2, s4 = (tid & 3) * 16;
#pragma unroll
    for (int i = 0; i < 16; i += 4) {
        float4 v = *(const float4*)&I[(long)(c0 + r) * cols + n0 + s4 + i];
        t[r][s4 + i] = v.x; t[r][s4 + i + 1] = v.y;
        t[r][s4 + i + 2] = v.z; t[r][s4 + i + 3] = v.w;
    }
    __syncthreads();
    union { ushort_t s[16]; uint4 u[2]; } pk;
#pragma unroll
    for (int i = 0; i < 16; ++i) pk.s[i] = f2b(t[s4 + i][r]);
    uint4* dst = (uint4*)&Ot[(long)(n0 + r) * rows + c0 + s4];
    dst[0] = pk.u[0]; dst[1] = pk.u[1];
}

// transpose fp32 [z][rows][cols] -> fp32 [z][cols][rows]
__global__ __launch_bounds__(256) void transpose_ff(
    const float* __restrict__ in, float* __restrict__ out,
    int rows, int cols, long in_z, long out_z)
{
    __shared__ float t[64][65];
    const int tid = threadIdx.x;
    const int n0 = blockIdx.x * 64, c0 = blockIdx.y * 64;
    const float* I = in + (long)blockIdx.z * in_z;
    float* Ot = out + (long)blockIdx.z * out_z;
    const int r = tid >> 2, s4 = (tid & 3) * 16;
#pragma unroll
    for (int i = 0; i < 16; i += 4) {
        float4 v = *(const float4*)&I[(long)(c0 + r) * cols + n0 + s4 + i];
        t[r][s4 + i] = v.x; t[r][s4 + i + 1] = v.y;
        t[r][s4 + i + 2] = v.z; t[r][s4 + i + 3] = v.w;
    }
    __syncthreads();
#pragma unroll
    for (int i = 0; i < 16; i += 4) {
        float4 o = make_float4(t[s4 + i][r], t[s4 + i + 1][r], t[s4 + i + 2][r], t[s4 + i + 3][r]);
        *(float4*)&Ot[(long)(n0 + r) * rows + c0 + s4 + i] = o;
    }
}

// part[ns][b][c] = sum_{n in 128-row chunk ns} X[b][n][c] * (wgt?[b][n])
__global__ __launch_bounds__(256) void colreduce_part(
    const ushort_t* __restrict__ X, const float* __restrict__ wgt,
    float* __restrict__ part)
{
    const int ns = blockIdx.x, b = blockIdx.y;
    const int tid = threadIdx.x;
    const int w = tid >> 6, l = tid & 63;
    const int c8 = l * 8;
    const ushort_t* Xb = X + (long)b * CN_;
    float acc[8] = {0.f, 0.f, 0.f, 0.f, 0.f, 0.f, 0.f, 0.f};
    for (int r = w; r < 128; r += 4) {
        const int n = ns * 128 + r;
        uint4 u = *(const uint4*)&Xb[(long)n * C_DIM + c8];
        const ushort_t* us = (const ushort_t*)&u;
        const float wv = wgt ? wgt[(long)b * N_DIM + n] : 1.f;
#pragma unroll
        for (int i = 0; i < 8; ++i) acc[i] += b2f(us[i]) * wv;
    }
    __shared__ float red[4][512];
#pragma unroll
    for (int i = 0; i < 8; ++i) red[w][c8 + i] = acc[i];
    __syncthreads();
    for (int c = tid; c < 512; c += 256) {
        part[((long)ns * 4 + b) * C_DIM + c] =
            red[0][c] + red[1][c] + red[2][c] + red[3][c];
    }
}

__global__ __launch_bounds__(256) void colreduce_fin(
    const float* __restrict__ part, float* __restrict__ out, float scale)
{
    int b = blockIdx.x;
    for (int c = threadIdx.x; c < 512; c += 256) {
        float s = 0.f;
        for (int ns = 0; ns < 32; ++ns) s += part[((long)ns * 4 + b) * C_DIM + c];
        out[b * C_DIM + c] = s * scale;
    }
}

// out[z][n] = sum_c X[z][n][c] * w[z][c]
__global__ __launch_bounds__(256) void dot_rows(
    const ushort_t* __restrict__ X, const float* __restrict__ w,
    float* __restrict__ out)
{
    const int tid = threadIdx.x;
    const int rn = tid >> 2, cs = (tid & 3) * 128;
    const int z = blockIdx.y;
    const int n = blockIdx.x * 64 + rn;
    const ushort_t* row = X + (long)z * CN_ + (long)n * C_DIM;
    const float* wz = w + (long)z * C_DIM;
    float s = 0.f;
    for (int i = 0; i < 128; i += 8) {
        uint4 u = *(const uint4*)&row[cs + i];
        const ushort_t* us = (const ushort_t*)&u;
#pragma unroll
        for (int k2 = 0; k2 < 8; ++k2) s += b2f(us[k2]) * wz[cs + i + k2];
    }
    s += __shfl_xor(s, 1); s += __shfl_xor(s, 2);
    if ((tid & 3) == 0) out[(long)z * N_DIM + n] = s;
}

// alpha[b,n] = softmax_n(logits[b,:]) * N
__global__ __launch_bounds__(256) void softmax_alpha(
    const float* __restrict__ logits, float* __restrict__ alpha)
{
    int b = blockIdx.x, tid = threadIdx.x;
    const float* L = logits + (long)b * N_DIM;
    float* A = alpha + (long)b * N_DIM;
    float lv[16];
    float mx = -3.4e38f;
#pragma unroll
    for (int i = 0; i < 4; i++) {
        float4 v = *(const float4*)&L[tid * 4 + i * 1024];
        lv[4 * i + 0] = v.x; lv[4 * i + 1] = v.y; lv[4 * i + 2] = v.z; lv[4 * i + 3] = v.w;
        mx = fmaxf(mx, fmaxf(fmaxf(v.x, v.y), fmaxf(v.z, v.w)));
    }
    __shared__ float red[8];
    float m = mx;
#pragma unroll
    for (int off = 32; off; off >>= 1) m = fmaxf(m, __shfl_down(m, off, 64));
    int wid = tid >> 6, lane = tid & 63;
    if (lane == 0) red[wid] = m;
    __syncthreads();
    m = fmaxf(fmaxf(red[0], red[1]), fmaxf(red[2], red[3]));
    float e[16], s = 0.f;
#pragma unroll
    for (int i = 0; i < 16; i++) { e[i] = expf(lv[i] - m); s += e[i]; }
#pragma unroll
    for (int off = 32; off; off >>= 1) s += __shfl_down(s, off, 64);
    if (lane == 0) red[4 + wid] = s;
    __syncthreads();
    float S = red[4] + red[5] + red[6] + red[7];
    float sc = 4096.f / S;
#pragma unroll
    for (int i = 0; i < 4; i++)
        *(float4*)&A[tid * 4 + i * 1024] =
            make_float4(e[4 * i] * sc, e[4 * i + 1] * sc, e[4 * i + 2] * sc, e[4 * i + 3] * sc);
}

// row LayerNorm over c (512) per (z,n); optional relu; out bf16 or f32
template<int RELU, int OBF>
__global__ __launch_bounds__(256) void ln_row(
    const float* __restrict__ in, const float* __restrict__ g,
    const float* __restrict__ bt, void* __restrict__ outv)
{
    const int tid = threadIdx.x;
    const int r = tid >> 3, cs = (tid & 7) * 64;
    const long base = (((long)blockIdx.y * N_DIM) + blockIdx.x * 32 + r) * C_DIM + cs;
    const float* I = in + base;
    float4 v[16];
    float s = 0.f, s2 = 0.f;
#pragma unroll
    for (int i = 0; i < 16; ++i) {
        v[i] = *(const float4*)&I[i * 4];
        s += v[i].x + v[i].y + v[i].z + v[i].w;
        s2 += v[i].x * v[i].x + v[i].y * v[i].y + v[i].z * v[i].z + v[i].w * v[i].w;
    }
#pragma unroll
    for (int off = 1; off < 8; off <<= 1) { s += __shfl_xor(s, off); s2 += __shfl_xor(s2, off); }
    const float mean = s * (1.f / 512.f);
    const float var = s2 * (1.f / 512.f) - mean * mean;
    const float rs = rsqrtf(var + 1e-6f);
#pragma unroll
    for (int i = 0; i < 16; ++i) {
        float4 gv = *(const float4*)&g[cs + i * 4];
        float4 bv = *(const float4*)&bt[cs + i * 4];
        float o[4];
        o[0] = (v[i].x - mean) * rs * gv.x + bv.x;
        o[1] = (v[i].y - mean) * rs * gv.y + bv.y;
        o[2] = (v[i].z - mean) * rs * gv.z + bv.z;
        o[3] = (v[i].w - mean) * rs * gv.w + bv.w;
        if (RELU) {
            o[0] = fmaxf(o[0], 0.f); o[1] = fmaxf(o[1], 0.f);
            o[2] = fmaxf(o[2], 0.f); o[3] = fmaxf(o[3], 0.f);
        }
        if (OBF) {
            union { ushort_t s4[4]; uint2 u; } p;
            p.s4[0] = f2b(o[0]); p.s4[1] = f2b(o[1]); p.s4[2] = f2b(o[2]); p.s4[3] = f2b(o[3]);
            *(uint2*)&((ushort_t*)outv)[base + i * 4] = p.u;
        } else {
            *(float4*)&((float*)outv)[base + i * 4] = make_float4(o[0], o[1], o[2], o[3]);
        }
    }
}

extern "C" void kernel_launch(void* const* d_in, const int* in_sizes, int n_in,
                              void* d_out, int out_size, void* d_ws, size_t ws_size,
                              hipStream_t stream)
{
    const float* x     = (const float*)d_in[0];
    const float* Wq    = (const float*)d_in[1];
    const float* Wk    = (const float*)d_in[2];
    const float* Wv    = (const float*)d_in[3];
    const float* Wphi  = (const float*)d_in[4];
    const float* ln1_w = (const float*)d_in[5];
    const float* ln1_b = (const float*)d_in[6];
    const float* fc1_w = (const float*)d_in[7];
    const float* fc1_bias = (const float*)d_in[8];
    const float* fc2_w = (const float*)d_in[9];
    const float* fc2_bias = (const float*)d_in[10];
    const float* ln2_w = (const float*)d_in[11];
    const float* ln2_b = (const float*)d_in[12];
    float* out = (float*)d_out;

    float* ws = (float*)d_ws;
    const long CN = CN_;
    // region map (float units); lifetimes are stream-sequential:
    ushort_t* xTfirst = (ushort_t*)ws;                 // [0,2CN)
    ushort_t* tln     = (ushort_t*)ws;
    ushort_t* xTc  = (ushort_t*)(ws + 2 * CN);         // [2CN,4CN)
    ushort_t* k0b = (ushort_t*)(ws + 4 * CN);          // [4CN,6CN)
    ushort_t* v0b = (ushort_t*)(ws + 6 * CN);          // [6CN,8CN)
    float* pre = ws + 4 * CN;                          // stage3 reuse
    float* tmp = ws + 4 * CN;
    ushort_t* khat = (ushort_t*)(ws + 8 * CN);         // [8CN,10CN) stage1
    ushort_t* q4   = (ushort_t*)(ws + 8 * CN);         // stage2 reuse
    ushort_t* v0c  = (ushort_t*)(ws + 10 * CN);        // [10CN,12CN) stage1
    ushort_t* phi4 = (ushort_t*)(ws + 10 * CN);        // stage2 reuse
    float* ubuf = ws + 8 * CN;                         // stage3 reuse
    float* ybar = ws + 12 * CN;                        // [12CN,13CN)
    float* kvb  = ws + 13 * CN;                        // 1M floats
    ushort_t* kvT = (ushort_t*)(ws + 13 * CN + 1048576);   // 1M bf16
    float* wb = ws + 13 * CN + 1048576 + 524288;
    ushort_t* Wk_b   = (ushort_t*)(wb);
    ushort_t* Wq_b   = (ushort_t*)(wb + 32768);
    ushort_t* Wv_b   = (ushort_t*)(wb + 65536);
    ushort_t* Wphi_b = (ushort_t*)(wb + 196608);
    ushort_t* fc1_b16 = (ushort_t*)(wb + 327680);
    ushort_t* fc2_b16 = (ushort_t*)(wb + 851968);
    float* part   = wb + 1376256;                      // 65536 floats
    float* Qg     = wb + 1441792;
    float* ksum   = wb + 1443840;
    float* logits = wb + 1445888;
    float* alpha  = wb + 1462272;
    float* den4   = wb + 1478656;
    ushort_t* hbuf4 = (ushort_t*)(ws + 16 * CN);       // [16CN,24CN): 4 x 4096x2048 bf16

    dim3 blk(256);

    // weights -> bf16
    cvt_f2b<<<64, blk, 0, stream>>>(Wk, Wk_b, 65536);
    cvt_f2b<<<64, blk, 0, stream>>>(Wq, Wq_b, 65536);
    cvt_f2b<<<256, blk, 0, stream>>>(Wv, Wv_b, 262144);
    cvt_f2b<<<256, blk, 0, stream>>>(Wphi, Wphi_b, 262144);
    cvt_f2b<<<1024, blk, 0, stream>>>(fc1_w, fc1_b16, 1048576);
    cvt_f2b<<<1024, blk, 0, stream>>>(fc2_w, fc2_b16, 1048576);
    hipMemsetAsync(kvb, 0, 1048576 * sizeof(float), stream);

    // xT for first 4 batches (residual + phi_first source)
    transpose_f2b<<<dim3(64, 8, 4), blk, 0, stream>>>(x, xTfirst, 512, 4096, CN, CN);

    // stage 1: k0, v0, reductions, alpha, ksum, kv (MFMA path)
    mfma_gemm<EPI_PHI, true, true><<<dim3(4, 32, 4), blk, 0, stream>>>(
        Wk_b, xTfirst, k0b, nullptr, nullptr, nullptr, 128, 512, 512, CN, CN, 0);
    mfma_gemm<EPI_NONE, false, true><<<dim3(4, 32, 4), blk, 0, stream>>>(
        Wv_b, xTfirst, v0b, nullptr, nullptr, nullptr, 512, 512, 512, CN, CN, 0);
    colreduce_part<<<dim3(32, 4), blk, 0, stream>>>(k0b, nullptr, part);
    colreduce_fin<<<4, blk, 0, stream>>>(part, Qg, 1.f / 4096.f);
    dot_rows<<<dim3(64, 4), blk, 0, stream>>>(k0b, Qg, logits);
    softmax_alpha<<<4, blk, 0, stream>>>(logits, alpha);
    colreduce_part<<<dim3(32, 4), blk, 0, stream>>>(k0b, alpha, part);
    colreduce_fin<<<4, blk, 0, stream>>>(part, ksum, 1.f);
    transpose_b2b<1><<<dim3(64, 8, 4), blk, 0, stream>>>(k0b, khat, alpha);
    transpose_b2b<0><<<dim3(64, 8, 4), blk, 0, stream>>>(v0b, v0c, nullptr);
    kv_mfma<<<dim3(4, 8, 16), blk, 0, stream>>>(v0c, khat, kvb);
    cvt_scale<<<1024, blk, 0, stream>>>(kvb, kvT);

    // stage 2: rest in 3 chunks of 4 (b = mm since chunks are 4-aligned)
    for (int ch = 0; ch < 3; ++ch) {
        const float* xr = x + (long)(4 + 4 * ch) * CN;
        transpose_f2b<<<dim3(64, 8, 4), blk, 0, stream>>>(xr, xTc, 512, 4096, CN, CN);
        mfma_gemm<EPI_PHI, true, true><<<dim3(4, 32, 4), blk, 0, stream>>>(
            Wq_b, xTc, q4, nullptr, nullptr, nullptr, 128, 512, 512, CN, CN, 0);
        mfma_gemm<EPI_NONE, false, true><<<dim3(4, 32, 4), blk, 0, stream>>>(
            Wphi_b, xTc, phi4, nullptr, nullptr, nullptr, 512, 512, 512, CN, CN, 0);
        dot_rows<<<dim3(64, 4), blk, 0, stream>>>(q4, ksum, den4);
        ybar_mfma<<<dim3(4, 64), blk, 0, stream>>>(q4, kvT, phi4, den4, ybar, ch > 0);
    }

    // stage 3: pre = firstT + ybar*phiF; LN1; MLP (batched z=4); LN2+relu; transpose out
    mfma_gemm<EPI_PRE, false, false><<<dim3(4, 32, 4), blk, 0, stream>>>(
        Wphi_b, xTfirst, pre, nullptr, xTfirst, ybar, 512, 512, 512, CN, CN, CN);
    ln_row<0, 1><<<dim3(128, 4), blk, 0, stream>>>(pre, ln1_w, ln1_b, tln);
    mfma_gemm<EPI_RELU_BIAS, false, true><<<dim3(16, 32, 4), blk, 0, stream>>>(
        fc1_b16, tln, hbuf4, fc1_bias, nullptr, nullptr,
        512, 2048, 512, CN, 8388608, 0);
    mfma_gemm<EPI_RES_BIAS, false, false><<<dim3(4, 32, 4), blk, 0, stream>>>(
        fc2_b16, hbuf4, ubuf, fc2_bias, tln, nullptr,
        2048, 512, 2048, 8388608, CN, CN);
    ln_row<1, 0><<<dim3(128, 4), blk, 0, stream>>>(ubuf, ln2_w, ln2_b, tmp);
    transpose_ff<<<dim3(8, 64, 4), blk, 0, stream>>>(tmp, out, 4096, 512, CN, CN);

    // passthrough: out[4:] = rest
    hipMemcpyAsync(out + 4 * CN, x + 4 * CN, 12 * CN * sizeof(float),
                   hipMemcpyDeviceToDevice, stream);
}

// Round 7
// 690.454 us; speedup vs baseline: 3.5113x; 1.0112x over previous
//
#include <hip/hip_runtime.h>

#define N_DIM 4096
#define C_DIM 512
#define CN_ ((long)C_DIM * (long)N_DIM)   // 2,097,152

typedef unsigned short ushort_t;
typedef __attribute__((ext_vector_type(8))) short bf16x8;
typedef __attribute__((ext_vector_type(4))) float f32x4;

__device__ __forceinline__ ushort_t f2b(float f) {
    unsigned u = __builtin_bit_cast(unsigned, f);
    u += 0x7fffu + ((u >> 16) & 1u);
    return (ushort_t)(u >> 16);
}
__device__ __forceinline__ float b2f(ushort_t s) {
    return __builtin_bit_cast(float, (unsigned)s << 16);
}

enum { EPI_NONE = 0, EPI_PHI = 1, EPI_RELU_BIAS = 2, EPI_RES_BIAS = 3, EPI_PRE = 4 };

// ---------------------------------------------------------------------------
// bf16 MFMA GEMM: OUT[z][n][o] = epi( sum_k A[z][n][k] * W[o][k] )
// Tile: 128 n x 128 o, BK=32, 4 waves (2x2), wave = 64n x 64o = 4x4 frags.
// 1D grid with bijective XCD remap: xcd = L&7 owns all o-tiles of a
// contiguous 1/8 of (n,z) panels (A-panel fetched on exactly one XCD).
// LDS: unpadded [128][32] ushort rows (64B), granule XOR swizzle
// g' = g ^ ((row>>1)&3) -> conflict-free ds_read_b128 / ds_write_b128.
// ---------------------------------------------------------------------------
template<int EPI, bool GROUPED, bool OBF>
__global__ __launch_bounds__(256) void mfma_gemm(
    const ushort_t* __restrict__ Wb, const ushort_t* __restrict__ A,
    void* __restrict__ OUTV, const float* __restrict__ bias,
    const ushort_t* __restrict__ auxb, const float* __restrict__ auxf,
    int K, int O, int a_rstride, long a_zstride, long o_zstride, long auxb_zstride,
    int xt, int yt)
{
    __shared__ ushort_t Als[128 * 32];
    __shared__ ushort_t Bls[128 * 32];
    const int tid = threadIdx.x;

    // XCD-aware bijective remap (requires gridDim.x%8==0, (gridDim.x/8)%xt==0)
    const int L = blockIdx.x;
    const int gpx = (gridDim.x >> 3) / xt;     // (y,z)-groups per XCD
    const int xcd = L & 7;
    const int j = L >> 3;
    const int xtile = j % xt;
    const int g = xcd * gpx + j / xt;
    const int ytile = g % yt;
    const int z = g / yt;

    const int o0 = xtile * 128;
    const int n0 = ytile * 128;
    const ushort_t* Az = A + (long)z * a_zstride;
    const ushort_t* Wp = Wb;
    int kbase = 0, obase = o0;
    if (GROUPED) { int gg = o0 >> 7; Wp = Wb + (long)gg * (128 * 128); kbase = gg << 7; obase = 0; }

    const int sr = tid >> 1, p = tid & 1;      // stage: row, half (2x16B each)
    const int s_ = (sr >> 1) & 3;
    ushort_t* awr0 = &Als[sr * 32 + (((2 * p) ^ s_) << 3)];
    ushort_t* awr1 = &Als[sr * 32 + (((2 * p + 1) ^ s_) << 3)];
    ushort_t* bwr0 = &Bls[sr * 32 + (((2 * p) ^ s_) << 3)];
    ushort_t* bwr1 = &Bls[sr * 32 + (((2 * p + 1) ^ s_) << 3)];

    const int w = tid >> 6, l = tid & 63;
    const int wr = (w >> 1) * 64, wc = (w & 1) * 64;
    const int fr = l & 15, ks = l >> 4;
    const int rsw = (ks ^ ((fr >> 1) & 3)) << 3;   // swizzled granule offset (ushorts)

    f32x4 acc[4][4];
#pragma unroll
    for (int m = 0; m < 4; ++m)
#pragma unroll
        for (int nf = 0; nf < 4; ++nf) acc[m][nf] = f32x4{0.f, 0.f, 0.f, 0.f};

    const ushort_t* aptr = Az + (long)(n0 + sr) * a_rstride + kbase + p * 16;
    const ushort_t* bptr = Wp + (long)(obase + sr) * K + p * 16;

    for (int kk = 0; kk < K; kk += 32) {
        uint4 av0 = *(const uint4*)(aptr + kk);
        uint4 av1 = *(const uint4*)(aptr + kk + 8);
        uint4 bv0 = *(const uint4*)(bptr + kk);
        uint4 bv1 = *(const uint4*)(bptr + kk + 8);
        __syncthreads();
        *(uint4*)awr0 = av0;
        *(uint4*)awr1 = av1;
        *(uint4*)bwr0 = bv0;
        *(uint4*)bwr1 = bv1;
        __syncthreads();
        bf16x8 af[4], bfv[4];
#pragma unroll
        for (int m = 0; m < 4; ++m)
            af[m] = *(const bf16x8*)&Als[(wr + m * 16 + fr) * 32 + rsw];
#pragma unroll
        for (int nf = 0; nf < 4; ++nf)
            bfv[nf] = *(const bf16x8*)&Bls[(wc + nf * 16 + fr) * 32 + rsw];
#pragma unroll
        for (int m = 0; m < 4; ++m)
#pragma unroll
            for (int nf = 0; nf < 4; ++nf)
                acc[m][nf] = __builtin_amdgcn_mfma_f32_16x16x32_bf16(
                    af[m], bfv[nf], acc[m][nf], 0, 0, 0);
    }

#pragma unroll
    for (int m = 0; m < 4; ++m) {
#pragma unroll
        for (int nf = 0; nf < 4; ++nf) {
            const int oo = o0 + wc + nf * 16 + fr;
            float bval = 0.f;
            if (EPI == EPI_RELU_BIAS || EPI == EPI_RES_BIAS) bval = bias[oo];
#pragma unroll
            for (int j2 = 0; j2 < 4; ++j2) {
                const int nn = n0 + wr + m * 16 + ks * 4 + j2;
                const long ridx = (long)nn * O + oo;
                float v = acc[m][nf][j2];
                if (EPI == EPI_PHI)            v = fmaxf(v, 0.f) + 1.f;
                else if (EPI == EPI_RELU_BIAS) v = fmaxf(v + bval, 0.f);
                else if (EPI == EPI_RES_BIAS)  v = v + bval + b2f(auxb[(long)z * auxb_zstride + ridx]);
                else if (EPI == EPI_PRE)       v = b2f(auxb[(long)z * auxb_zstride + ridx]) + auxf[ridx] * v;
                if (OBF) ((ushort_t*)OUTV)[(long)z * o_zstride + ridx] = f2b(v);
                else     ((float*)OUTV)[(long)z * o_zstride + ridx] = v;
            }
        }
    }
}

// ---------------------------------------------------------------------------
// kv NT-MFMA: kvb[b][d][c] += sum_{n in chunk} v0c[b][d][n] * khat[b][c][n]
// ---------------------------------------------------------------------------
__global__ __launch_bounds__(256) void kv_mfma(
    const ushort_t* __restrict__ v0c, const ushort_t* __restrict__ khat,
    float* __restrict__ kvb)
{
    __shared__ ushort_t Als[64][40];
    __shared__ ushort_t Bls[128][40];
    const int tid = threadIdx.x;
    const int c0 = blockIdx.x * 128;
    const int d0 = blockIdx.y * 64;
    const int b = blockIdx.z >> 2, nch = blockIdx.z & 3;
    const ushort_t* Ab = v0c + (long)b * CN_;
    const ushort_t* Bb = khat + (long)b * CN_;
    const int ar = tid >> 2, as = (tid & 3) * 8;
    const int br = tid >> 1, bs = (tid & 1) * 16;
    const int w = tid >> 6, l = tid & 63;
    const int wr = (w >> 1) * 32, wc = (w & 1) * 64;
    const int fr = l & 15, ks = l >> 4;

    f32x4 acc[2][4];
#pragma unroll
    for (int m = 0; m < 2; ++m)
#pragma unroll
        for (int nf = 0; nf < 4; ++nf) acc[m][nf] = f32x4{0.f, 0.f, 0.f, 0.f};

    const ushort_t* aptr = Ab + (long)(d0 + ar) * N_DIM + nch * 1024 + as;
    const ushort_t* bptr = Bb + (long)(c0 + br) * N_DIM + nch * 1024 + bs;

    for (int kk = 0; kk < 1024; kk += 32) {
        uint4 av = *(const uint4*)(aptr + kk);
        uint4 bv0 = *(const uint4*)(bptr + kk);
        uint4 bv1 = *(const uint4*)(bptr + kk + 8);
        __syncthreads();
        *(uint4*)&Als[ar][as] = av;
        *(uint4*)&Bls[br][bs] = bv0;
        *(uint4*)&Bls[br][bs + 8] = bv1;
        __syncthreads();
        bf16x8 af[2], bfv[4];
#pragma unroll
        for (int m = 0; m < 2; ++m)
            af[m] = *(const bf16x8*)&Als[wr + m * 16 + fr][ks * 8];
#pragma unroll
        for (int nf = 0; nf < 4; ++nf)
            bfv[nf] = *(const bf16x8*)&Bls[wc + nf * 16 + fr][ks * 8];
#pragma unroll
        for (int m = 0; m < 2; ++m)
#pragma unroll
            for (int nf = 0; nf < 4; ++nf)
                acc[m][nf] = __builtin_amdgcn_mfma_f32_16x16x32_bf16(
                    af[m], bfv[nf], acc[m][nf], 0, 0, 0);
    }

    float* KV = kvb + (long)b * 262144;
#pragma unroll
    for (int m = 0; m < 2; ++m)
#pragma unroll
        for (int nf = 0; nf < 4; ++nf) {
            const int cc = c0 + wc + nf * 16 + fr;
#pragma unroll
            for (int j = 0; j < 4; ++j) {
                const int dd = d0 + wr + m * 16 + ks * 4 + j;
                atomicAdd(&KV[(long)dd * 512 + cc], acc[m][nf][j]);
            }
        }
}

// kvT[i] = f2b(kvb[i] * 1/sqrt(512))
__global__ __launch_bounds__(256) void cvt_scale(
    const float* __restrict__ in, ushort_t* __restrict__ out)
{
    const float s = 0.044194173824159216f;
    int i = (blockIdx.x * 256 + threadIdx.x) * 4;
    float4 v = *(const float4*)&in[i];
    union { ushort_t sh[4]; uint2 u; } p;
    p.sh[0] = f2b(v.x * s); p.sh[1] = f2b(v.y * s);
    p.sh[2] = f2b(v.z * s); p.sh[3] = f2b(v.w * s);
    *(uint2*)&out[i] = p.u;
}

// bf16 [z][4096][512] -> bf16 [z][512][4096]; ALPHA: out *= alpha[z][n]
template<int ALPHA>
__global__ __launch_bounds__(256) void transpose_b2b(
    const ushort_t* __restrict__ in, ushort_t* __restrict__ out,
    const float* __restrict__ alpha)
{
    __shared__ ushort_t t[64][72];
    const int tid = threadIdx.x;
    const int n0 = blockIdx.x * 64, c0 = blockIdx.y * 64, z = blockIdx.z;
    const ushort_t* I = in + (long)z * CN_;
    ushort_t* O = out + (long)z * CN_;
    const int r = tid >> 2, s8 = (tid & 3) * 16;
    uint4 u0 = *(const uint4*)&I[(long)(n0 + r) * 512 + c0 + s8];
    uint4 u1 = *(const uint4*)&I[(long)(n0 + r) * 512 + c0 + s8 + 8];
    *(uint4*)&t[r][s8] = u0;
    *(uint4*)&t[r][s8 + 8] = u1;
    __syncthreads();
    union { ushort_t sh[16]; uint4 u[2]; } p;
#pragma unroll
    for (int i = 0; i < 16; ++i) {
        ushort_t v = t[s8 + i][r];
        if (ALPHA) v = f2b(b2f(v) * alpha[(long)z * N_DIM + n0 + s8 + i]);
        p.sh[i] = v;
    }
    uint4* dst = (uint4*)&O[(long)(c0 + r) * N_DIM + n0 + s8];
    dst[0] = p.u[0]; dst[1] = p.u[1];
}

// ---------------------------------------------------------------------------
// ybar[n][d] (+)= (1/12) sum_mm (sum_c q4[mm][n][c]*kvT[mm][d][c]) * z * phi4
// ---------------------------------------------------------------------------
__global__ __launch_bounds__(256) void ybar_mfma(
    const ushort_t* __restrict__ q4, const ushort_t* __restrict__ kvT,
    const ushort_t* __restrict__ phi4, const float* __restrict__ den4,
    float* __restrict__ ybar, int accflag)
{
    __shared__ ushort_t Als[64][40];
    __shared__ ushort_t Bls[128][40];
    const int tid = threadIdx.x;
    const int o0 = blockIdx.x * 128;
    const int n0 = blockIdx.y * 64;
    const int ar = tid >> 2, as = (tid & 3) * 8;
    const int br = tid >> 1, bs = (tid & 1) * 16;
    const int w = tid >> 6, l = tid & 63;
    const int wr = (w >> 1) * 32, wc = (w & 1) * 64;
    const int fr = l & 15, ks = l >> 4;

    f32x4 yt[2][4];
#pragma unroll
    for (int m = 0; m < 2; ++m)
#pragma unroll
        for (int nf = 0; nf < 4; ++nf) yt[m][nf] = f32x4{0.f, 0.f, 0.f, 0.f};

    for (int mm = 0; mm < 4; ++mm) {
        const ushort_t* aptr = q4 + (long)mm * CN_ + (long)(n0 + ar) * 512 + as;
        const ushort_t* bptr = kvT + (long)mm * (512 * 512) + (long)(o0 + br) * 512 + bs;
        f32x4 acc[2][4];
#pragma unroll
        for (int m = 0; m < 2; ++m)
#pragma unroll
            for (int nf = 0; nf < 4; ++nf) acc[m][nf] = f32x4{0.f, 0.f, 0.f, 0.f};

        for (int kk = 0; kk < 512; kk += 32) {
            uint4 av = *(const uint4*)(aptr + kk);
            uint4 bv0 = *(const uint4*)(bptr + kk);
            uint4 bv1 = *(const uint4*)(bptr + kk + 8);
            __syncthreads();
            *(uint4*)&Als[ar][as] = av;
            *(uint4*)&Bls[br][bs] = bv0;
            *(uint4*)&Bls[br][bs + 8] = bv1;
            __syncthreads();
            bf16x8 af[2], bfv[4];
#pragma unroll
            for (int m = 0; m < 2; ++m)
                af[m] = *(const bf16x8*)&Als[wr + m * 16 + fr][ks * 8];
#pragma unroll
            for (int nf = 0; nf < 4; ++nf)
                bfv[nf] = *(const bf16x8*)&Bls[wc + nf * 16 + fr][ks * 8];
#pragma unroll
            for (int m = 0; m < 2; ++m)
#pragma unroll
                for (int nf = 0; nf < 4; ++nf)
                    acc[m][nf] = __builtin_amdgcn_mfma_f32_16x16x32_bf16(
                        af[m], bfv[nf], acc[m][nf], 0, 0, 0);
        }
        const ushort_t* P = phi4 + (long)mm * CN_;
        const float* D = den4 + (long)mm * N_DIM;
        float zr[2][4];
#pragma unroll
        for (int m = 0; m < 2; ++m)
#pragma unroll
            for (int j = 0; j < 4; ++j)
                zr[m][j] = 1.f / (D[n0 + wr + m * 16 + ks * 4 + j] + 1e-6f);
#pragma unroll
        for (int m = 0; m < 2; ++m)
#pragma unroll
            for (int nf = 0; nf < 4; ++nf) {
                const int oo = o0 + wc + nf * 16 + fr;
#pragma unroll
                for (int j = 0; j < 4; ++j) {
                    const int nn = n0 + wr + m * 16 + ks * 4 + j;
                    yt[m][nf][j] += acc[m][nf][j] * zr[m][j] * b2f(P[(long)nn * 512 + oo]);
                }
            }
        __syncthreads();
    }
#pragma unroll
    for (int m = 0; m < 2; ++m)
#pragma unroll
        for (int nf = 0; nf < 4; ++nf) {
            const int oo = o0 + wc + nf * 16 + fr;
#pragma unroll
            for (int j = 0; j < 4; ++j) {
                const int nn = n0 + wr + m * 16 + ks * 4 + j;
                const long idx = (long)nn * 512 + oo;
                float r = yt[m][nf][j] * (1.f / 12.f);
                if (accflag) r += ybar[idx];
                ybar[idx] = r;
            }
        }
}

// fp32 -> bf16 elementwise
__global__ __launch_bounds__(256) void cvt_f2b(
    const float* __restrict__ in, ushort_t* __restrict__ out, int n)
{
    int i = (blockIdx.x * 256 + threadIdx.x) * 4;
    if (i >= n) return;
    float4 v = *(const float4*)&in[i];
    union { ushort_t s[4]; uint2 u; } p;
    p.s[0] = f2b(v.x); p.s[1] = f2b(v.y); p.s[2] = f2b(v.z); p.s[3] = f2b(v.w);
    *(uint2*)&out[i] = p.u;
}

// transpose fp32 [z][rows][cols] -> bf16 [z][cols][rows]
__global__ __launch_bounds__(256) void transpose_f2b(
    const float* __restrict__ in, ushort_t* __restrict__ out,
    int rows, int cols, long in_z, long out_z)
{
    __shared__ float t[64][65];
    const int tid = threadIdx.x;
    const int n0 = blockIdx.x * 64, c0 = blockIdx.y * 64;
    const float* I = in + (long)blockIdx.z * in_z;
    ushort_t* Ot = out + (long)blockIdx.z * out_z;
    const int r = tid >> 2, s4 = (tid & 3) * 16;
#pragma unroll
    for (int i = 0; i < 16; i += 4) {
        float4 v = *(const float4*)&I[(long)(c0 + r) * cols + n0 + s4 + i];
        t[r][s4 + i] = v.x; t[r][s4 + i + 1] = v.y;
        t[r][s4 + i + 2] = v.z; t[r][s4 + i + 3] = v.w;
    }
    __syncthreads();
    union { ushort_t s[16]; uint4 u[2]; } pk;
#pragma unroll
    for (int i = 0; i < 16; ++i) pk.s[i] = f2b(t[s4 + i][r]);
    uint4* dst = (uint4*)&Ot[(long)(n0 + r) * rows + c0 + s4];
    dst[0] = pk.u[0]; dst[1] = pk.u[1];
}

// transpose fp32 [z][rows][cols] -> fp32 [z][cols][rows]
__global__ __launch_bounds__(256) void transpose_ff(
    const float* __restrict__ in, float* __restrict__ out,
    int rows, int cols, long in_z, long out_z)
{
    __shared__ float t[64][65];
    const int tid = threadIdx.x;
    const int n0 = blockIdx.x * 64, c0 = blockIdx.y * 64;
    const float* I = in + (long)blockIdx.z * in_z;
    float* Ot = out + (long)blockIdx.z * out_z;
    const int r = tid >> 2, s4 = (tid & 3) * 16;
#pragma unroll
    for (int i = 0; i < 16; i += 4) {
        float4 v = *(const float4*)&I[(long)(c0 + r) * cols + n0 + s4 + i];
        t[r][s4 + i] = v.x; t[r][s4 + i + 1] = v.y;
        t[r][s4 + i + 2] = v.z; t[r][s4 + i + 3] = v.w;
    }
    __syncthreads();
#pragma unroll
    for (int i = 0; i < 16; i += 4) {
        float4 o = make_float4(t[s4 + i][r], t[s4 + i + 1][r], t[s4 + i + 2][r], t[s4 + i + 3][r]);
        *(float4*)&Ot[(long)(n0 + r) * rows + c0 + s4 + i] = o;
    }
}

// part[ns][b][c] = sum_{n in 128-row chunk ns} X[b][n][c] * (wgt?[b][n])
__global__ __launch_bounds__(256) void colreduce_part(
    const ushort_t* __restrict__ X, const float* __restrict__ wgt,
    float* __restrict__ part)
{
    const int ns = blockIdx.x, b = blockIdx.y;
    const int tid = threadIdx.x;
    const int w = tid >> 6, l = tid & 63;
    const int c8 = l * 8;
    const ushort_t* Xb = X + (long)b * CN_;
    float acc[8] = {0.f, 0.f, 0.f, 0.f, 0.f, 0.f, 0.f, 0.f};
    for (int r = w; r < 128; r += 4) {
        const int n = ns * 128 + r;
        uint4 u = *(const uint4*)&Xb[(long)n * C_DIM + c8];
        const ushort_t* us = (const ushort_t*)&u;
        const float wv = wgt ? wgt[(long)b * N_DIM + n] : 1.f;
#pragma unroll
        for (int i = 0; i < 8; ++i) acc[i] += b2f(us[i]) * wv;
    }
    __shared__ float red[4][512];
#pragma unroll
    for (int i = 0; i < 8; ++i) red[w][c8 + i] = acc[i];
    __syncthreads();
    for (int c = tid; c < 512; c += 256) {
        part[((long)ns * 4 + b) * C_DIM + c] =
            red[0][c] + red[1][c] + red[2][c] + red[3][c];
    }
}

__global__ __launch_bounds__(256) void colreduce_fin(
    const float* __restrict__ part, float* __restrict__ out, float scale)
{
    int b = blockIdx.x;
    for (int c = threadIdx.x; c < 512; c += 256) {
        float s = 0.f;
        for (int ns = 0; ns < 32; ++ns) s += part[((long)ns * 4 + b) * C_DIM + c];
        out[b * C_DIM + c] = s * scale;
    }
}

// out[z][n] = sum_c X[z][n][c] * w[z][c]
__global__ __launch_bounds__(256) void dot_rows(
    const ushort_t* __restrict__ X, const float* __restrict__ w,
    float* __restrict__ out)
{
    const int tid = threadIdx.x;
    const int rn = tid >> 2, cs = (tid & 3) * 128;
    const int z = blockIdx.y;
    const int n = blockIdx.x * 64 + rn;
    const ushort_t* row = X + (long)z * CN_ + (long)n * C_DIM;
    const float* wz = w + (long)z * C_DIM;
    float s = 0.f;
    for (int i = 0; i < 128; i += 8) {
        uint4 u = *(const uint4*)&row[cs + i];
        const ushort_t* us = (const ushort_t*)&u;
#pragma unroll
        for (int k2 = 0; k2 < 8; ++k2) s += b2f(us[k2]) * wz[cs + i + k2];
    }
    s += __shfl_xor(s, 1); s += __shfl_xor(s, 2);
    if ((tid & 3) == 0) out[(long)z * N_DIM + n] = s;
}

// alpha[b,n] = softmax_n(logits[b,:]) * N
__global__ __launch_bounds__(256) void softmax_alpha(
    const float* __restrict__ logits, float* __restrict__ alpha)
{
    int b = blockIdx.x, tid = threadIdx.x;
    const float* L = logits + (long)b * N_DIM;
    float* A = alpha + (long)b * N_DIM;
    float lv[16];
    float mx = -3.4e38f;
#pragma unroll
    for (int i = 0; i < 4; i++) {
        float4 v = *(const float4*)&L[tid * 4 + i * 1024];
        lv[4 * i + 0] = v.x; lv[4 * i + 1] = v.y; lv[4 * i + 2] = v.z; lv[4 * i + 3] = v.w;
        mx = fmaxf(mx, fmaxf(fmaxf(v.x, v.y), fmaxf(v.z, v.w)));
    }
    __shared__ float red[8];
    float m = mx;
#pragma unroll
    for (int off = 32; off; off >>= 1) m = fmaxf(m, __shfl_down(m, off, 64));
    int wid = tid >> 6, lane = tid & 63;
    if (lane == 0) red[wid] = m;
    __syncthreads();
    m = fmaxf(fmaxf(red[0], red[1]), fmaxf(red[2], red[3]));
    float e[16], s = 0.f;
#pragma unroll
    for (int i = 0; i < 16; i++) { e[i] = expf(lv[i] - m); s += e[i]; }
#pragma unroll
    for (int off = 32; off; off >>= 1) s += __shfl_down(s, off, 64);
    if (lane == 0) red[4 + wid] = s;
    __syncthreads();
    float S = red[4] + red[5] + red[6] + red[7];
    float sc = 4096.f / S;
#pragma unroll
    for (int i = 0; i < 4; i++)
        *(float4*)&A[tid * 4 + i * 1024] =
            make_float4(e[4 * i] * sc, e[4 * i + 1] * sc, e[4 * i + 2] * sc, e[4 * i + 3] * sc);
}

// row LayerNorm over c (512) per (z,n); optional relu; out bf16 or f32
template<int RELU, int OBF>
__global__ __launch_bounds__(256) void ln_row(
    const float* __restrict__ in, const float* __restrict__ g,
    const float* __restrict__ bt, void* __restrict__ outv)
{
    const int tid = threadIdx.x;
    const int r = tid >> 3, cs = (tid & 7) * 64;
    const long base = (((long)blockIdx.y * N_DIM) + blockIdx.x * 32 + r) * C_DIM + cs;
    const float* I = in + base;
    float4 v[16];
    float s = 0.f, s2 = 0.f;
#pragma unroll
    for (int i = 0; i < 16; ++i) {
        v[i] = *(const float4*)&I[i * 4];
        s += v[i].x + v[i].y + v[i].z + v[i].w;
        s2 += v[i].x * v[i].x + v[i].y * v[i].y + v[i].z * v[i].z + v[i].w * v[i].w;
    }
#pragma unroll
    for (int off = 1; off < 8; off <<= 1) { s += __shfl_xor(s, off); s2 += __shfl_xor(s2, off); }
    const float mean = s * (1.f / 512.f);
    const float var = s2 * (1.f / 512.f) - mean * mean;
    const float rs = rsqrtf(var + 1e-6f);
#pragma unroll
    for (int i = 0; i < 16; ++i) {
        float4 gv = *(const float4*)&g[cs + i * 4];
        float4 bv = *(const float4*)&bt[cs + i * 4];
        float o[4];
        o[0] = (v[i].x - mean) * rs * gv.x + bv.x;
        o[1] = (v[i].y - mean) * rs * gv.y + bv.y;
        o[2] = (v[i].z - mean) * rs * gv.z + bv.z;
        o[3] = (v[i].w - mean) * rs * gv.w + bv.w;
        if (RELU) {
            o[0] = fmaxf(o[0], 0.f); o[1] = fmaxf(o[1], 0.f);
            o[2] = fmaxf(o[2], 0.f); o[3] = fmaxf(o[3], 0.f);
        }
        if (OBF) {
            union { ushort_t s4[4]; uint2 u; } p;
            p.s4[0] = f2b(o[0]); p.s4[1] = f2b(o[1]); p.s4[2] = f2b(o[2]); p.s4[3] = f2b(o[3]);
            *(uint2*)&((ushort_t*)outv)[base + i * 4] = p.u;
        } else {
            *(float4*)&((float*)outv)[base + i * 4] = make_float4(o[0], o[1], o[2], o[3]);
        }
    }
}

extern "C" void kernel_launch(void* const* d_in, const int* in_sizes, int n_in,
                              void* d_out, int out_size, void* d_ws, size_t ws_size,
                              hipStream_t stream)
{
    const float* x     = (const float*)d_in[0];
    const float* Wq    = (const float*)d_in[1];
    const float* Wk    = (const float*)d_in[2];
    const float* Wv    = (const float*)d_in[3];
    const float* Wphi  = (const float*)d_in[4];
    const float* ln1_w = (const float*)d_in[5];
    const float* ln1_b = (const float*)d_in[6];
    const float* fc1_w = (const float*)d_in[7];
    const float* fc1_bias = (const float*)d_in[8];
    const float* fc2_w = (const float*)d_in[9];
    const float* fc2_bias = (const float*)d_in[10];
    const float* ln2_w = (const float*)d_in[11];
    const float* ln2_b = (const float*)d_in[12];
    float* out = (float*)d_out;

    float* ws = (float*)d_ws;
    const long CN = CN_;
    // region map (float units); lifetimes are stream-sequential:
    ushort_t* xTfirst = (ushort_t*)ws;                 // [0,2CN)
    ushort_t* tln     = (ushort_t*)ws;
    ushort_t* xTc  = (ushort_t*)(ws + 2 * CN);         // [2CN,4CN)
    ushort_t* k0b = (ushort_t*)(ws + 4 * CN);          // [4CN,6CN)
    ushort_t* v0b = (ushort_t*)(ws + 6 * CN);          // [6CN,8CN)
    float* pre = ws + 4 * CN;                          // stage3 reuse
    float* tmp = ws + 4 * CN;
    ushort_t* khat = (ushort_t*)(ws + 8 * CN);         // [8CN,10CN) stage1
    ushort_t* q4   = (ushort_t*)(ws + 8 * CN);         // stage2 reuse
    ushort_t* v0c  = (ushort_t*)(ws + 10 * CN);        // [10CN,12CN) stage1
    ushort_t* phi4 = (ushort_t*)(ws + 10 * CN);        // stage2 reuse
    float* ubuf = ws + 8 * CN;                         // stage3 reuse
    float* ybar = ws + 12 * CN;                        // [12CN,13CN)
    float* kvb  = ws + 13 * CN;                        // 1M floats
    ushort_t* kvT = (ushort_t*)(ws + 13 * CN + 1048576);   // 1M bf16
    float* wb = ws + 13 * CN + 1048576 + 524288;
    ushort_t* Wk_b   = (ushort_t*)(wb);
    ushort_t* Wq_b   = (ushort_t*)(wb + 32768);
    ushort_t* Wv_b   = (ushort_t*)(wb + 65536);
    ushort_t* Wphi_b = (ushort_t*)(wb + 196608);
    ushort_t* fc1_b16 = (ushort_t*)(wb + 327680);
    ushort_t* fc2_b16 = (ushort_t*)(wb + 851968);
    float* part   = wb + 1376256;                      // 65536 floats
    float* Qg     = wb + 1441792;
    float* ksum   = wb + 1443840;
    float* logits = wb + 1445888;
    float* alpha  = wb + 1462272;
    float* den4   = wb + 1478656;
    ushort_t* hbuf4 = (ushort_t*)(ws + 16 * CN);       // [16CN,24CN): 4 x 4096x2048 bf16

    dim3 blk(256);

    // weights -> bf16
    cvt_f2b<<<64, blk, 0, stream>>>(Wk, Wk_b, 65536);
    cvt_f2b<<<64, blk, 0, stream>>>(Wq, Wq_b, 65536);
    cvt_f2b<<<256, blk, 0, stream>>>(Wv, Wv_b, 262144);
    cvt_f2b<<<256, blk, 0, stream>>>(Wphi, Wphi_b, 262144);
    cvt_f2b<<<1024, blk, 0, stream>>>(fc1_w, fc1_b16, 1048576);
    cvt_f2b<<<1024, blk, 0, stream>>>(fc2_w, fc2_b16, 1048576);
    hipMemsetAsync(kvb, 0, 1048576 * sizeof(float), stream);

    // xT for first 4 batches (residual + phi_first source)
    transpose_f2b<<<dim3(64, 8, 4), blk, 0, stream>>>(x, xTfirst, 512, 4096, CN, CN);

    // stage 1: k0, v0, reductions, alpha, ksum, kv (MFMA path)
    mfma_gemm<EPI_PHI, true, true><<<512, blk, 0, stream>>>(
        Wk_b, xTfirst, k0b, nullptr, nullptr, nullptr, 128, 512, 512, CN, CN, 0, 4, 32);
    mfma_gemm<EPI_NONE, false, true><<<512, blk, 0, stream>>>(
        Wv_b, xTfirst, v0b, nullptr, nullptr, nullptr, 512, 512, 512, CN, CN, 0, 4, 32);
    colreduce_part<<<dim3(32, 4), blk, 0, stream>>>(k0b, nullptr, part);
    colreduce_fin<<<4, blk, 0, stream>>>(part, Qg, 1.f / 4096.f);
    dot_rows<<<dim3(64, 4), blk, 0, stream>>>(k0b, Qg, logits);
    softmax_alpha<<<4, blk, 0, stream>>>(logits, alpha);
    colreduce_part<<<dim3(32, 4), blk, 0, stream>>>(k0b, alpha, part);
    colreduce_fin<<<4, blk, 0, stream>>>(part, ksum, 1.f);
    transpose_b2b<1><<<dim3(64, 8, 4), blk, 0, stream>>>(k0b, khat, alpha);
    transpose_b2b<0><<<dim3(64, 8, 4), blk, 0, stream>>>(v0b, v0c, nullptr);
    kv_mfma<<<dim3(4, 8, 16), blk, 0, stream>>>(v0c, khat, kvb);
    cvt_scale<<<1024, blk, 0, stream>>>(kvb, kvT);

    // stage 2: rest in 3 chunks of 4 (b = mm since chunks are 4-aligned)
    for (int ch = 0; ch < 3; ++ch) {
        const float* xr = x + (long)(4 + 4 * ch) * CN;
        transpose_f2b<<<dim3(64, 8, 4), blk, 0, stream>>>(xr, xTc, 512, 4096, CN, CN);
        mfma_gemm<EPI_PHI, true, true><<<512, blk, 0, stream>>>(
            Wq_b, xTc, q4, nullptr, nullptr, nullptr, 128, 512, 512, CN, CN, 0, 4, 32);
        mfma_gemm<EPI_NONE, false, true><<<512, blk, 0, stream>>>(
            Wphi_b, xTc, phi4, nullptr, nullptr, nullptr, 512, 512, 512, CN, CN, 0, 4, 32);
        dot_rows<<<dim3(64, 4), blk, 0, stream>>>(q4, ksum, den4);
        ybar_mfma<<<dim3(4, 64), blk, 0, stream>>>(q4, kvT, phi4, den4, ybar, ch > 0);
    }

    // stage 3: pre = firstT + ybar*phiF; LN1; MLP (batched z=4); LN2+relu; transpose out
    mfma_gemm<EPI_PRE, false, false><<<512, blk, 0, stream>>>(
        Wphi_b, xTfirst, pre, nullptr, xTfirst, ybar, 512, 512, 512, CN, CN, CN, 4, 32);
    ln_row<0, 1><<<dim3(128, 4), blk, 0, stream>>>(pre, ln1_w, ln1_b, tln);
    mfma_gemm<EPI_RELU_BIAS, false, true><<<2048, blk, 0, stream>>>(
        fc1_b16, tln, hbuf4, fc1_bias, nullptr, nullptr,
        512, 2048, 512, CN, 8388608, 0, 16, 32);
    mfma_gemm<EPI_RES_BIAS, false, false><<<512, blk, 0, stream>>>(
        fc2_b16, hbuf4, ubuf, fc2_bias, tln, nullptr,
        2048, 512, 2048, 8388608, CN, CN, 4, 32);
    ln_row<1, 0><<<dim3(128, 4), blk, 0, stream>>>(ubuf, ln2_w, ln2_b, tmp);
    transpose_ff<<<dim3(8, 64, 4), blk, 0, stream>>>(tmp, out, 4096, 512, CN, CN);

    // passthrough: out[4:] = rest
    hipMemcpyAsync(out + 4 * CN, x + 4 * CN, 12 * CN * sizeof(float),
                   hipMemcpyDeviceToDevice, stream);
}

// Round 8
// 653.136 us; speedup vs baseline: 3.7119x; 1.0571x over previous
//
#include <hip/hip_runtime.h>

#define N_DIM 4096
#define C_DIM 512
#define CN_ ((long)C_DIM * (long)N_DIM)   // 2,097,152

typedef unsigned short ushort_t;
typedef __attribute__((ext_vector_type(8))) short bf16x8;
typedef __attribute__((ext_vector_type(4))) float f32x4;

typedef const __attribute__((address_space(1))) unsigned int* gas_t;
typedef __attribute__((address_space(3))) unsigned int* las_t;
#define GLOAD(g, l) __builtin_amdgcn_global_load_lds((gas_t)(g), (las_t)(l), 16, 0, 0)

__device__ __forceinline__ ushort_t f2b(float f) {
    unsigned u = __builtin_bit_cast(unsigned, f);
    u += 0x7fffu + ((u >> 16) & 1u);
    return (ushort_t)(u >> 16);
}
__device__ __forceinline__ float b2f(ushort_t s) {
    return __builtin_bit_cast(float, (unsigned)s << 16);
}

enum { EPI_NONE = 0, EPI_PHI = 1, EPI_RELU_BIAS = 2, EPI_RES_BIAS = 3, EPI_PRE = 4 };

// ---------------------------------------------------------------------------
// v2 structure: 128x128 tile, BK=32, 4 waves, global_load_lds(16B) staging
// into linear LDS [128][32] ushort; XOR swizzle via pre-swizzled GLOBAL src
// (LDS[r][g] = global[r][g ^ ((r>>1)&3)]); reads use rsw = ks ^ ((fr>>1)&3).
// XCD-bijective 1D remap: xcd = L&7 owns all o-tiles of contiguous (n,z).
// ---------------------------------------------------------------------------
template<int EPI, bool GROUPED, bool OBF>
__global__ __launch_bounds__(256) void mfma_gemm(
    const ushort_t* __restrict__ Wb, const ushort_t* __restrict__ A,
    void* __restrict__ OUTV, const float* __restrict__ bias,
    const ushort_t* __restrict__ auxb, const float* __restrict__ auxf,
    int K, int O, int a_rstride, long a_zstride, long o_zstride, long auxb_zstride,
    int xt, int yt)
{
    __shared__ ushort_t Als[128 * 32];
    __shared__ ushort_t Bls[128 * 32];
    const int tid = threadIdx.x;

    const int L = blockIdx.x;
    const int gpx = (gridDim.x >> 3) / xt;
    const int xcd = L & 7;
    const int j = L >> 3;
    const int xtile = j % xt;
    const int g = xcd * gpx + j / xt;
    const int ytile = g % yt;
    const int z = g / yt;

    const int o0 = xtile * 128;
    const int n0 = ytile * 128;
    const ushort_t* Az = A + (long)z * a_zstride;
    const ushort_t* Wp = Wb;
    int kbase = 0, obase = o0;
    if (GROUPED) { int gg = o0 >> 7; Wp = Wb + (long)gg * (128 * 128); kbase = gg << 7; obase = 0; }

    const int w = tid >> 6, l = tid & 63;
    const int lr = l >> 2, lg = l & 3;
    const int rA0 = w * 32 + lr, rA1 = w * 32 + 16 + lr;
    const int gA0 = lg ^ ((rA0 >> 1) & 3), gA1 = lg ^ ((rA1 >> 1) & 3);
    const ushort_t* ap0 = Az + (long)(n0 + rA0) * a_rstride + kbase + gA0 * 8;
    const ushort_t* ap1 = Az + (long)(n0 + rA1) * a_rstride + kbase + gA1 * 8;
    const ushort_t* bp0 = Wp + (long)(obase + rA0) * K + gA0 * 8;
    const ushort_t* bp1 = Wp + (long)(obase + rA1) * K + gA1 * 8;
    ushort_t* la0 = &Als[(w * 32) * 32];
    ushort_t* la1 = &Als[(w * 32 + 16) * 32];
    ushort_t* lb0 = &Bls[(w * 32) * 32];
    ushort_t* lb1 = &Bls[(w * 32 + 16) * 32];

    const int wr = (w >> 1) * 64, wc = (w & 1) * 64;
    const int fr = l & 15, ks = l >> 4;
    const int rsw = (ks ^ ((fr >> 1) & 3)) << 3;

    f32x4 acc[4][4];
#pragma unroll
    for (int m = 0; m < 4; ++m)
#pragma unroll
        for (int nf = 0; nf < 4; ++nf) acc[m][nf] = f32x4{0.f, 0.f, 0.f, 0.f};

    for (int kk = 0; kk < K; kk += 32) {
        __syncthreads();
        GLOAD(ap0 + kk, la0);
        GLOAD(ap1 + kk, la1);
        GLOAD(bp0 + kk, lb0);
        GLOAD(bp1 + kk, lb1);
        __syncthreads();
        bf16x8 af[4], bfv[4];
#pragma unroll
        for (int m = 0; m < 4; ++m)
            af[m] = *(const bf16x8*)&Als[(wr + m * 16 + fr) * 32 + rsw];
#pragma unroll
        for (int nf = 0; nf < 4; ++nf)
            bfv[nf] = *(const bf16x8*)&Bls[(wc + nf * 16 + fr) * 32 + rsw];
#pragma unroll
        for (int m = 0; m < 4; ++m)
#pragma unroll
            for (int nf = 0; nf < 4; ++nf)
                acc[m][nf] = __builtin_amdgcn_mfma_f32_16x16x32_bf16(
                    af[m], bfv[nf], acc[m][nf], 0, 0, 0);
    }

#pragma unroll
    for (int m = 0; m < 4; ++m) {
#pragma unroll
        for (int nf = 0; nf < 4; ++nf) {
            const int oo = o0 + wc + nf * 16 + fr;
            float bval = 0.f;
            if (EPI == EPI_RELU_BIAS || EPI == EPI_RES_BIAS) bval = bias[oo];
#pragma unroll
            for (int j2 = 0; j2 < 4; ++j2) {
                const int nn = n0 + wr + m * 16 + ks * 4 + j2;
                const long ridx = (long)nn * O + oo;
                float v = acc[m][nf][j2];
                if (EPI == EPI_PHI)            v = fmaxf(v, 0.f) + 1.f;
                else if (EPI == EPI_RELU_BIAS) v = fmaxf(v + bval, 0.f);
                else if (EPI == EPI_RES_BIAS)  v = v + bval + b2f(auxb[(long)z * auxb_zstride + ridx]);
                else if (EPI == EPI_PRE)       v = b2f(auxb[(long)z * auxb_zstride + ridx]) + auxf[ridx] * v;
                if (OBF) ((ushort_t*)OUTV)[(long)z * o_zstride + ridx] = f2b(v);
                else     ((float*)OUTV)[(long)z * o_zstride + ridx] = v;
            }
        }
    }
}

// ---------------------------------------------------------------------------
// kv v2: kvb[b][d][c] += sum_{n in chunk} v0c[b][d][n] * khat[b][c][n]
// grid 256: xt=4 c-tiles, yt=4 d-tiles, z = b*4+nch
// ---------------------------------------------------------------------------
__global__ __launch_bounds__(256) void kv_mfma(
    const ushort_t* __restrict__ v0c, const ushort_t* __restrict__ khat,
    float* __restrict__ kvb)
{
    __shared__ ushort_t Als[128 * 32];
    __shared__ ushort_t Bls[128 * 32];
    const int tid = threadIdx.x;
    const int L = blockIdx.x;
    const int gpx = (gridDim.x >> 3) >> 2;   // /4 xt
    const int xcd = L & 7;
    const int j = L >> 3;
    const int xtile = j & 3;
    const int g = xcd * gpx + (j >> 2);
    const int ytile = g & 3;
    const int z = g >> 2;
    const int c0 = xtile * 128, d0 = ytile * 128;
    const int b = z >> 2, nch = z & 3;

    const int w = tid >> 6, l = tid & 63;
    const int lr = l >> 2, lg = l & 3;
    const int rA0 = w * 32 + lr, rA1 = w * 32 + 16 + lr;
    const int gA0 = lg ^ ((rA0 >> 1) & 3), gA1 = lg ^ ((rA1 >> 1) & 3);
    const ushort_t* Ab = v0c + (long)b * CN_ + nch * 1024;
    const ushort_t* Bb = khat + (long)b * CN_ + nch * 1024;
    const ushort_t* ap0 = Ab + (long)(d0 + rA0) * N_DIM + gA0 * 8;
    const ushort_t* ap1 = Ab + (long)(d0 + rA1) * N_DIM + gA1 * 8;
    const ushort_t* bp0 = Bb + (long)(c0 + rA0) * N_DIM + gA0 * 8;
    const ushort_t* bp1 = Bb + (long)(c0 + rA1) * N_DIM + gA1 * 8;
    ushort_t* la0 = &Als[(w * 32) * 32];
    ushort_t* la1 = &Als[(w * 32 + 16) * 32];
    ushort_t* lb0 = &Bls[(w * 32) * 32];
    ushort_t* lb1 = &Bls[(w * 32 + 16) * 32];

    const int wr = (w >> 1) * 64, wc = (w & 1) * 64;
    const int fr = l & 15, ks = l >> 4;
    const int rsw = (ks ^ ((fr >> 1) & 3)) << 3;

    f32x4 acc[4][4];
#pragma unroll
    for (int m = 0; m < 4; ++m)
#pragma unroll
        for (int nf = 0; nf < 4; ++nf) acc[m][nf] = f32x4{0.f, 0.f, 0.f, 0.f};

    for (int kk = 0; kk < 1024; kk += 32) {
        __syncthreads();
        GLOAD(ap0 + kk, la0);
        GLOAD(ap1 + kk, la1);
        GLOAD(bp0 + kk, lb0);
        GLOAD(bp1 + kk, lb1);
        __syncthreads();
        bf16x8 af[4], bfv[4];
#pragma unroll
        for (int m = 0; m < 4; ++m)
            af[m] = *(const bf16x8*)&Als[(wr + m * 16 + fr) * 32 + rsw];
#pragma unroll
        for (int nf = 0; nf < 4; ++nf)
            bfv[nf] = *(const bf16x8*)&Bls[(wc + nf * 16 + fr) * 32 + rsw];
#pragma unroll
        for (int m = 0; m < 4; ++m)
#pragma unroll
            for (int nf = 0; nf < 4; ++nf)
                acc[m][nf] = __builtin_amdgcn_mfma_f32_16x16x32_bf16(
                    af[m], bfv[nf], acc[m][nf], 0, 0, 0);
    }

    float* KV = kvb + (long)b * 262144;
#pragma unroll
    for (int m = 0; m < 4; ++m)
#pragma unroll
        for (int nf = 0; nf < 4; ++nf) {
            const int cc = c0 + wc + nf * 16 + fr;
#pragma unroll
            for (int j2 = 0; j2 < 4; ++j2) {
                const int dd = d0 + wr + m * 16 + ks * 4 + j2;
                atomicAdd(&KV[(long)dd * 512 + cc], acc[m][nf][j2]);
            }
        }
}

// ---------------------------------------------------------------------------
// ybar v2: ybar[n][d] += (1/12) sum_mm (sum_c q12[mmg][n][c]*kvT[b][d][c])
//                       * (1/(den12[mmg][n]+eps)) * phi12[mmg][n][d]
// grid 384: xt=4 d-tiles, yt=32 n-tiles, z = mm-group (0..2); atomicAdd out.
// ---------------------------------------------------------------------------
__global__ __launch_bounds__(256) void ybar_mfma(
    const ushort_t* __restrict__ q12, const ushort_t* __restrict__ kvT,
    const ushort_t* __restrict__ phi12, const float* __restrict__ den12,
    float* __restrict__ ybar)
{
    __shared__ ushort_t Als[128 * 32];
    __shared__ ushort_t Bls[128 * 32];
    const int tid = threadIdx.x;
    const int L = blockIdx.x;
    const int gpx = (gridDim.x >> 3) >> 2;   // /4 xt
    const int xcd = L & 7;
    const int j = L >> 3;
    const int xtile = j & 3;
    const int g = xcd * gpx + (j >> 2);
    const int ytile = g & 31;
    const int zg = g >> 5;                   // mm-group
    const int o0 = xtile * 128, n0 = ytile * 128;
    const int mm0 = zg * 4;

    const int w = tid >> 6, l = tid & 63;
    const int lr = l >> 2, lg = l & 3;
    const int rA0 = w * 32 + lr, rA1 = w * 32 + 16 + lr;
    const int gA0 = lg ^ ((rA0 >> 1) & 3), gA1 = lg ^ ((rA1 >> 1) & 3);
    const long aoff0 = (long)(n0 + rA0) * 512 + gA0 * 8;
    const long aoff1 = (long)(n0 + rA1) * 512 + gA1 * 8;
    const long boff0 = (long)(o0 + rA0) * 512 + gA0 * 8;
    const long boff1 = (long)(o0 + rA1) * 512 + gA1 * 8;
    ushort_t* la0 = &Als[(w * 32) * 32];
    ushort_t* la1 = &Als[(w * 32 + 16) * 32];
    ushort_t* lb0 = &Bls[(w * 32) * 32];
    ushort_t* lb1 = &Bls[(w * 32 + 16) * 32];

    const int wr = (w >> 1) * 64, wc = (w & 1) * 64;
    const int fr = l & 15, ks = l >> 4;
    const int rsw = (ks ^ ((fr >> 1) & 3)) << 3;

    f32x4 yt4[4][4];
#pragma unroll
    for (int m = 0; m < 4; ++m)
#pragma unroll
        for (int nf = 0; nf < 4; ++nf) yt4[m][nf] = f32x4{0.f, 0.f, 0.f, 0.f};

    for (int mm = 0; mm < 4; ++mm) {
        const int mmg = mm0 + mm;
        const ushort_t* ap0 = q12 + (long)mmg * CN_ + aoff0;
        const ushort_t* ap1 = q12 + (long)mmg * CN_ + aoff1;
        const ushort_t* bp0 = kvT + (long)mm * 262144 + boff0;
        const ushort_t* bp1 = kvT + (long)mm * 262144 + boff1;
        f32x4 acc[4][4];
#pragma unroll
        for (int m = 0; m < 4; ++m)
#pragma unroll
            for (int nf = 0; nf < 4; ++nf) acc[m][nf] = f32x4{0.f, 0.f, 0.f, 0.f};

        for (int kk = 0; kk < 512; kk += 32) {
            __syncthreads();
            GLOAD(ap0 + kk, la0);
            GLOAD(ap1 + kk, la1);
            GLOAD(bp0 + kk, lb0);
            GLOAD(bp1 + kk, lb1);
            __syncthreads();
            bf16x8 af[4], bfv[4];
#pragma unroll
            for (int m = 0; m < 4; ++m)
                af[m] = *(const bf16x8*)&Als[(wr + m * 16 + fr) * 32 + rsw];
#pragma unroll
            for (int nf = 0; nf < 4; ++nf)
                bfv[nf] = *(const bf16x8*)&Bls[(wc + nf * 16 + fr) * 32 + rsw];
#pragma unroll
            for (int m = 0; m < 4; ++m)
#pragma unroll
                for (int nf = 0; nf < 4; ++nf)
                    acc[m][nf] = __builtin_amdgcn_mfma_f32_16x16x32_bf16(
                        af[m], bfv[nf], acc[m][nf], 0, 0, 0);
        }

        const ushort_t* P = phi12 + (long)mmg * CN_;
        const float* D = den12 + (long)mmg * N_DIM;
        float zr[4][4];
#pragma unroll
        for (int m = 0; m < 4; ++m)
#pragma unroll
            for (int j2 = 0; j2 < 4; ++j2)
                zr[m][j2] = 1.f / (D[n0 + wr + m * 16 + ks * 4 + j2] + 1e-6f);
#pragma unroll
        for (int m = 0; m < 4; ++m)
#pragma unroll
            for (int nf = 0; nf < 4; ++nf) {
                const int oo = o0 + wc + nf * 16 + fr;
#pragma unroll
                for (int j2 = 0; j2 < 4; ++j2) {
                    const int nn = n0 + wr + m * 16 + ks * 4 + j2;
                    yt4[m][nf][j2] += acc[m][nf][j2] * zr[m][j2] * b2f(P[(long)nn * 512 + oo]);
                }
            }
    }

#pragma unroll
    for (int m = 0; m < 4; ++m)
#pragma unroll
        for (int nf = 0; nf < 4; ++nf) {
            const int oo = o0 + wc + nf * 16 + fr;
#pragma unroll
            for (int j2 = 0; j2 < 4; ++j2) {
                const int nn = n0 + wr + m * 16 + ks * 4 + j2;
                atomicAdd(&ybar[(long)nn * 512 + oo], yt4[m][nf][j2] * (1.f / 12.f));
            }
        }
}

// kvT[i] = f2b(kvb[i] * 1/sqrt(512))
__global__ __launch_bounds__(256) void cvt_scale(
    const float* __restrict__ in, ushort_t* __restrict__ out)
{
    const float s = 0.044194173824159216f;
    int i = (blockIdx.x * 256 + threadIdx.x) * 4;
    float4 v = *(const float4*)&in[i];
    union { ushort_t sh[4]; uint2 u; } p;
    p.sh[0] = f2b(v.x * s); p.sh[1] = f2b(v.y * s);
    p.sh[2] = f2b(v.z * s); p.sh[3] = f2b(v.w * s);
    *(uint2*)&out[i] = p.u;
}

// bf16 [z][4096][512] -> bf16 [z][512][4096]; ALPHA: out *= alpha[z][n]
template<int ALPHA>
__global__ __launch_bounds__(256) void transpose_b2b(
    const ushort_t* __restrict__ in, ushort_t* __restrict__ out,
    const float* __restrict__ alpha)
{
    __shared__ ushort_t t[64][72];
    const int tid = threadIdx.x;
    const int n0 = blockIdx.x * 64, c0 = blockIdx.y * 64, z = blockIdx.z;
    const ushort_t* I = in + (long)z * CN_;
    ushort_t* O = out + (long)z * CN_;
    const int r = tid >> 2, s8 = (tid & 3) * 16;
    uint4 u0 = *(const uint4*)&I[(long)(n0 + r) * 512 + c0 + s8];
    uint4 u1 = *(const uint4*)&I[(long)(n0 + r) * 512 + c0 + s8 + 8];
    *(uint4*)&t[r][s8] = u0;
    *(uint4*)&t[r][s8 + 8] = u1;
    __syncthreads();
    union { ushort_t sh[16]; uint4 u[2]; } p;
#pragma unroll
    for (int i = 0; i < 16; ++i) {
        ushort_t v = t[s8 + i][r];
        if (ALPHA) v = f2b(b2f(v) * alpha[(long)z * N_DIM + n0 + s8 + i]);
        p.sh[i] = v;
    }
    uint4* dst = (uint4*)&O[(long)(c0 + r) * N_DIM + n0 + s8];
    dst[0] = p.u[0]; dst[1] = p.u[1];
}

// fp32 -> bf16 elementwise
__global__ __launch_bounds__(256) void cvt_f2b(
    const float* __restrict__ in, ushort_t* __restrict__ out, int n)
{
    int i = (blockIdx.x * 256 + threadIdx.x) * 4;
    if (i >= n) return;
    float4 v = *(const float4*)&in[i];
    union { ushort_t s[4]; uint2 u; } p;
    p.s[0] = f2b(v.x); p.s[1] = f2b(v.y); p.s[2] = f2b(v.z); p.s[3] = f2b(v.w);
    *(uint2*)&out[i] = p.u;
}

// transpose fp32 [z][rows][cols] -> bf16 [z][cols][rows]
__global__ __launch_bounds__(256) void transpose_f2b(
    const float* __restrict__ in, ushort_t* __restrict__ out,
    int rows, int cols, long in_z, long out_z)
{
    __shared__ float t[64][65];
    const int tid = threadIdx.x;
    const int n0 = blockIdx.x * 64, c0 = blockIdx.y * 64;
    const float* I = in + (long)blockIdx.z * in_z;
    ushort_t* Ot = out + (long)blockIdx.z * out_z;
    const int r = tid >> 2, s4 = (tid & 3) * 16;
#pragma unroll
    for (int i = 0; i < 16; i += 4) {
        float4 v = *(const float4*)&I[(long)(c0 + r) * cols + n0 + s4 + i];
        t[r][s4 + i] = v.x; t[r][s4 + i + 1] = v.y;
        t[r][s4 + i + 2] = v.z; t[r][s4 + i + 3] = v.w;
    }
    __syncthreads();
    union { ushort_t s[16]; uint4 u[2]; } pk;
#pragma unroll
    for (int i = 0; i < 16; ++i) pk.s[i] = f2b(t[s4 + i][r]);
    uint4* dst = (uint4*)&Ot[(long)(n0 + r) * rows + c0 + s4];
    dst[0] = pk.u[0]; dst[1] = pk.u[1];
}

// transpose fp32 [z][rows][cols] -> fp32 [z][cols][rows]
__global__ __launch_bounds__(256) void transpose_ff(
    const float* __restrict__ in, float* __restrict__ out,
    int rows, int cols, long in_z, long out_z)
{
    __shared__ float t[64][65];
    const int tid = threadIdx.x;
    const int n0 = blockIdx.x * 64, c0 = blockIdx.y * 64;
    const float* I = in + (long)blockIdx.z * in_z;
    float* Ot = out + (long)blockIdx.z * out_z;
    const int r = tid >> 2, s4 = (tid & 3) * 16;
#pragma unroll
    for (int i = 0; i < 16; i += 4) {
        float4 v = *(const float4*)&I[(long)(c0 + r) * cols + n0 + s4 + i];
        t[r][s4 + i] = v.x; t[r][s4 + i + 1] = v.y;
        t[r][s4 + i + 2] = v.z; t[r][s4 + i + 3] = v.w;
    }
    __syncthreads();
#pragma unroll
    for (int i = 0; i < 16; i += 4) {
        float4 o = make_float4(t[s4 + i][r], t[s4 + i + 1][r], t[s4 + i + 2][r], t[s4 + i + 3][r]);
        *(float4*)&Ot[(long)(n0 + r) * rows + c0 + s4 + i] = o;
    }
}

// part[ns][b][c] = sum_{n in 128-row chunk ns} X[b][n][c] * (wgt?[b][n])
__global__ __launch_bounds__(256) void colreduce_part(
    const ushort_t* __restrict__ X, const float* __restrict__ wgt,
    float* __restrict__ part)
{
    const int ns = blockIdx.x, b = blockIdx.y;
    const int tid = threadIdx.x;
    const int w = tid >> 6, l = tid & 63;
    const int c8 = l * 8;
    const ushort_t* Xb = X + (long)b * CN_;
    float acc[8] = {0.f, 0.f, 0.f, 0.f, 0.f, 0.f, 0.f, 0.f};
    for (int r = w; r < 128; r += 4) {
        const int n = ns * 128 + r;
        uint4 u = *(const uint4*)&Xb[(long)n * C_DIM + c8];
        const ushort_t* us = (const ushort_t*)&u;
        const float wv = wgt ? wgt[(long)b * N_DIM + n] : 1.f;
#pragma unroll
        for (int i = 0; i < 8; ++i) acc[i] += b2f(us[i]) * wv;
    }
    __shared__ float red[4][512];
#pragma unroll
    for (int i = 0; i < 8; ++i) red[w][c8 + i] = acc[i];
    __syncthreads();
    for (int c = tid; c < 512; c += 256) {
        part[((long)ns * 4 + b) * C_DIM + c] =
            red[0][c] + red[1][c] + red[2][c] + red[3][c];
    }
}

__global__ __launch_bounds__(256) void colreduce_fin(
    const float* __restrict__ part, float* __restrict__ out, float scale)
{
    int b = blockIdx.x;
    for (int c = threadIdx.x; c < 512; c += 256) {
        float s = 0.f;
        for (int ns = 0; ns < 32; ++ns) s += part[((long)ns * 4 + b) * C_DIM + c];
        out[b * C_DIM + c] = s * scale;
    }
}

// out[z][n] = sum_c X[z][n][c] * w[(z&3)][c]
__global__ __launch_bounds__(256) void dot_rows(
    const ushort_t* __restrict__ X, const float* __restrict__ w,
    float* __restrict__ out)
{
    const int tid = threadIdx.x;
    const int rn = tid >> 2, cs = (tid & 3) * 128;
    const int z = blockIdx.y;
    const int n = blockIdx.x * 64 + rn;
    const ushort_t* row = X + (long)z * CN_ + (long)n * C_DIM;
    const float* wz = w + (long)(z & 3) * C_DIM;
    float s = 0.f;
    for (int i = 0; i < 128; i += 8) {
        uint4 u = *(const uint4*)&row[cs + i];
        const ushort_t* us = (const ushort_t*)&u;
#pragma unroll
        for (int k2 = 0; k2 < 8; ++k2) s += b2f(us[k2]) * wz[cs + i + k2];
    }
    s += __shfl_xor(s, 1); s += __shfl_xor(s, 2);
    if ((tid & 3) == 0) out[(long)z * N_DIM + n] = s;
}

// alpha[b,n] = softmax_n(logits[b,:]) * N
__global__ __launch_bounds__(256) void softmax_alpha(
    const float* __restrict__ logits, float* __restrict__ alpha)
{
    int b = blockIdx.x, tid = threadIdx.x;
    const float* L = logits + (long)b * N_DIM;
    float* A = alpha + (long)b * N_DIM;
    float lv[16];
    float mx = -3.4e38f;
#pragma unroll
    for (int i = 0; i < 4; i++) {
        float4 v = *(const float4*)&L[tid * 4 + i * 1024];
        lv[4 * i + 0] = v.x; lv[4 * i + 1] = v.y; lv[4 * i + 2] = v.z; lv[4 * i + 3] = v.w;
        mx = fmaxf(mx, fmaxf(fmaxf(v.x, v.y), fmaxf(v.z, v.w)));
    }
    __shared__ float red[8];
    float m = mx;
#pragma unroll
    for (int off = 32; off; off >>= 1) m = fmaxf(m, __shfl_down(m, off, 64));
    int wid = tid >> 6, lane = tid & 63;
    if (lane == 0) red[wid] = m;
    __syncthreads();
    m = fmaxf(fmaxf(red[0], red[1]), fmaxf(red[2], red[3]));
    float e[16], s = 0.f;
#pragma unroll
    for (int i = 0; i < 16; i++) { e[i] = expf(lv[i] - m); s += e[i]; }
#pragma unroll
    for (int off = 32; off; off >>= 1) s += __shfl_down(s, off, 64);
    if (lane == 0) red[4 + wid] = s;
    __syncthreads();
    float S = red[4] + red[5] + red[6] + red[7];
    float sc = 4096.f / S;
#pragma unroll
    for (int i = 0; i < 4; i++)
        *(float4*)&A[tid * 4 + i * 1024] =
            make_float4(e[4 * i] * sc, e[4 * i + 1] * sc, e[4 * i + 2] * sc, e[4 * i + 3] * sc);
}

// row LayerNorm over c (512) per (z,n); optional relu; out bf16 or f32
template<int RELU, int OBF>
__global__ __launch_bounds__(256) void ln_row(
    const float* __restrict__ in, const float* __restrict__ g,
    const float* __restrict__ bt, void* __restrict__ outv)
{
    const int tid = threadIdx.x;
    const int r = tid >> 3, cs = (tid & 7) * 64;
    const long base = (((long)blockIdx.y * N_DIM) + blockIdx.x * 32 + r) * C_DIM + cs;
    const float* I = in + base;
    float4 v[16];
    float s = 0.f, s2 = 0.f;
#pragma unroll
    for (int i = 0; i < 16; ++i) {
        v[i] = *(const float4*)&I[i * 4];
        s += v[i].x + v[i].y + v[i].z + v[i].w;
        s2 += v[i].x * v[i].x + v[i].y * v[i].y + v[i].z * v[i].z + v[i].w * v[i].w;
    }
#pragma unroll
    for (int off = 1; off < 8; off <<= 1) { s += __shfl_xor(s, off); s2 += __shfl_xor(s2, off); }
    const float mean = s * (1.f / 512.f);
    const float var = s2 * (1.f / 512.f) - mean * mean;
    const float rs = rsqrtf(var + 1e-6f);
#pragma unroll
    for (int i = 0; i < 16; ++i) {
        float4 gv = *(const float4*)&g[cs + i * 4];
        float4 bv = *(const float4*)&bt[cs + i * 4];
        float o[4];
        o[0] = (v[i].x - mean) * rs * gv.x + bv.x;
        o[1] = (v[i].y - mean) * rs * gv.y + bv.y;
        o[2] = (v[i].z - mean) * rs * gv.z + bv.z;
        o[3] = (v[i].w - mean) * rs * gv.w + bv.w;
        if (RELU) {
            o[0] = fmaxf(o[0], 0.f); o[1] = fmaxf(o[1], 0.f);
            o[2] = fmaxf(o[2], 0.f); o[3] = fmaxf(o[3], 0.f);
        }
        if (OBF) {
            union { ushort_t s4[4]; uint2 u; } p;
            p.s4[0] = f2b(o[0]); p.s4[1] = f2b(o[1]); p.s4[2] = f2b(o[2]); p.s4[3] = f2b(o[3]);
            *(uint2*)&((ushort_t*)outv)[base + i * 4] = p.u;
        } else {
            *(float4*)&((float*)outv)[base + i * 4] = make_float4(o[0], o[1], o[2], o[3]);
        }
    }
}

extern "C" void kernel_launch(void* const* d_in, const int* in_sizes, int n_in,
                              void* d_out, int out_size, void* d_ws, size_t ws_size,
                              hipStream_t stream)
{
    const float* x     = (const float*)d_in[0];
    const float* Wq    = (const float*)d_in[1];
    const float* Wk    = (const float*)d_in[2];
    const float* Wv    = (const float*)d_in[3];
    const float* Wphi  = (const float*)d_in[4];
    const float* ln1_w = (const float*)d_in[5];
    const float* ln1_b = (const float*)d_in[6];
    const float* fc1_w = (const float*)d_in[7];
    const float* fc1_bias = (const float*)d_in[8];
    const float* fc2_w = (const float*)d_in[9];
    const float* fc2_bias = (const float*)d_in[10];
    const float* ln2_w = (const float*)d_in[11];
    const float* ln2_b = (const float*)d_in[12];
    float* out = (float*)d_out;

    float* ws = (float*)d_ws;
    const long CN = CN_;
    // region map (float units); lifetimes are stream-sequential:
    ushort_t* xTfirst = (ushort_t*)ws;                 // [0,2CN)  (tln later)
    ushort_t* tln     = (ushort_t*)ws;
    ushort_t* xT12 = (ushort_t*)(ws + 2 * CN);         // [2CN,8CN) stage2
    ushort_t* hbuf4 = (ushort_t*)(ws + 2 * CN);        // stage3 reuse [2CN,6CN)
    ushort_t* q12   = (ushort_t*)(ws + 8 * CN);        // [8CN,14CN)
    ushort_t* phi12 = (ushort_t*)(ws + 14 * CN);       // [14CN,20CN)
    ushort_t* k0b = (ushort_t*)(ws + 20 * CN);         // [20CN,22CN)
    ushort_t* v0b = (ushort_t*)(ws + 22 * CN);         // [22CN,24CN)
    float* pre = ws + 20 * CN;                         // stage3 reuse [20CN,24CN)
    ushort_t* khat = (ushort_t*)(ws + 24 * CN);        // [24CN,26CN)
    ushort_t* v0c  = (ushort_t*)(ws + 26 * CN);        // [26CN,28CN)
    float* ubuf = ws + 24 * CN;                        // stage3 reuse [24CN,28CN)
    float* tmp  = ws + 28 * CN;                        // [28CN,32CN)
    float* ybar = ws + 32 * CN;                        // [32CN,33CN)
    float* kvb  = ws + 33 * CN;                        // 1M floats
    ushort_t* kvT = (ushort_t*)(ws + 33 * CN + 1048576);   // 1M bf16
    float* wb = ws + 33 * CN + 1572864;
    ushort_t* Wk_b   = (ushort_t*)(wb);
    ushort_t* Wq_b   = (ushort_t*)(wb + 32768);
    ushort_t* Wv_b   = (ushort_t*)(wb + 65536);
    ushort_t* Wphi_b = (ushort_t*)(wb + 196608);
    ushort_t* fc1_b16 = (ushort_t*)(wb + 327680);
    ushort_t* fc2_b16 = (ushort_t*)(wb + 851968);
    float* part   = wb + 1376256;                      // 65536 floats
    float* Qg     = wb + 1441792;
    float* ksum   = wb + 1443840;
    float* logits = wb + 1445888;
    float* alpha  = wb + 1462272;
    float* den12  = wb + 1478656;                      // 49152 floats

    dim3 blk(256);

    // weights -> bf16
    cvt_f2b<<<64, blk, 0, stream>>>(Wk, Wk_b, 65536);
    cvt_f2b<<<64, blk, 0, stream>>>(Wq, Wq_b, 65536);
    cvt_f2b<<<256, blk, 0, stream>>>(Wv, Wv_b, 262144);
    cvt_f2b<<<256, blk, 0, stream>>>(Wphi, Wphi_b, 262144);
    cvt_f2b<<<1024, blk, 0, stream>>>(fc1_w, fc1_b16, 1048576);
    cvt_f2b<<<1024, blk, 0, stream>>>(fc2_w, fc2_b16, 1048576);
    hipMemsetAsync(kvb, 0, 1048576 * sizeof(float), stream);
    hipMemsetAsync(ybar, 0, (size_t)CN * sizeof(float), stream);

    // transposes: first 4 batches + rest 12 batches
    transpose_f2b<<<dim3(64, 8, 4), blk, 0, stream>>>(x, xTfirst, 512, 4096, CN, CN);
    transpose_f2b<<<dim3(64, 8, 12), blk, 0, stream>>>(x + 4 * CN, xT12, 512, 4096, CN, CN);

    // stage 1: k0, v0, reductions, alpha, ksum, kv
    mfma_gemm<EPI_PHI, true, true><<<512, blk, 0, stream>>>(
        Wk_b, xTfirst, k0b, nullptr, nullptr, nullptr, 128, 512, 512, CN, CN, 0, 4, 32);
    mfma_gemm<EPI_NONE, false, true><<<512, blk, 0, stream>>>(
        Wv_b, xTfirst, v0b, nullptr, nullptr, nullptr, 512, 512, 512, CN, CN, 0, 4, 32);
    colreduce_part<<<dim3(32, 4), blk, 0, stream>>>(k0b, nullptr, part);
    colreduce_fin<<<4, blk, 0, stream>>>(part, Qg, 1.f / 4096.f);
    dot_rows<<<dim3(64, 4), blk, 0, stream>>>(k0b, Qg, logits);
    softmax_alpha<<<4, blk, 0, stream>>>(logits, alpha);
    colreduce_part<<<dim3(32, 4), blk, 0, stream>>>(k0b, alpha, part);
    colreduce_fin<<<4, blk, 0, stream>>>(part, ksum, 1.f);
    transpose_b2b<1><<<dim3(64, 8, 4), blk, 0, stream>>>(k0b, khat, alpha);
    transpose_b2b<0><<<dim3(64, 8, 4), blk, 0, stream>>>(v0b, v0c, nullptr);
    kv_mfma<<<256, blk, 0, stream>>>(v0c, khat, kvb);
    cvt_scale<<<1024, blk, 0, stream>>>(kvb, kvT);

    // stage 2: all 12 rest batches in one pass
    mfma_gemm<EPI_PHI, true, true><<<1536, blk, 0, stream>>>(
        Wq_b, xT12, q12, nullptr, nullptr, nullptr, 128, 512, 512, CN, CN, 0, 4, 32);
    mfma_gemm<EPI_NONE, false, true><<<1536, blk, 0, stream>>>(
        Wphi_b, xT12, phi12, nullptr, nullptr, nullptr, 512, 512, 512, CN, CN, 0, 4, 32);
    dot_rows<<<dim3(64, 12), blk, 0, stream>>>(q12, ksum, den12);
    ybar_mfma<<<384, blk, 0, stream>>>(q12, kvT, phi12, den12, ybar);

    // stage 3: pre = firstT + ybar*phiF; LN1; MLP (batched z=4); LN2+relu; out
    mfma_gemm<EPI_PRE, false, false><<<512, blk, 0, stream>>>(
        Wphi_b, xTfirst, pre, nullptr, xTfirst, ybar, 512, 512, 512, CN, CN, CN, 4, 32);
    ln_row<0, 1><<<dim3(128, 4), blk, 0, stream>>>(pre, ln1_w, ln1_b, tln);
    mfma_gemm<EPI_RELU_BIAS, false, true><<<2048, blk, 0, stream>>>(
        fc1_b16, tln, hbuf4, fc1_bias, nullptr, nullptr,
        512, 2048, 512, CN, 8388608, 0, 16, 32);
    mfma_gemm<EPI_RES_BIAS, false, false><<<512, blk, 0, stream>>>(
        fc2_b16, hbuf4, ubuf, fc2_bias, tln, nullptr,
        2048, 512, 2048, 8388608, CN, CN, 4, 32);
    ln_row<1, 0><<<dim3(128, 4), blk, 0, stream>>>(ubuf, ln2_w, ln2_b, tmp);
    transpose_ff<<<dim3(8, 64, 4), blk, 0, stream>>>(tmp, out, 4096, 512, CN, CN);

    // passthrough: out[4:] = rest
    hipMemcpyAsync(out + 4 * CN, x + 4 * CN, 12 * CN * sizeof(float),
                   hipMemcpyDeviceToDevice, stream);
}

// Round 9
// 564.672 us; speedup vs baseline: 4.2935x; 1.1567x over previous
//
#include <hip/hip_runtime.h>

#define N_DIM 4096
#define C_DIM 512
#define CN_ ((long)C_DIM * (long)N_DIM)   // 2,097,152

typedef unsigned short ushort_t;
typedef __attribute__((ext_vector_type(8))) short bf16x8;
typedef __attribute__((ext_vector_type(4))) float f32x4;

typedef const __attribute__((address_space(1))) unsigned int* gas_t;
typedef __attribute__((address_space(3))) unsigned int* las_t;
#define GLOAD(g, l) __builtin_amdgcn_global_load_lds((gas_t)(g), (las_t)(l), 16, 0, 0)

__device__ __forceinline__ ushort_t f2b(float f) {
    unsigned u = __builtin_bit_cast(unsigned, f);
    u += 0x7fffu + ((u >> 16) & 1u);
    return (ushort_t)(u >> 16);
}
__device__ __forceinline__ float b2f(ushort_t s) {
    return __builtin_bit_cast(float, (unsigned)s << 16);
}

enum { EPI_NONE = 0, EPI_PHI = 1, EPI_RELU_BIAS = 2, EPI_RES_BIAS = 3, EPI_PRE = 4 };

// ---------------------------------------------------------------------------
// v3 structure: 128x128 tile, 4 waves, K-unroll x2 (two LDS buffer pairs,
// 8 global_load_lds(16B) in flight per phase). XOR swizzle via pre-swizzled
// global src; reads use rsw. XCD-bijective 1D remap.
// ---------------------------------------------------------------------------
template<int EPI, bool GROUPED, bool OBF>
__global__ __launch_bounds__(256) void mfma_gemm(
    const ushort_t* __restrict__ Wb, const ushort_t* __restrict__ A,
    void* __restrict__ OUTV, const float* __restrict__ bias,
    const ushort_t* __restrict__ auxb, const float* __restrict__ auxf,
    int K, int O, int a_rstride, long a_zstride, long o_zstride, long auxb_zstride,
    int xt, int yt)
{
    __shared__ ushort_t Als[2][128 * 32];
    __shared__ ushort_t Bls[2][128 * 32];
    const int tid = threadIdx.x;

    const int L = blockIdx.x;
    const int gpx = (gridDim.x >> 3) / xt;
    const int xcd = L & 7;
    const int j = L >> 3;
    const int xtile = j % xt;
    const int g = xcd * gpx + j / xt;
    const int ytile = g % yt;
    const int z = g / yt;

    const int o0 = xtile * 128;
    const int n0 = ytile * 128;
    const ushort_t* Az = A + (long)z * a_zstride;
    const ushort_t* Wp = Wb;
    int kbase = 0, obase = o0;
    if (GROUPED) { int gg = o0 >> 7; Wp = Wb + (long)gg * (128 * 128); kbase = gg << 7; obase = 0; }

    const int w = tid >> 6, l = tid & 63;
    const int lr = l >> 2, lg = l & 3;
    const int rA0 = w * 32 + lr, rA1 = w * 32 + 16 + lr;
    const int gA0 = lg ^ ((rA0 >> 1) & 3), gA1 = lg ^ ((rA1 >> 1) & 3);
    const ushort_t* ap0 = Az + (long)(n0 + rA0) * a_rstride + kbase + gA0 * 8;
    const ushort_t* ap1 = Az + (long)(n0 + rA1) * a_rstride + kbase + gA1 * 8;
    const ushort_t* bp0 = Wp + (long)(obase + rA0) * K + gA0 * 8;
    const ushort_t* bp1 = Wp + (long)(obase + rA1) * K + gA1 * 8;
    const int la0 = (w * 32) * 32, la1 = (w * 32 + 16) * 32;

    const int wr = (w >> 1) * 64, wc = (w & 1) * 64;
    const int fr = l & 15, ks = l >> 4;
    const int rsw = (ks ^ ((fr >> 1) & 3)) << 3;

    f32x4 acc[4][4];
#pragma unroll
    for (int m = 0; m < 4; ++m)
#pragma unroll
        for (int nf = 0; nf < 4; ++nf) acc[m][nf] = f32x4{0.f, 0.f, 0.f, 0.f};

    for (int kk = 0; kk < K; kk += 64) {
        __syncthreads();
        GLOAD(ap0 + kk, &Als[0][la0]);
        GLOAD(ap1 + kk, &Als[0][la1]);
        GLOAD(bp0 + kk, &Bls[0][la0]);
        GLOAD(bp1 + kk, &Bls[0][la1]);
        GLOAD(ap0 + kk + 32, &Als[1][la0]);
        GLOAD(ap1 + kk + 32, &Als[1][la1]);
        GLOAD(bp0 + kk + 32, &Bls[1][la0]);
        GLOAD(bp1 + kk + 32, &Bls[1][la1]);
        __syncthreads();
#pragma unroll
        for (int s = 0; s < 2; ++s) {
            bf16x8 af[4], bfv[4];
#pragma unroll
            for (int m = 0; m < 4; ++m)
                af[m] = *(const bf16x8*)&Als[s][(wr + m * 16 + fr) * 32 + rsw];
#pragma unroll
            for (int nf = 0; nf < 4; ++nf)
                bfv[nf] = *(const bf16x8*)&Bls[s][(wc + nf * 16 + fr) * 32 + rsw];
#pragma unroll
            for (int m = 0; m < 4; ++m)
#pragma unroll
                for (int nf = 0; nf < 4; ++nf)
                    acc[m][nf] = __builtin_amdgcn_mfma_f32_16x16x32_bf16(
                        af[m], bfv[nf], acc[m][nf], 0, 0, 0);
        }
    }

#pragma unroll
    for (int m = 0; m < 4; ++m) {
#pragma unroll
        for (int nf = 0; nf < 4; ++nf) {
            const int oo = o0 + wc + nf * 16 + fr;
            float bval = 0.f;
            if (EPI == EPI_RELU_BIAS || EPI == EPI_RES_BIAS) bval = bias[oo];
#pragma unroll
            for (int j2 = 0; j2 < 4; ++j2) {
                const int nn = n0 + wr + m * 16 + ks * 4 + j2;
                const long ridx = (long)nn * O + oo;
                float v = acc[m][nf][j2];
                if (EPI == EPI_PHI)            v = fmaxf(v, 0.f) + 1.f;
                else if (EPI == EPI_RELU_BIAS) v = fmaxf(v + bval, 0.f);
                else if (EPI == EPI_RES_BIAS)  v = v + bval + b2f(auxb[(long)z * auxb_zstride + ridx]);
                else if (EPI == EPI_PRE)       v = b2f(auxb[(long)z * auxb_zstride + ridx]) + auxf[ridx] * v;
                if (OBF) ((ushort_t*)OUTV)[(long)z * o_zstride + ridx] = f2b(v);
                else     ((float*)OUTV)[(long)z * o_zstride + ridx] = v;
            }
        }
    }
}

// ---------------------------------------------------------------------------
// kv v3: kvb[b][d][c] += sum_{n in 512-chunk} v0c[b][d][n] * khat[b][c][n]
// grid 512: xt=4 c-tiles, 4 d-tiles, z = b*8+nch
// ---------------------------------------------------------------------------
__global__ __launch_bounds__(256) void kv_mfma(
    const ushort_t* __restrict__ v0c, const ushort_t* __restrict__ khat,
    float* __restrict__ kvb)
{
    __shared__ ushort_t Als[2][128 * 32];
    __shared__ ushort_t Bls[2][128 * 32];
    const int tid = threadIdx.x;
    const int L = blockIdx.x;
    const int gpx = (gridDim.x >> 3) >> 2;
    const int xcd = L & 7;
    const int j = L >> 3;
    const int xtile = j & 3;
    const int g = xcd * gpx + (j >> 2);
    const int ytile = g & 3;
    const int z = g >> 2;
    const int c0 = xtile * 128, d0 = ytile * 128;
    const int b = z >> 3, nch = z & 7;

    const int w = tid >> 6, l = tid & 63;
    const int lr = l >> 2, lg = l & 3;
    const int rA0 = w * 32 + lr, rA1 = w * 32 + 16 + lr;
    const int gA0 = lg ^ ((rA0 >> 1) & 3), gA1 = lg ^ ((rA1 >> 1) & 3);
    const ushort_t* Ab = v0c + (long)b * CN_ + nch * 512;
    const ushort_t* Bb = khat + (long)b * CN_ + nch * 512;
    const ushort_t* ap0 = Ab + (long)(d0 + rA0) * N_DIM + gA0 * 8;
    const ushort_t* ap1 = Ab + (long)(d0 + rA1) * N_DIM + gA1 * 8;
    const ushort_t* bp0 = Bb + (long)(c0 + rA0) * N_DIM + gA0 * 8;
    const ushort_t* bp1 = Bb + (long)(c0 + rA1) * N_DIM + gA1 * 8;
    const int la0 = (w * 32) * 32, la1 = (w * 32 + 16) * 32;

    const int wr = (w >> 1) * 64, wc = (w & 1) * 64;
    const int fr = l & 15, ks = l >> 4;
    const int rsw = (ks ^ ((fr >> 1) & 3)) << 3;

    f32x4 acc[4][4];
#pragma unroll
    for (int m = 0; m < 4; ++m)
#pragma unroll
        for (int nf = 0; nf < 4; ++nf) acc[m][nf] = f32x4{0.f, 0.f, 0.f, 0.f};

    for (int kk = 0; kk < 512; kk += 64) {
        __syncthreads();
        GLOAD(ap0 + kk, &Als[0][la0]);
        GLOAD(ap1 + kk, &Als[0][la1]);
        GLOAD(bp0 + kk, &Bls[0][la0]);
        GLOAD(bp1 + kk, &Bls[0][la1]);
        GLOAD(ap0 + kk + 32, &Als[1][la0]);
        GLOAD(ap1 + kk + 32, &Als[1][la1]);
        GLOAD(bp0 + kk + 32, &Bls[1][la0]);
        GLOAD(bp1 + kk + 32, &Bls[1][la1]);
        __syncthreads();
#pragma unroll
        for (int s = 0; s < 2; ++s) {
            bf16x8 af[4], bfv[4];
#pragma unroll
            for (int m = 0; m < 4; ++m)
                af[m] = *(const bf16x8*)&Als[s][(wr + m * 16 + fr) * 32 + rsw];
#pragma unroll
            for (int nf = 0; nf < 4; ++nf)
                bfv[nf] = *(const bf16x8*)&Bls[s][(wc + nf * 16 + fr) * 32 + rsw];
#pragma unroll
            for (int m = 0; m < 4; ++m)
#pragma unroll
                for (int nf = 0; nf < 4; ++nf)
                    acc[m][nf] = __builtin_amdgcn_mfma_f32_16x16x32_bf16(
                        af[m], bfv[nf], acc[m][nf], 0, 0, 0);
        }
    }

    float* KV = kvb + (long)b * 262144;
#pragma unroll
    for (int m = 0; m < 4; ++m)
#pragma unroll
        for (int nf = 0; nf < 4; ++nf) {
            const int cc = c0 + wc + nf * 16 + fr;
#pragma unroll
            for (int j2 = 0; j2 < 4; ++j2) {
                const int dd = d0 + wr + m * 16 + ks * 4 + j2;
                atomicAdd(&KV[(long)dd * 512 + cc], acc[m][nf][j2]);
            }
        }
}

// ---------------------------------------------------------------------------
// ybar stage A: y12[mm][n][d] = bf16( (sum_c q12[mm][n][c]*kvT[mm&3][d][c])
//                                     * (1/(den12[mm][n]+eps)) * phi12[mm][n][d] )
// grid 1536: xt=4 d-tiles, yt=32 n-tiles, z=mm (0..11)
// ---------------------------------------------------------------------------
__global__ __launch_bounds__(256) void ybar_gemm(
    const ushort_t* __restrict__ q12, const ushort_t* __restrict__ kvT,
    const ushort_t* __restrict__ phi12, const float* __restrict__ den12,
    ushort_t* __restrict__ y12)
{
    __shared__ ushort_t Als[2][128 * 32];
    __shared__ ushort_t Bls[2][128 * 32];
    const int tid = threadIdx.x;
    const int L = blockIdx.x;
    const int gpx = (gridDim.x >> 3) >> 2;
    const int xcd = L & 7;
    const int j = L >> 3;
    const int xtile = j & 3;
    const int g = xcd * gpx + (j >> 2);
    const int ytile = g & 31;
    const int mm = g >> 5;
    const int o0 = xtile * 128, n0 = ytile * 128;

    const int w = tid >> 6, l = tid & 63;
    const int lr = l >> 2, lg = l & 3;
    const int rA0 = w * 32 + lr, rA1 = w * 32 + 16 + lr;
    const int gA0 = lg ^ ((rA0 >> 1) & 3), gA1 = lg ^ ((rA1 >> 1) & 3);
    const ushort_t* ap0 = q12 + (long)mm * CN_ + (long)(n0 + rA0) * 512 + gA0 * 8;
    const ushort_t* ap1 = q12 + (long)mm * CN_ + (long)(n0 + rA1) * 512 + gA1 * 8;
    const ushort_t* bp0 = kvT + (long)(mm & 3) * 262144 + (long)(o0 + rA0) * 512 + gA0 * 8;
    const ushort_t* bp1 = kvT + (long)(mm & 3) * 262144 + (long)(o0 + rA1) * 512 + gA1 * 8;
    const int la0 = (w * 32) * 32, la1 = (w * 32 + 16) * 32;

    const int wr = (w >> 1) * 64, wc = (w & 1) * 64;
    const int fr = l & 15, ks = l >> 4;
    const int rsw = (ks ^ ((fr >> 1) & 3)) << 3;

    f32x4 acc[4][4];
#pragma unroll
    for (int m = 0; m < 4; ++m)
#pragma unroll
        for (int nf = 0; nf < 4; ++nf) acc[m][nf] = f32x4{0.f, 0.f, 0.f, 0.f};

    for (int kk = 0; kk < 512; kk += 64) {
        __syncthreads();
        GLOAD(ap0 + kk, &Als[0][la0]);
        GLOAD(ap1 + kk, &Als[0][la1]);
        GLOAD(bp0 + kk, &Bls[0][la0]);
        GLOAD(bp1 + kk, &Bls[0][la1]);
        GLOAD(ap0 + kk + 32, &Als[1][la0]);
        GLOAD(ap1 + kk + 32, &Als[1][la1]);
        GLOAD(bp0 + kk + 32, &Bls[1][la0]);
        GLOAD(bp1 + kk + 32, &Bls[1][la1]);
        __syncthreads();
#pragma unroll
        for (int s = 0; s < 2; ++s) {
            bf16x8 af[4], bfv[4];
#pragma unroll
            for (int m = 0; m < 4; ++m)
                af[m] = *(const bf16x8*)&Als[s][(wr + m * 16 + fr) * 32 + rsw];
#pragma unroll
            for (int nf = 0; nf < 4; ++nf)
                bfv[nf] = *(const bf16x8*)&Bls[s][(wc + nf * 16 + fr) * 32 + rsw];
#pragma unroll
            for (int m = 0; m < 4; ++m)
#pragma unroll
                for (int nf = 0; nf < 4; ++nf)
                    acc[m][nf] = __builtin_amdgcn_mfma_f32_16x16x32_bf16(
                        af[m], bfv[nf], acc[m][nf], 0, 0, 0);
        }
    }

    const ushort_t* P = phi12 + (long)mm * CN_;
    const float* D = den12 + (long)mm * N_DIM;
    ushort_t* Y = y12 + (long)mm * CN_;
#pragma unroll
    for (int m = 0; m < 4; ++m) {
        float zr[4];
#pragma unroll
        for (int j2 = 0; j2 < 4; ++j2)
            zr[j2] = 1.f / (D[n0 + wr + m * 16 + ks * 4 + j2] + 1e-6f);
#pragma unroll
        for (int nf = 0; nf < 4; ++nf) {
            const int oo = o0 + wc + nf * 16 + fr;
#pragma unroll
            for (int j2 = 0; j2 < 4; ++j2) {
                const int nn = n0 + wr + m * 16 + ks * 4 + j2;
                const long idx = (long)nn * 512 + oo;
                Y[idx] = f2b(acc[m][nf][j2] * zr[j2] * b2f(P[idx]));
            }
        }
    }
}

// ybar stage B: ybar[i] = (1/12) sum_mm y12[mm][i]   (8 elems/thread)
__global__ __launch_bounds__(256) void ybar_reduce(
    const ushort_t* __restrict__ y12, float* __restrict__ ybar)
{
    const long i = ((long)blockIdx.x * 256 + threadIdx.x) * 8;
    float s[8] = {0.f, 0.f, 0.f, 0.f, 0.f, 0.f, 0.f, 0.f};
    for (int mm = 0; mm < 12; ++mm) {
        uint4 u = *(const uint4*)&y12[(long)mm * CN_ + i];
        const ushort_t* us = (const ushort_t*)&u;
#pragma unroll
        for (int j = 0; j < 8; ++j) s[j] += b2f(us[j]);
    }
#pragma unroll
    for (int j = 0; j < 8; ++j) s[j] *= (1.f / 12.f);
    *(float4*)&ybar[i] = make_float4(s[0], s[1], s[2], s[3]);
    *(float4*)&ybar[i + 4] = make_float4(s[4], s[5], s[6], s[7]);
}

// kvT[i] = f2b(kvb[i] * 1/sqrt(512))
__global__ __launch_bounds__(256) void cvt_scale(
    const float* __restrict__ in, ushort_t* __restrict__ out)
{
    const float s = 0.044194173824159216f;
    int i = (blockIdx.x * 256 + threadIdx.x) * 4;
    float4 v = *(const float4*)&in[i];
    union { ushort_t sh[4]; uint2 u; } p;
    p.sh[0] = f2b(v.x * s); p.sh[1] = f2b(v.y * s);
    p.sh[2] = f2b(v.z * s); p.sh[3] = f2b(v.w * s);
    *(uint2*)&out[i] = p.u;
}

// bf16 [z][4096][512] -> bf16 [z][512][4096]; ALPHA: out *= alpha[z][n]
template<int ALPHA>
__global__ __launch_bounds__(256) void transpose_b2b(
    const ushort_t* __restrict__ in, ushort_t* __restrict__ out,
    const float* __restrict__ alpha)
{
    __shared__ ushort_t t[64][72];
    const int tid = threadIdx.x;
    const int n0 = blockIdx.x * 64, c0 = blockIdx.y * 64, z = blockIdx.z;
    const ushort_t* I = in + (long)z * CN_;
    ushort_t* O = out + (long)z * CN_;
    const int r = tid >> 2, s8 = (tid & 3) * 16;
    uint4 u0 = *(const uint4*)&I[(long)(n0 + r) * 512 + c0 + s8];
    uint4 u1 = *(const uint4*)&I[(long)(n0 + r) * 512 + c0 + s8 + 8];
    *(uint4*)&t[r][s8] = u0;
    *(uint4*)&t[r][s8 + 8] = u1;
    __syncthreads();
    union { ushort_t sh[16]; uint4 u[2]; } p;
#pragma unroll
    for (int i = 0; i < 16; ++i) {
        ushort_t v = t[s8 + i][r];
        if (ALPHA) v = f2b(b2f(v) * alpha[(long)z * N_DIM + n0 + s8 + i]);
        p.sh[i] = v;
    }
    uint4* dst = (uint4*)&O[(long)(c0 + r) * N_DIM + n0 + s8];
    dst[0] = p.u[0]; dst[1] = p.u[1];
}

// fp32 -> bf16 elementwise
__global__ __launch_bounds__(256) void cvt_f2b(
    const float* __restrict__ in, ushort_t* __restrict__ out, int n)
{
    int i = (blockIdx.x * 256 + threadIdx.x) * 4;
    if (i >= n) return;
    float4 v = *(const float4*)&in[i];
    union { ushort_t s[4]; uint2 u; } p;
    p.s[0] = f2b(v.x); p.s[1] = f2b(v.y); p.s[2] = f2b(v.z); p.s[3] = f2b(v.w);
    *(uint2*)&out[i] = p.u;
}

// transpose fp32 [z][rows][cols] -> bf16 [z][cols][rows]
__global__ __launch_bounds__(256) void transpose_f2b(
    const float* __restrict__ in, ushort_t* __restrict__ out,
    int rows, int cols, long in_z, long out_z)
{
    __shared__ float t[64][65];
    const int tid = threadIdx.x;
    const int n0 = blockIdx.x * 64, c0 = blockIdx.y * 64;
    const float* I = in + (long)blockIdx.z * in_z;
    ushort_t* Ot = out + (long)blockIdx.z * out_z;
    const int r = tid >> 2, s4 = (tid & 3) * 16;
#pragma unroll
    for (int i = 0; i < 16; i += 4) {
        float4 v = *(const float4*)&I[(long)(c0 + r) * cols + n0 + s4 + i];
        t[r][s4 + i] = v.x; t[r][s4 + i + 1] = v.y;
        t[r][s4 + i + 2] = v.z; t[r][s4 + i + 3] = v.w;
    }
    __syncthreads();
    union { ushort_t s[16]; uint4 u[2]; } pk;
#pragma unroll
    for (int i = 0; i < 16; ++i) pk.s[i] = f2b(t[s4 + i][r]);
    uint4* dst = (uint4*)&Ot[(long)(n0 + r) * rows + c0 + s4];
    dst[0] = pk.u[0]; dst[1] = pk.u[1];
}

// transpose fp32 [z][rows][cols] -> fp32 [z][cols][rows]
__global__ __launch_bounds__(256) void transpose_ff(
    const float* __restrict__ in, float* __restrict__ out,
    int rows, int cols, long in_z, long out_z)
{
    __shared__ float t[64][65];
    const int tid = threadIdx.x;
    const int n0 = blockIdx.x * 64, c0 = blockIdx.y * 64;
    const float* I = in + (long)blockIdx.z * in_z;
    float* Ot = out + (long)blockIdx.z * out_z;
    const int r = tid >> 2, s4 = (tid & 3) * 16;
#pragma unroll
    for (int i = 0; i < 16; i += 4) {
        float4 v = *(const float4*)&I[(long)(c0 + r) * cols + n0 + s4 + i];
        t[r][s4 + i] = v.x; t[r][s4 + i + 1] = v.y;
        t[r][s4 + i + 2] = v.z; t[r][s4 + i + 3] = v.w;
    }
    __syncthreads();
#pragma unroll
    for (int i = 0; i < 16; i += 4) {
        float4 o = make_float4(t[s4 + i][r], t[s4 + i + 1][r], t[s4 + i + 2][r], t[s4 + i + 3][r]);
        *(float4*)&Ot[(long)(n0 + r) * rows + c0 + s4 + i] = o;
    }
}

// part[ns][b][c] = sum_{n in 128-row chunk ns} X[b][n][c] * (wgt?[b][n])
__global__ __launch_bounds__(256) void colreduce_part(
    const ushort_t* __restrict__ X, const float* __restrict__ wgt,
    float* __restrict__ part)
{
    const int ns = blockIdx.x, b = blockIdx.y;
    const int tid = threadIdx.x;
    const int w = tid >> 6, l = tid & 63;
    const int c8 = l * 8;
    const ushort_t* Xb = X + (long)b * CN_;
    float acc[8] = {0.f, 0.f, 0.f, 0.f, 0.f, 0.f, 0.f, 0.f};
    for (int r = w; r < 128; r += 4) {
        const int n = ns * 128 + r;
        uint4 u = *(const uint4*)&Xb[(long)n * C_DIM + c8];
        const ushort_t* us = (const ushort_t*)&u;
        const float wv = wgt ? wgt[(long)b * N_DIM + n] : 1.f;
#pragma unroll
        for (int i = 0; i < 8; ++i) acc[i] += b2f(us[i]) * wv;
    }
    __shared__ float red[4][512];
#pragma unroll
    for (int i = 0; i < 8; ++i) red[w][c8 + i] = acc[i];
    __syncthreads();
    for (int c = tid; c < 512; c += 256) {
        part[((long)ns * 4 + b) * C_DIM + c] =
            red[0][c] + red[1][c] + red[2][c] + red[3][c];
    }
}

__global__ __launch_bounds__(256) void colreduce_fin(
    const float* __restrict__ part, float* __restrict__ out, float scale)
{
    int b = blockIdx.x;
    for (int c = threadIdx.x; c < 512; c += 256) {
        float s = 0.f;
        for (int ns = 0; ns < 32; ++ns) s += part[((long)ns * 4 + b) * C_DIM + c];
        out[b * C_DIM + c] = s * scale;
    }
}

// out[z][n] = sum_c X[z][n][c] * w[(z&3)][c]
__global__ __launch_bounds__(256) void dot_rows(
    const ushort_t* __restrict__ X, const float* __restrict__ w,
    float* __restrict__ out)
{
    const int tid = threadIdx.x;
    const int rn = tid >> 2, cs = (tid & 3) * 128;
    const int z = blockIdx.y;
    const int n = blockIdx.x * 64 + rn;
    const ushort_t* row = X + (long)z * CN_ + (long)n * C_DIM;
    const float* wz = w + (long)(z & 3) * C_DIM;
    float s = 0.f;
    for (int i = 0; i < 128; i += 8) {
        uint4 u = *(const uint4*)&row[cs + i];
        const ushort_t* us = (const ushort_t*)&u;
#pragma unroll
        for (int k2 = 0; k2 < 8; ++k2) s += b2f(us[k2]) * wz[cs + i + k2];
    }
    s += __shfl_xor(s, 1); s += __shfl_xor(s, 2);
    if ((tid & 3) == 0) out[(long)z * N_DIM + n] = s;
}

// alpha[b,n] = softmax_n(logits[b,:]) * N
__global__ __launch_bounds__(256) void softmax_alpha(
    const float* __restrict__ logits, float* __restrict__ alpha)
{
    int b = blockIdx.x, tid = threadIdx.x;
    const float* L = logits + (long)b * N_DIM;
    float* A = alpha + (long)b * N_DIM;
    float lv[16];
    float mx = -3.4e38f;
#pragma unroll
    for (int i = 0; i < 4; i++) {
        float4 v = *(const float4*)&L[tid * 4 + i * 1024];
        lv[4 * i + 0] = v.x; lv[4 * i + 1] = v.y; lv[4 * i + 2] = v.z; lv[4 * i + 3] = v.w;
        mx = fmaxf(mx, fmaxf(fmaxf(v.x, v.y), fmaxf(v.z, v.w)));
    }
    __shared__ float red[8];
    float m = mx;
#pragma unroll
    for (int off = 32; off; off >>= 1) m = fmaxf(m, __shfl_down(m, off, 64));
    int wid = tid >> 6, lane = tid & 63;
    if (lane == 0) red[wid] = m;
    __syncthreads();
    m = fmaxf(fmaxf(red[0], red[1]), fmaxf(red[2], red[3]));
    float e[16], s = 0.f;
#pragma unroll
    for (int i = 0; i < 16; i++) { e[i] = expf(lv[i] - m); s += e[i]; }
#pragma unroll
    for (int off = 32; off; off >>= 1) s += __shfl_down(s, off, 64);
    if (lane == 0) red[4 + wid] = s;
    __syncthreads();
    float S = red[4] + red[5] + red[6] + red[7];
    float sc = 4096.f / S;
#pragma unroll
    for (int i = 0; i < 4; i++)
        *(float4*)&A[tid * 4 + i * 1024] =
            make_float4(e[4 * i] * sc, e[4 * i + 1] * sc, e[4 * i + 2] * sc, e[4 * i + 3] * sc);
}

// row LayerNorm over c (512) per (z,n); optional relu; out bf16 or f32
template<int RELU, int OBF>
__global__ __launch_bounds__(256) void ln_row(
    const float* __restrict__ in, const float* __restrict__ g,
    const float* __restrict__ bt, void* __restrict__ outv)
{
    const int tid = threadIdx.x;
    const int r = tid >> 3, cs = (tid & 7) * 64;
    const long base = (((long)blockIdx.y * N_DIM) + blockIdx.x * 32 + r) * C_DIM + cs;
    const float* I = in + base;
    float4 v[16];
    float s = 0.f, s2 = 0.f;
#pragma unroll
    for (int i = 0; i < 16; ++i) {
        v[i] = *(const float4*)&I[i * 4];
        s += v[i].x + v[i].y + v[i].z + v[i].w;
        s2 += v[i].x * v[i].x + v[i].y * v[i].y + v[i].z * v[i].z + v[i].w * v[i].w;
    }
#pragma unroll
    for (int off = 1; off < 8; off <<= 1) { s += __shfl_xor(s, off); s2 += __shfl_xor(s2, off); }
    const float mean = s * (1.f / 512.f);
    const float var = s2 * (1.f / 512.f) - mean * mean;
    const float rs = rsqrtf(var + 1e-6f);
#pragma unroll
    for (int i = 0; i < 16; ++i) {
        float4 gv = *(const float4*)&g[cs + i * 4];
        float4 bv = *(const float4*)&bt[cs + i * 4];
        float o[4];
        o[0] = (v[i].x - mean) * rs * gv.x + bv.x;
        o[1] = (v[i].y - mean) * rs * gv.y + bv.y;
        o[2] = (v[i].z - mean) * rs * gv.z + bv.z;
        o[3] = (v[i].w - mean) * rs * gv.w + bv.w;
        if (RELU) {
            o[0] = fmaxf(o[0], 0.f); o[1] = fmaxf(o[1], 0.f);
            o[2] = fmaxf(o[2], 0.f); o[3] = fmaxf(o[3], 0.f);
        }
        if (OBF) {
            union { ushort_t s4[4]; uint2 u; } p;
            p.s4[0] = f2b(o[0]); p.s4[1] = f2b(o[1]); p.s4[2] = f2b(o[2]); p.s4[3] = f2b(o[3]);
            *(uint2*)&((ushort_t*)outv)[base + i * 4] = p.u;
        } else {
            *(float4*)&((float*)outv)[base + i * 4] = make_float4(o[0], o[1], o[2], o[3]);
        }
    }
}

extern "C" void kernel_launch(void* const* d_in, const int* in_sizes, int n_in,
                              void* d_out, int out_size, void* d_ws, size_t ws_size,
                              hipStream_t stream)
{
    const float* x     = (const float*)d_in[0];
    const float* Wq    = (const float*)d_in[1];
    const float* Wk    = (const float*)d_in[2];
    const float* Wv    = (const float*)d_in[3];
    const float* Wphi  = (const float*)d_in[4];
    const float* ln1_w = (const float*)d_in[5];
    const float* ln1_b = (const float*)d_in[6];
    const float* fc1_w = (const float*)d_in[7];
    const float* fc1_bias = (const float*)d_in[8];
    const float* fc2_w = (const float*)d_in[9];
    const float* fc2_bias = (const float*)d_in[10];
    const float* ln2_w = (const float*)d_in[11];
    const float* ln2_b = (const float*)d_in[12];
    float* out = (float*)d_out;

    float* ws = (float*)d_ws;
    const long CN = CN_;
    // region map (float units); lifetimes are stream-sequential:
    ushort_t* xTfirst = (ushort_t*)ws;                 // [0,2CN)  (tln later)
    ushort_t* tln     = (ushort_t*)ws;
    ushort_t* xT12 = (ushort_t*)(ws + 2 * CN);         // [2CN,8CN) stage2
    ushort_t* hbuf4 = (ushort_t*)(ws + 2 * CN);        // stage3 reuse [2CN,6CN)
    ushort_t* q12   = (ushort_t*)(ws + 8 * CN);        // [8CN,14CN)
    ushort_t* phi12 = (ushort_t*)(ws + 14 * CN);       // [14CN,20CN)
    ushort_t* k0b = (ushort_t*)(ws + 20 * CN);         // [20CN,22CN) stage1
    ushort_t* v0b = (ushort_t*)(ws + 22 * CN);         // [22CN,24CN) stage1
    ushort_t* y12 = (ushort_t*)(ws + 20 * CN);         // stage2 reuse [20CN,26CN)
    float* pre = ws + 20 * CN;                         // stage3 reuse [20CN,24CN)
    ushort_t* khat = (ushort_t*)(ws + 24 * CN);        // [24CN,26CN) stage1
    ushort_t* v0c  = (ushort_t*)(ws + 26 * CN);        // [26CN,28CN) stage1
    float* ubuf = ws + 24 * CN;                        // stage3 reuse [24CN,28CN)
    float* tmp  = ws + 28 * CN;                        // [28CN,32CN)
    float* ybar = ws + 32 * CN;                        // [32CN,33CN)
    float* kvb  = ws + 33 * CN;                        // 1M floats
    ushort_t* kvT = (ushort_t*)(ws + 33 * CN + 1048576);   // 1M bf16
    float* wb = ws + 33 * CN + 1572864;
    ushort_t* Wk_b   = (ushort_t*)(wb);
    ushort_t* Wq_b   = (ushort_t*)(wb + 32768);
    ushort_t* Wv_b   = (ushort_t*)(wb + 65536);
    ushort_t* Wphi_b = (ushort_t*)(wb + 196608);
    ushort_t* fc1_b16 = (ushort_t*)(wb + 327680);
    ushort_t* fc2_b16 = (ushort_t*)(wb + 851968);
    float* part   = wb + 1376256;                      // 65536 floats
    float* Qg     = wb + 1441792;
    float* ksum   = wb + 1443840;
    float* logits = wb + 1445888;
    float* alpha  = wb + 1462272;
    float* den12  = wb + 1478656;                      // 49152 floats

    dim3 blk(256);

    // weights -> bf16
    cvt_f2b<<<64, blk, 0, stream>>>(Wk, Wk_b, 65536);
    cvt_f2b<<<64, blk, 0, stream>>>(Wq, Wq_b, 65536);
    cvt_f2b<<<256, blk, 0, stream>>>(Wv, Wv_b, 262144);
    cvt_f2b<<<256, blk, 0, stream>>>(Wphi, Wphi_b, 262144);
    cvt_f2b<<<1024, blk, 0, stream>>>(fc1_w, fc1_b16, 1048576);
    cvt_f2b<<<1024, blk, 0, stream>>>(fc2_w, fc2_b16, 1048576);
    hipMemsetAsync(kvb, 0, 1048576 * sizeof(float), stream);

    // transposes: first 4 batches + rest 12 batches
    transpose_f2b<<<dim3(64, 8, 4), blk, 0, stream>>>(x, xTfirst, 512, 4096, CN, CN);
    transpose_f2b<<<dim3(64, 8, 12), blk, 0, stream>>>(x + 4 * CN, xT12, 512, 4096, CN, CN);

    // stage 1: k0, v0, reductions, alpha, ksum, kv
    mfma_gemm<EPI_PHI, true, true><<<512, blk, 0, stream>>>(
        Wk_b, xTfirst, k0b, nullptr, nullptr, nullptr, 128, 512, 512, CN, CN, 0, 4, 32);
    mfma_gemm<EPI_NONE, false, true><<<512, blk, 0, stream>>>(
        Wv_b, xTfirst, v0b, nullptr, nullptr, nullptr, 512, 512, 512, CN, CN, 0, 4, 32);
    colreduce_part<<<dim3(32, 4), blk, 0, stream>>>(k0b, nullptr, part);
    colreduce_fin<<<4, blk, 0, stream>>>(part, Qg, 1.f / 4096.f);
    dot_rows<<<dim3(64, 4), blk, 0, stream>>>(k0b, Qg, logits);
    softmax_alpha<<<4, blk, 0, stream>>>(logits, alpha);
    colreduce_part<<<dim3(32, 4), blk, 0, stream>>>(k0b, alpha, part);
    colreduce_fin<<<4, blk, 0, stream>>>(part, ksum, 1.f);
    transpose_b2b<1><<<dim3(64, 8, 4), blk, 0, stream>>>(k0b, khat, alpha);
    transpose_b2b<0><<<dim3(64, 8, 4), blk, 0, stream>>>(v0b, v0c, nullptr);
    kv_mfma<<<512, blk, 0, stream>>>(v0c, khat, kvb);
    cvt_scale<<<1024, blk, 0, stream>>>(kvb, kvT);

    // stage 2: all 12 rest batches in one pass
    mfma_gemm<EPI_PHI, true, true><<<1536, blk, 0, stream>>>(
        Wq_b, xT12, q12, nullptr, nullptr, nullptr, 128, 512, 512, CN, CN, 0, 4, 32);
    mfma_gemm<EPI_NONE, false, true><<<1536, blk, 0, stream>>>(
        Wphi_b, xT12, phi12, nullptr, nullptr, nullptr, 512, 512, 512, CN, CN, 0, 4, 32);
    dot_rows<<<dim3(64, 12), blk, 0, stream>>>(q12, ksum, den12);
    ybar_gemm<<<1536, blk, 0, stream>>>(q12, kvT, phi12, den12, y12);
    ybar_reduce<<<1024, blk, 0, stream>>>(y12, ybar);

    // stage 3: pre = firstT + ybar*phiF; LN1; MLP (batched z=4); LN2+relu; out
    mfma_gemm<EPI_PRE, false, false><<<512, blk, 0, stream>>>(
        Wphi_b, xTfirst, pre, nullptr, xTfirst, ybar, 512, 512, 512, CN, CN, CN, 4, 32);
    ln_row<0, 1><<<dim3(128, 4), blk, 0, stream>>>(pre, ln1_w, ln1_b, tln);
    mfma_gemm<EPI_RELU_BIAS, false, true><<<2048, blk, 0, stream>>>(
        fc1_b16, tln, hbuf4, fc1_bias, nullptr, nullptr,
        512, 2048, 512, CN, 8388608, 0, 16, 32);
    mfma_gemm<EPI_RES_BIAS, false, false><<<512, blk, 0, stream>>>(
        fc2_b16, hbuf4, ubuf, fc2_bias, tln, nullptr,
        2048, 512, 2048, 8388608, CN, CN, 4, 32);
    ln_row<1, 0><<<dim3(128, 4), blk, 0, stream>>>(ubuf, ln2_w, ln2_b, tmp);
    transpose_ff<<<dim3(8, 64, 4), blk, 0, stream>>>(tmp, out, 4096, 512, CN, CN);

    // passthrough: out[4:] = rest
    hipMemcpyAsync(out + 4 * CN, x + 4 * CN, 12 * CN * sizeof(float),
                   hipMemcpyDeviceToDevice, stream);
}